// Round 15
// baseline (521.874 us; speedup 1.0000x reference)
//
#include <hip/hip_runtime.h>
#include <math.h>

#define KC 512
#define DD 128

typedef __attribute__((ext_vector_type(8))) short short8;
typedef __attribute__((ext_vector_type(4))) short short4v;
typedef __attribute__((ext_vector_type(4))) float f32x4;

#define MFMA(a, b, c) __builtin_amdgcn_mfma_f32_16x16x32_bf16(a, b, c, 0, 0, 0)

#define GLOAD_LDS16(g, l)                                        \
  __builtin_amdgcn_global_load_lds(                              \
      (const __attribute__((address_space(1))) void*)(g),        \
      (__attribute__((address_space(3))) void*)(l), 16, 0, 0)

__device__ __forceinline__ short f2bf(float f) {
  unsigned u = __float_as_uint(f);
  u = (u + 0x7FFFu + ((u >> 16) & 1u)) >> 16;
  return (short)u;
}
__device__ __forceinline__ float bf2f(short s) {
  return __uint_as_float(((unsigned)(unsigned short)s) << 16);
}

// ============================================================================
// k_prep: ALL weight permutations + embnorm + border-zero + counts-zero in
// ONE dispatch. grid 2881 x 256
// ============================================================================
__global__ __launch_bounds__(256) void k_prep(
    const float* __restrict__ c2w,
    const float* __restrict__ r1w3, const float* __restrict__ r2w3,
    const float* __restrict__ d1w3, const float* __restrict__ d2w3,
    const float* __restrict__ r1w1, const float* __restrict__ r2w1,
    const float* __restrict__ d1w1, const float* __restrict__ d2w1,
    const float* __restrict__ prew, const float* __restrict__ t1w,
    const float* __restrict__ emb,
    short* __restrict__ wAc2, short* __restrict__ wAr3,
    short* __restrict__ wAr1, short* __restrict__ wApre,
    short* __restrict__ wAt1, short* __restrict__ Ecat,
    float* __restrict__ en, short* __restrict__ A1,
    short* __restrict__ XrP, int* __restrict__ counts) {
  int blk = blockIdx.x, t = threadIdx.x;
  if (blk < 512) {  // perm_c2
    int e = blk * 256 + t;
    int j = e & 7, l = (e >> 3) & 63, ot = (e >> 9) & 7, kc = e >> 12;
    int o = ot * 16 + (l & 15), g = l >> 4;
    int tap = kc >> 1, ci = (kc & 1) * 32 + 8 * g + j;
    wAc2[e] = f2bf(c2w[(o * 64 + ci) * 16 + tap]);
  } else if (blk < 1088) {  // perm_r3 x4
    int sub = blk - 512;
    int which = sub / 144, bb = sub - which * 144;
    const float* w = which == 0 ? r1w3 : which == 1 ? r2w3
                     : which == 2 ? d1w3 : d2w3;
    short* dst = wAr3 + which * 36864;
    int e = bb * 256 + t;
    int j = e & 7, l = (e >> 3) & 63, ot = (e >> 9) & 1, kc = e >> 10;
    int o = ot * 16 + (l & 15), g = l >> 4;
    int tap = kc >> 2, ci = (kc & 3) * 32 + 8 * g + j;
    dst[e] = f2bf(w[(o * 128 + ci) * 9 + tap]);
  } else if (blk < 1152) {  // perm_r1 x4
    int sub = blk - 1088;
    int which = sub >> 4, bb = sub & 15;
    const float* w = which == 0 ? r1w1 : which == 1 ? r2w1
                     : which == 2 ? d1w1 : d2w1;
    short* dst = wAr1 + which * 4096;
    int e = bb * 256 + t;
    int j = e & 7, l = (e >> 3) & 63, ot = e >> 9;
    int o = ot * 16 + (l & 15), g = l >> 4;
    int ci = 8 * g + j;
    dst[e] = f2bf(w[o * 32 + ci]);
  } else if (blk < 1216) {  // perm_pre
    int e = (blk - 1152) * 256 + t;
    int j = e & 7, l = (e >> 3) & 63, ot = (e >> 9) & 7, kc = e >> 12;
    int o = ot * 16 + (l & 15), g = l >> 4;
    int ci = kc * 32 + 8 * g + j;
    wApre[e] = f2bf(prew[o * 128 + ci]);
  } else if (blk < 1728) {  // perm_t1
    int e = (blk - 1216) * 256 + t;
    int j = e & 7, l = (e >> 3) & 63, ot = (e >> 9) & 3, kc = (e >> 11) & 15,
        pp = e >> 15;
    int pyr = pp >> 1, pxr = pp & 1;
    int o = ot * 16 + (l & 15), g = l >> 4;
    int tt = kc >> 2, dy = tt >> 1, dx = tt & 1;
    int ky = (1 - pyr) + 2 * dy, kx = (1 - pxr) + 2 * dx;
    int ci = (kc & 3) * 32 + 8 * g + j;
    wAt1[e] = f2bf(t1w[(ci * 64 + o) * 16 + ky * 4 + kx]);
  } else if (blk < 2496) {  // perm_E
    int e = (blk - 1728) * 256 + t;
    int j = e & 7, l = (e >> 3) & 63, ot = (e >> 9) & 31, kc = e >> 14;
    int c = ot * 16 + (l & 15);
    int k = kc * 32 + 8 * (l >> 4) + j;
    float v = emb[c * DD + (k & 127)];
    short hi = f2bf(v);
    Ecat[e] = (k < 256) ? hi : f2bf(v - bf2f(hi));
  } else if (blk < 2624) {  // embnorm: 4 codes per block (wave = code)
    int c = (blk - 2496) * 4 + (t >> 6), l = t & 63;
    float a = emb[c * DD + l], b2 = emb[c * DD + 64 + l];
    float s = a * a + b2 * b2;
#pragma unroll
    for (int m = 32; m >= 1; m >>= 1) s += __shfl_xor(s, m);
    if (l == 0) en[c] = s;
  } else if (blk < 2880) {  // border zero
    int bb = blk - 2624;
    int b = bb >> 3;
    int tid = ((bb & 7) << 8) + t;  // 0..2047
    short8 z8 = {};
    long baseA = (long)b * 1081600;  // 130*130*64
    for (int e = tid; e < 2080; e += 2048) {
      int r = e >= 1040;
      int rem = r ? e - 1040 : e;
      *(short8*)(A1 + baseA + (r ? 129L * 130 * 64 : 0) + rem * 8) = z8;
    }
    {
      int c = tid >> 10, rem = tid & 1023;
      int row = 1 + (rem >> 3), s8 = rem & 7;
      *(short8*)(A1 + baseA + (row * 130L + (c ? 129 : 0)) * 64 + s8 * 8) = z8;
    }
    long baseX = (long)b * 557568;  // 66*66*128
    for (int e = tid; e < 2112; e += 2048) {
      int r = e >= 1056;
      int rem = r ? e - 1056 : e;
      *(short8*)(XrP + baseX + (r ? 65L * 66 * 128 : 0) + rem * 8) = z8;
    }
    {
      int c = tid >> 10, rem = tid & 1023;
      int row = 1 + (rem >> 4), s8 = rem & 15;
      *(short8*)(XrP + baseX + (row * 66L + (c ? 65 : 0)) * 128 + s8 * 8) = z8;
    }
  } else {  // counts zero
    counts[t] = 0;
    counts[t + 256] = 0;
  }
}

// ============================================================================
// conv1: x[32,1,256,256] f32 -> A1[32,130,130,64] bf16 relu (padded, ch-last)
// grid 4096 = 32 b x 128 y
// ============================================================================
__global__ __launch_bounds__(256) void k_conv1(const float* __restrict__ x,
    const float* __restrict__ w, const float* __restrict__ bias,
    short* __restrict__ A1) {
  __shared__ float sXp[4 * 260];
  __shared__ float sWt[16 * 64];
  int blk = blockIdx.x;
  int y = blk & 127, b = blk >> 7;
  int t = threadIdx.x;
  for (int e = t; e < 1024; e += 256) sWt[e] = w[(e & 63) * 16 + (e >> 6)];
  if (t < 4) {
    sXp[t * 260] = 0.f;
    sXp[t * 260 + 257] = 0.f;
    sXp[t * 260 + 258] = 0.f;
    sXp[t * 260 + 259] = 0.f;
  }
  for (int e = t; e < 1024; e += 256) {
    int r = e >> 8, col = e & 255;
    int giy = 2 * y - 1 + r;
    float v = 0.f;
    if ((unsigned)giy < 256u) v = x[(b * 256 + giy) * 256 + col];
    sXp[r * 260 + col + 1] = v;
  }
  __syncthreads();
  int og = t >> 6, l = t & 63, o0 = og * 16;
  float acc0[16], acc1[16];
#pragma unroll
  for (int oo = 0; oo < 16; ++oo) { acc0[oo] = 0.f; acc1[oo] = 0.f; }
  int xA = 2 * l, xB = 2 * l + 128;
#pragma unroll
  for (int ky = 0; ky < 4; ++ky) {
#pragma unroll
    for (int kx = 0; kx < 4; ++kx) {
      float a0 = sXp[ky * 260 + xA + kx];
      float a1 = sXp[ky * 260 + xB + kx];
      const float* wrow = &sWt[(ky * 4 + kx) * 64 + o0];
#pragma unroll
      for (int oo = 0; oo < 16; ++oo) {
        float wv = wrow[oo];
        acc0[oo] = fmaf(a0, wv, acc0[oo]);
        acc1[oo] = fmaf(a1, wv, acc1[oo]);
      }
    }
  }
  long base0 = (((long)(b * 130 + y + 1)) * 130 + l + 1) * 64 + o0;
  long base1 = base0 + 64 * 64;
  short8 s0a, s0b, s1a, s1b;
#pragma unroll
  for (int oo = 0; oo < 8; ++oo) {
    s0a[oo] = f2bf(fmaxf(acc0[oo] + bias[o0 + oo], 0.f));
    s0b[oo] = f2bf(fmaxf(acc0[oo + 8] + bias[o0 + oo + 8], 0.f));
    s1a[oo] = f2bf(fmaxf(acc1[oo] + bias[o0 + oo], 0.f));
    s1b[oo] = f2bf(fmaxf(acc1[oo + 8] + bias[o0 + oo + 8], 0.f));
  }
  *(short8*)(A1 + base0) = s0a;
  *(short8*)(A1 + base0 + 8) = s0b;
  *(short8*)(A1 + base1) = s1a;
  *(short8*)(A1 + base1 + 8) = s1b;
}

// ============================================================================
// conv2 MFMA v3 (LDS-staged input + async wave-local weight slabs):
// A1[130,130,64] bf16 -> relu -> Xf[64,64,128] f32 + XrP[66,66,128] bf16.
// Per K-step each wave stages its 2 KB weight slab via global_load_lds
// (lgkmcnt WAR guard, vmcnt(0) before use) -> A-latency becomes an async
// stream; B read direct from sX with absolute per-step offsets.
// grid 2048 = 32 b x 8 by x 8 bx
// ============================================================================
__global__ __launch_bounds__(256) void k_conv2m(const short* __restrict__ A1,
    const short* __restrict__ wA, const float* __restrict__ bias,
    float* __restrict__ Xf, short* __restrict__ XrP) {
  __shared__ short sX[22032];  // 324 px * 68 shorts (136 B) = 44,064 B
  __shared__ short sE[4096];   // 4 waves x 1024 shorts = 8 KB
  int blk = blockIdx.x;
  int bx = blk & 7, by = (blk >> 3) & 7, b = blk >> 6;
  int t = threadIdx.x;
  int R0 = by * 16, C0 = bx * 16;
  for (int q = t; q < 2592; q += 256) {
    int p = q >> 3, seg = q & 7;
    int iy = p / 18, ix = p - iy * 18;
    short8 v = *(const short8*)(A1 +
        (((long)b * 130 + R0 + iy) * 130 + C0 + ix) * 64 + seg * 8);
    *(short8*)((char*)sX + p * 136 + seg * 16) = v;
  }
  __syncthreads();
  int w = t >> 6, l = t & 63, lr = l & 15, g = l >> 4;
  int Bb[4];
#pragma unroll
  for (int pt = 0; pt < 4; ++pt) {
    int p = pt * 16 + lr;
    int lp = 2 * (p >> 3) * 18 + 2 * (p & 7);
    Bb[pt] = lp * 136 + g * 16;
  }
  short* sEw = sE + w * 1024;
  const short* gEw = wA + w * 1024 + l * 8;
  f32x4 acc[2][4] = {};
  for (int kc = 0; kc < 32; ++kc) {
    if (kc) asm volatile("s_waitcnt lgkmcnt(0)" ::: "memory");
    GLOAD_LDS16(gEw + kc * 4096, sEw);
    GLOAD_LDS16(gEw + kc * 4096 + 512, sEw + 512);
    asm volatile("s_waitcnt vmcnt(0)" ::: "memory");
    int tap = kc >> 1;
    int off = ((tap >> 2) * 18 + (tap & 3)) * 136 + (kc & 1) * 64;
    short8 a0 = *(const short8*)(sEw + l * 8);
    short8 a1 = *(const short8*)(sEw + 512 + l * 8);
#pragma unroll
    for (int i = 0; i < 4; ++i) {
      short8 bv = *(const short8*)((const char*)sX + Bb[i] + off);
      acc[0][i] = MFMA(a0, bv, acc[0][i]);
      acc[1][i] = MFMA(a1, bv, acc[1][i]);
    }
  }
#pragma unroll
  for (int oi = 0; oi < 2; ++oi) {
    int o0 = (2 * w + oi) * 16 + 4 * g;
#pragma unroll
    for (int pt = 0; pt < 4; ++pt) {
      int p = pt * 16 + lr;
      int y = by * 8 + (p >> 3), x = bx * 8 + (p & 7);
      f32x4 nv; short4v sv;
#pragma unroll
      for (int r = 0; r < 4; ++r) {
        float v = fmaxf(acc[oi][pt][r] + bias[o0 + r], 0.f);
        nv[r] = v; sv[r] = f2bf(v);
      }
      *(f32x4*)(Xf + ((b * 64 + y) * 64 + x) * 128 + o0) = nv;
      *(short4v*)(XrP + ((b * 66 + y + 1) * 66 + x + 1) * 128 + o0) = sv;
    }
  }
}

// ============================================================================
// resblk fused: res3 (3x3 conv, XrP -> H in LDS) + res1 (1x1 conv + residual).
// Block = 8x16 out-px (res3m tiling), grid 1024 = 32 b x 8 yt x 4 tx.
// MODE 0: write Xf + XrPout.  MODE 1: write XrPout only.  MODE 2: encoder
// tail - xr stays in LDS, then prem -> Zcat (Zc aliases Xf, barrier-ordered).
// ============================================================================
template <int MODE>
__global__ __launch_bounds__(256) void k_resblk(
    const short* __restrict__ XrPin, const short* __restrict__ wA3,
    const short* __restrict__ wA1, float* Xf, short* XrPout,
    const short* __restrict__ wAp, const float* __restrict__ preb,
    short* Zc) {
  __shared__ short sX[23040];  // phase1 XrP tile; MODE2 phase2 reuses as sXr
  __shared__ short sH[128 * 40];  // H: 128 px * 40 sh (80 B stride)
  int blk = blockIdx.x;
  int tx = blk & 3, yt = (blk >> 2) & 7, b = blk >> 5;
  int t = threadIdx.x;
  int r0 = yt * 8, c0 = tx * 16;
  for (int q = t; q < 2880; q += 256) {
    int p = q >> 4, seg = q & 15;
    int iy = p / 18, ix = p - iy * 18;
    short8 v = *(const short8*)(XrPin +
        (((long)b * 66 + r0 + iy) * 66 + c0 + ix) * 128 + seg * 8);
    *(short8*)((char*)sX + p * 256 + ((seg * 16) ^ ((p & 7) << 4))) = v;
  }
  __syncthreads();
  int w = t >> 6, l = t & 63, lr = l & 15, g = l >> 4;
  // ---- phase 1: res3 3x3 conv, H -> sH ----
  {
    const short* pA0 = wA3 + l * 8;
    const short* pA1 = pA0 + 512;
    f32x4 acc[2][2] = {};
    short8 a0 = *(const short8*)pA0;
    short8 a1 = *(const short8*)pA1;
    short8 bv[2];
#pragma unroll
    for (int j = 0; j < 2; ++j) {
      int lp = (2 * w + j) * 18 + lr;
      bv[j] = *(const short8*)((const char*)sX + lp * 256 +
                               ((g * 16) ^ ((lp & 7) << 4)));
    }
    for (int kc = 0; kc < 35; ++kc) {
      int nk = kc + 1;
      int tap = nk >> 2;
      int ky = tap / 3, kx = tap - ky * 3;
      int inner = g * 16 + (nk & 3) * 64;
      short8 na0 = *(const short8*)(pA0 + nk * 1024);
      short8 na1 = *(const short8*)(pA1 + nk * 1024);
      short8 nb[2];
#pragma unroll
      for (int j = 0; j < 2; ++j) {
        int lp = (2 * w + j + ky) * 18 + lr + kx;
        nb[j] = *(const short8*)((const char*)sX + lp * 256 +
                                 (inner ^ ((lp & 7) << 4)));
      }
#pragma unroll
      for (int j = 0; j < 2; ++j) {
        acc[0][j] = MFMA(a0, bv[j], acc[0][j]);
        acc[1][j] = MFMA(a1, bv[j], acc[1][j]);
      }
      a0 = na0; a1 = na1;
      bv[0] = nb[0]; bv[1] = nb[1];
    }
#pragma unroll
    for (int j = 0; j < 2; ++j) {
      acc[0][j] = MFMA(a0, bv[j], acc[0][j]);
      acc[1][j] = MFMA(a1, bv[j], acc[1][j]);
    }
#pragma unroll
    for (int oi = 0; oi < 2; ++oi) {
      int o0 = oi * 16 + 4 * g;
#pragma unroll
      for (int j = 0; j < 2; ++j) {
        int p = (2 * w + j) * 16 + lr;
        short4v sv;
#pragma unroll
        for (int r = 0; r < 4; ++r) sv[r] = f2bf(fmaxf(acc[oi][j][r], 0.f));
        *(short4v*)(sH + p * 40 + o0) = sv;
      }
    }
  }
  __syncthreads();
  // ---- phase 2: res1 1x1 conv + residual over 128 px ----
  {
    f32x4 acc[2][8] = {};
    short8 a0 = *(const short8*)(wA1 + (2 * w * 64 + l) * 8);
    short8 a1 = *(const short8*)(wA1 + ((2 * w + 1) * 64 + l) * 8);
#pragma unroll
    for (int pt = 0; pt < 8; ++pt) {
      short8 bv = *(const short8*)(sH + (pt * 16 + lr) * 40 + 8 * g);
      acc[0][pt] = MFMA(a0, bv, acc[0][pt]);
      acc[1][pt] = MFMA(a1, bv, acc[1][pt]);
    }
#pragma unroll
    for (int oi = 0; oi < 2; ++oi) {
      int o0 = (2 * w + oi) * 16 + 4 * g;
#pragma unroll
      for (int pt = 0; pt < 8; ++pt) {
        int y = r0 + pt, x = c0 + lr;
        float* xp = Xf + ((b * 64 + y) * 64 + x) * 128 + o0;
        f32x4 old = *(f32x4*)xp;
        f32x4 nv; short4v sv;
#pragma unroll
        for (int r = 0; r < 4; ++r) {
          nv[r] = old[r] + acc[oi][pt][r];
          sv[r] = f2bf(fmaxf(nv[r], 0.f));
        }
        if (MODE == 0) *(f32x4*)xp = nv;
        if (MODE != 2) {
          *(short4v*)(XrPout + ((b * 66 + y + 1) * 66 + x + 1) * 128 + o0) =
              sv;
        } else {
          int p = pt * 16 + lr;
          *(short4v*)((char*)sX + p * 256 + ((o0 * 2) ^ ((p & 7) << 4))) = sv;
        }
      }
    }
  }
  if (MODE == 2) {
    __syncthreads();
    // ---- phase 3: prem 1x1 conv over xr (in sX), write Zcat ----
    const short* pA0 = wAp + (2 * w * 64 + l) * 8;
    const short* pA1 = pA0 + 512;
    f32x4 acc[2][8] = {};
#pragma unroll
    for (int kc = 0; kc < 4; ++kc) {
      short8 a0 = *(const short8*)(pA0 + kc * 4096);
      short8 a1 = *(const short8*)(pA1 + kc * 4096);
#pragma unroll
      for (int pt = 0; pt < 8; ++pt) {
        int p = pt * 16 + lr;
        short8 bv = *(const short8*)((const char*)sX + p * 256 +
                                     ((kc * 64 + g * 16) ^ ((p & 7) << 4)));
        acc[0][pt] = MFMA(a0, bv, acc[0][pt]);
        acc[1][pt] = MFMA(a1, bv, acc[1][pt]);
      }
    }
#pragma unroll
    for (int oi = 0; oi < 2; ++oi) {
      int o0 = (2 * w + oi) * 16 + 4 * g;
#pragma unroll
      for (int pt = 0; pt < 8; ++pt) {
        int y = r0 + pt, x = c0 + lr;
        long pix = (long)(b * 64 + y) * 64 + x;
        short4v hv, lv;
#pragma unroll
        for (int r = 0; r < 4; ++r) {
          float v = acc[oi][pt][r] + preb[o0 + r];
          short hi = f2bf(v);
          hv[r] = hi;
          lv[r] = f2bf(v - bf2f(hi));
        }
        *(short4v*)(Zc + pix * 256 + o0) = hv;
        *(short4v*)(Zc + pix * 256 + 128 + o0) = lv;
      }
    }
  }
}

// ============================================================================
// VQ MFMA v9 (async E-staging, 128 px): 128 px x 512 codes, 8 waves (512 thr),
// grid 1024. Wave w owns 64 codes -> acc[4][8] = 128 AGPR; A operands via
// global_load_lds slab. Z tile 64 KB LDS (XOR swizzle). Fused argmin + hist +
// loss + gather.
// ============================================================================
__global__ __launch_bounds__(512) void k_vqm9(const short* __restrict__ Zc,
    const short* __restrict__ Ec, const float* __restrict__ en,
    const float* __restrict__ emb, int* __restrict__ counts,
    float* __restrict__ partials, float* __restrict__ Q,
    short* __restrict__ QrP) {
  __shared__ short sZ[32768];  // 128 px * 256 sh, swizzled = 64 KB
  __shared__ short sE[16384];  // E slab: 8 wave-regions x 2048 sh = 32 KB
  __shared__ float sV[8][128];
  __shared__ int sC[8][128];
  __shared__ float sZn[128];
  __shared__ int sIdx[128];
  __shared__ int sHist[KC];
  int blk = blockIdx.x;
  long pix0 = (long)blk * 128;
  int t = threadIdx.x, w = t >> 6, l = t & 63, c16 = l & 15, g = (l >> 4) & 3;
  for (int e = t; e < KC; e += 512) sHist[e] = 0;

  // stage Z tile: swizzle inner-byte ^ ((pix&7)<<4)
  for (int q = t; q < 4096; q += 512) {
    int p = q >> 5, seg = q & 31;
    short8 v = *(const short8*)(Zc + (pix0 + p) * 256 + seg * 8);
    *(short8*)((char*)sZ + p * 512 + ((seg * 16) ^ ((p & 7) << 4))) = v;
  }
  __syncthreads();

  // ||z||^2 per pixel from LDS: 4 threads/pixel, each 32 dims (128 px)
  {
    int pz = t >> 2, seg4 = t & 3;
    const char* zb = (const char*)sZ + pz * 512;
    int swp = (pz & 7) << 4;
    float s = 0.f;
#pragma unroll
    for (int qq = 0; qq < 4; ++qq) {
      int ih = seg4 * 64 + 16 * qq;  // zh inner byte
      short8 h8 = *(const short8*)(zb + (ih ^ swp));
      short8 l8 = *(const short8*)(zb + ((ih + 256) ^ swp));
#pragma unroll
      for (int j = 0; j < 8; ++j) {
        float zv = bf2f(h8[j]) + bf2f(l8[j]);
        s = fmaf(zv, zv, s);
      }
    }
    s += __shfl_xor(s, 1);
    s += __shfl_xor(s, 2);
    if (seg4 == 0) sZn[pz] = s;
  }

  // GEMM: 12 K-steps of 32; wave-local async E staging; 8 pixel-tiles.
  int sw = (c16 & 7) << 4;
  int zrow = c16 * 512;
  short* sEw = sE + w * 2048;                   // wave-uniform LDS base
  const short* gEw = Ec + w * 2048 + l * 8;     // per-lane global src
  f32x4 acc[4][8] = {};
  for (int kc = 0; kc < 12; ++kc) {
    if (kc) asm volatile("s_waitcnt lgkmcnt(0)" ::: "memory");
#pragma unroll
    for (int i = 0; i < 4; ++i)
      GLOAD_LDS16(gEw + kc * 16384 + i * 512, sEw + i * 512);
    asm volatile("s_waitcnt vmcnt(0)" ::: "memory");
    int koff = kc < 8 ? kc : kc - 8;
    int inn = ((koff * 64 + g * 16) ^ sw);
    const char* zb = (const char*)sZ + zrow + inn;
    short8 a0 = *(const short8*)(sEw + l * 8);
    short8 a1 = *(const short8*)(sEw + 512 + l * 8);
    short8 a2 = *(const short8*)(sEw + 1024 + l * 8);
    short8 a3 = *(const short8*)(sEw + 1536 + l * 8);
#pragma unroll
    for (int pt = 0; pt < 8; ++pt) {
      short8 bb = *(const short8*)(zb + pt * 8192);
      acc[0][pt] = MFMA(a0, bb, acc[0][pt]);
      acc[1][pt] = MFMA(a1, bb, acc[1][pt]);
      acc[2][pt] = MFMA(a2, bb, acc[2][pt]);
      acc[3][pt] = MFMA(a3, bb, acc[3][pt]);
    }
  }
  // running argmin over the wave's 64 codes (codes ascend: ct, r)
  float bvv[8];
  int bcc[8];
#pragma unroll
  for (int pt = 0; pt < 8; ++pt) { bvv[pt] = 3.4e38f; bcc[pt] = 0; }
#pragma unroll
  for (int ct = 0; ct < 4; ++ct) {
    f32x4 en4 = *(const f32x4*)(en + w * 64 + ct * 16 + 4 * g);
#pragma unroll
    for (int pt = 0; pt < 8; ++pt) {
#pragma unroll
      for (int r = 0; r < 4; ++r) {
        float d = en4[r] - 2.f * acc[ct][pt][r];
        int code = w * 64 + ct * 16 + 4 * g + r;
        if (d < bvv[pt]) { bvv[pt] = d; bcc[pt] = code; }
      }
    }
  }
  // cross-lane reduce (over g) per pixel
#pragma unroll
  for (int pt = 0; pt < 8; ++pt) {
    float bv = bvv[pt];
    int bc = bcc[pt];
#pragma unroll
    for (int m = 16; m <= 32; m <<= 1) {
      float ov = __shfl_xor(bv, m);
      int oc = __shfl_xor(bc, m);
      if (ov < bv || (ov == bv && oc < bc)) { bv = ov; bc = oc; }
    }
    if (g == 0) {
      sV[w][pt * 16 + c16] = bv;
      sC[w][pt * 16 + c16] = bc;
    }
  }
  __syncthreads();
  if (t < 128) {
    float bv = sV[0][t];
    int bc = sC[0][t];
#pragma unroll
    for (int w2 = 1; w2 < 8; ++w2) {
      float v = sV[w2][t];
      int c = sC[w2][t];
      if (v < bv || (v == bv && c < bc)) { bv = v; bc = c; }
    }
    sIdx[t] = bc;
    atomicAdd(&sHist[bc], 1);
    sV[0][t] = bv + sZn[t];
  }
  __syncthreads();
  if (t < 64) {
    float ls = sV[0][t] + sV[0][t + 64];
#pragma unroll
    for (int m = 32; m >= 1; m >>= 1) ls += __shfl_xor(ls, m);
    if (t == 0) partials[blk] = ls;
  }
  for (int e = t; e < KC; e += 512) {
    int c = sHist[e];
    if (c) atomicAdd(&counts[e], c);
  }
  // fused gather: Q = emb[idx] f32 (overwrites this block's Zc bytes),
  // QrP = relu bf16 (padded layout)
  for (int e = t; e < 4096; e += 512) {
    int p = e >> 5, d4 = (e & 31) << 2;
    int c = sIdx[p];
    f32x4 q = *(const f32x4*)(emb + c * DD + d4);
    *(f32x4*)(Q + (pix0 + p) * DD + d4) = q;
    short4v sv;
#pragma unroll
    for (int r = 0; r < 4; ++r) sv[r] = f2bf(fmaxf(q[r], 0.f));
    long pixg = pix0 + p;
    int xx = (int)(pixg & 63), yy = (int)((pixg >> 6) & 63),
        bb = (int)(pixg >> 12);
    *(short4v*)(QrP + (((long)(bb * 66 + yy + 1)) * 66 + xx + 1) * 128 + d4) =
        sv;
  }
}

// ============================================================================
// tconv1 MFMA v3 (LDS input + async wave-local weight slabs):
// QrP[66,66,128] -> T1[130,130,64] bf16 relu. Per K-step each wave stages
// its 4 KB weight slab via global_load_lds; B read direct from sX with
// absolute per-step offsets (no register prefetch arrays -> lower VGPR).
// grid 2048 = 32 b x 8 tyt x 8 txt
// ============================================================================
__global__ __launch_bounds__(256) void k_tconv1m(const short* __restrict__ QrP,
    const short* __restrict__ wA, const float* __restrict__ bias,
    short* __restrict__ T1) {
  __shared__ short sX[13600];  // 100 pixels x 136 shorts
  __shared__ short sE[8192];   // 4 waves x 2048 shorts = 16 KB
  int blk = blockIdx.x;
  int txt = blk & 7, tyt = (blk >> 3) & 7, b = blk >> 6;
  int my0 = tyt * 8, mx0 = txt * 8;
  int t = threadIdx.x;
  for (int q = t; q < 1600; q += 256) {
    int p = q >> 4, seg = q & 15;
    int iy = p / 10, ix = p - iy * 10;
    short8 v = *(const short8*)(QrP +
        ((b * 66 + my0 + iy) * 66 + mx0 + ix) * 128 + seg * 8);
    *(short8*)((char*)sX + p * 272 + seg * 16) = v;
  }
  __syncthreads();
  int w = t >> 6, l = t & 63, lr = l & 15, g = l >> 4;
  int pyr = w >> 1, pxr = w & 1;
  int Bb[4];
#pragma unroll
  for (int nt = 0; nt < 4; ++nt) {
    int p = nt * 16 + lr;
    int my = p >> 3, mx = p & 7;
    Bb[nt] = ((my + pyr + 1) * 10 + (mx + pxr + 1)) * 272 + g * 16;
  }
  short* sEw = sE + w * 2048;
  const short* gEw = wA + w * 32768 + l * 8;
  f32x4 acc[4][4] = {};
  for (int kc = 0; kc < 16; ++kc) {
    if (kc) asm volatile("s_waitcnt lgkmcnt(0)" ::: "memory");
#pragma unroll
    for (int i = 0; i < 4; ++i)
      GLOAD_LDS16(gEw + kc * 2048 + i * 512, sEw + i * 512);
    asm volatile("s_waitcnt vmcnt(0)" ::: "memory");
    int tt = kc >> 2, dy = tt >> 1, dx = tt & 1;
    int off = -(dy * 10 + dx) * 272 + (kc & 3) * 64;
    short8 a0 = *(const short8*)(sEw + l * 8);
    short8 a1 = *(const short8*)(sEw + 512 + l * 8);
    short8 a2 = *(const short8*)(sEw + 1024 + l * 8);
    short8 a3 = *(const short8*)(sEw + 1536 + l * 8);
#pragma unroll
    for (int nt = 0; nt < 4; ++nt) {
      short8 bv = *(const short8*)((const char*)sX + Bb[nt] + off);
      acc[0][nt] = MFMA(a0, bv, acc[0][nt]);
      acc[1][nt] = MFMA(a1, bv, acc[1][nt]);
      acc[2][nt] = MFMA(a2, bv, acc[2][nt]);
      acc[3][nt] = MFMA(a3, bv, acc[3][nt]);
    }
  }
#pragma unroll
  for (int ot = 0; ot < 4; ++ot) {
    int o0 = ot * 16 + 4 * g;
    f32x4 b4 = *(const f32x4*)(bias + o0);
#pragma unroll
    for (int nt = 0; nt < 4; ++nt) {
      int p = nt * 16 + lr;
      int my = my0 + (p >> 3), mx = mx0 + (p & 7);
      int oy = 2 * my + pyr, ox = 2 * mx + pxr;
      short4v sv;
#pragma unroll
      for (int r = 0; r < 4; ++r)
        sv[r] = f2bf(fmaxf(acc[ot][nt][r] + b4[r], 0.f));
      *(short4v*)(T1 + ((b * 130 + oy + 1) * 130 + ox + 1) * 64 + o0) = sv;
    }
  }
}

// ============================================================================
// tconv2 MFMA v2: T1[130,130,64] bf16 -> x_recon[32,256,256] f32.
// c[tap][px] = W^T * T1 via MFMA (16 taps x 112 px, K=128 [w_hi|w_lo]),
// then 4-entry LDS gather per output. grid 8192 = 32 b x 16 ty x 16 tx.
// ============================================================================
__global__ __launch_bounds__(256) void k_tconv2m(const short* __restrict__ T1,
    const float* __restrict__ w, const float* __restrict__ bias,
    float* __restrict__ xrec) {
  __shared__ short sT[112 * 72];  // 112 px * 144 B = 16,128 B
  __shared__ float sW[1024];
  __shared__ float sC[112 * 20];  // px stride 80 B (16-B aligned) = 8,960 B
  int blk = blockIdx.x;
  int tx = blk & 15, ty = (blk >> 4) & 15, b = blk >> 8;
  int t = threadIdx.x;
  for (int e = t; e < 1024; e += 256) sW[e] = w[e];
  for (int q = t; q < 800; q += 256) {
    int p = q >> 3, seg = q & 7;
    int iy = p / 10, ix = p - iy * 10;
    short8 v = *(const short8*)(T1 +
        (((long)b * 130 + ty * 8 + iy) * 130 + tx * 8 + ix) * 64 + seg * 8);
    *(short8*)((char*)sT + p * 144 + seg * 16) = v;
  }
  __syncthreads();
  int wv = t >> 6, l = t & 63, lr = l & 15, g = l >> 4;
  short8 af[4];
#pragma unroll
  for (int kc = 0; kc < 4; ++kc) {
#pragma unroll
    for (int j = 0; j < 8; ++j) {
      int k = kc * 32 + 8 * g + j;
      float val = sW[(k & 63) * 16 + lr];
      short hi = f2bf(val);
      af[kc][j] = (k < 64) ? hi : f2bf(val - bf2f(hi));
    }
  }
#pragma unroll
  for (int ti = 0; ti < 2; ++ti) {
    int tile = wv + 4 * ti;
    if (tile < 7) {
      f32x4 acc = {};
#pragma unroll
      for (int kc = 0; kc < 4; ++kc) {
        short8 bf = *(const short8*)((const char*)sT +
            (tile * 16 + lr) * 144 + ((kc & 1) * 64 + g * 16));
        acc = MFMA(af[kc], bf, acc);
      }
      *(f32x4*)(sC + (tile * 16 + lr) * 20 + g * 4) = acc;
    }
  }
  __syncthreads();
  int row = t >> 4, col = t & 15;
  int pyr = row & 1, pxr = col & 1;
  int ml = row >> 1, nl = col >> 1;
  int kye = 1 - pyr, kxe = 1 - pxr;
  float acc = bias[0];
#pragma unroll
  for (int dy = 0; dy < 2; ++dy)
#pragma unroll
    for (int dx = 0; dx < 2; ++dx) {
      int px = (ml + pyr - dy + 1) * 10 + (nl + pxr - dx + 1);
      int tap = (kye + 2 * dy) * 4 + (kxe + 2 * dx);
      acc += sC[px * 20 + tap];
    }
  int oy = ty * 16 + row, ox = tx * 16 + col;
  xrec[((long)b * 256 + oy) * 256 + ox] = acc;
}

// ============================================================================
// finalize: loss from 1024 partials; perplexity from counts
// ============================================================================
__global__ __launch_bounds__(256) void k_final(const float* __restrict__ partials,
    const int* __restrict__ counts, float* __restrict__ out) {
  int t = threadIdx.x;
  float s = 0.f;
  for (int i = t; i < 1024; i += 256) s += partials[i];
#pragma unroll
  for (int m = 32; m >= 1; m >>= 1) s += __shfl_xor(s, m);
  __shared__ float sr[4];
  if ((t & 63) == 0) sr[t >> 6] = s;
  __syncthreads();
  if (t == 0) {
    float tot = sr[0] + sr[1] + sr[2] + sr[3];
    out[0] = 1.25f * tot / 16777216.0f;
  }
  float h = 0.f;
  for (int c = t; c < KC; c += 256) {
    float avg = (float)counts[c] / 131072.0f;
    h += avg * logf(avg + 1e-10f);
  }
#pragma unroll
  for (int m = 32; m >= 1; m >>= 1) h += __shfl_xor(h, m);
  __shared__ float sr2[4];
  if ((t & 63) == 0) sr2[t >> 6] = h;
  __syncthreads();
  if (t == 0) out[1 + 32 * 256 * 256] = expf(-(sr2[0] + sr2[1] + sr2[2] + sr2[3]));
}

// ============================================================================
extern "C" void kernel_launch(void* const* d_in, const int* in_sizes, int n_in,
                              void* d_out, int out_size, void* d_ws, size_t ws_size,
                              hipStream_t stream) {
  const float* x    = (const float*)d_in[0];
  const float* c1w  = (const float*)d_in[1];
  const float* c1b  = (const float*)d_in[2];
  const float* c2w  = (const float*)d_in[3];
  const float* c2b  = (const float*)d_in[4];
  const float* r1w3 = (const float*)d_in[5];
  const float* r1w1 = (const float*)d_in[6];
  const float* r2w3 = (const float*)d_in[7];
  const float* r2w1 = (const float*)d_in[8];
  const float* prew = (const float*)d_in[9];
  const float* preb = (const float*)d_in[10];
  const float* emb  = (const float*)d_in[11];
  const float* d1w3 = (const float*)d_in[12];
  const float* d1w1 = (const float*)d_in[13];
  const float* d2w3 = (const float*)d_in[14];
  const float* d2w1 = (const float*)d_in[15];
  const float* t1w  = (const float*)d_in[16];
  const float* t1b  = (const float*)d_in[17];
  const float* t2w  = (const float*)d_in[18];
  const float* t2b  = (const float*)d_in[19];
  float* out = (float*)d_out;

  char* ws = (char*)d_ws;
  short* buf0 = (short*)(ws);                      // A1 / T1 : 69,222,400 B
  float* bufX = (float*)(ws + 69222400);           // Xf / Zcat / Q : 67,108,864 B
  short* bufR = (short*)(ws + 136331264);          // XrP / QrP : 35,684,352 B
  int*   counts = (int*)(ws + 180928512);          // 2,048 B
  float* partials = (float*)(ws + 180930560);      // 8,192 B
  float* en   = (float*)(ws + 180938752);          // 2,048 B
  short* wAc2 = (short*)(ws + 180940800);          // 262,144 B
  short* wAr3 = (short*)(ws + 181202944);          // 294,912 B
  short* wAr1 = (short*)(ws + 181497856);          // 32,768 B
  short* wApre= (short*)(ws + 181530624);          // 32,768 B
  short* wAt1 = (short*)(ws + 181563392);          // 262,144 B
  short* Ecat = (short*)(ws + 181825536);          // 393,216 B -> ends 182,218,752

  short* Zcat = (short*)bufX;  // Zcat aliases Xf (k_resblk<2> reads Xf,
                               // writes the same bytes after a barrier)

  short* wAr3_e1 = wAr3;
  short* wAr3_e2 = wAr3 + 36864;
  short* wAr3_d1 = wAr3 + 2 * 36864;
  short* wAr3_d2 = wAr3 + 3 * 36864;
  short* wAr1_e1 = wAr1;
  short* wAr1_e2 = wAr1 + 4096;
  short* wAr1_d1 = wAr1 + 2 * 4096;
  short* wAr1_d2 = wAr1 + 3 * 4096;

  k_prep <<<2881, 256, 0, stream>>>(c2w, r1w3, r2w3, d1w3, d2w3,
                                    r1w1, r2w1, d1w1, d2w1, prew, t1w, emb,
                                    wAc2, wAr3, wAr1, wApre, wAt1, Ecat,
                                    en, buf0, bufR, counts);

  k_conv1     <<<4096, 256, 0, stream>>>(x, c1w, c1b, buf0);
  k_conv2m    <<<2048, 256, 0, stream>>>(buf0, wAc2, c2b, bufX, bufR);
  k_resblk<0> <<<1024, 256, 0, stream>>>(bufR, wAr3_e1, wAr1_e1, bufX, bufR,
                                         nullptr, nullptr, nullptr);
  k_resblk<2> <<<1024, 256, 0, stream>>>(bufR, wAr3_e2, wAr1_e2, bufX, nullptr,
                                         wApre, preb, Zcat);
  k_vqm9      <<<1024, 512, 0, stream>>>(Zcat, Ecat, en, emb, counts,
                                         partials, bufX, bufR);
  k_resblk<0> <<<1024, 256, 0, stream>>>(bufR, wAr3_d1, wAr1_d1, bufX, bufR,
                                         nullptr, nullptr, nullptr);
  k_resblk<1> <<<1024, 256, 0, stream>>>(bufR, wAr3_d2, wAr1_d2, bufX, bufR,
                                         nullptr, nullptr, nullptr);
  k_tconv1m   <<<2048, 256, 0, stream>>>(bufR, wAt1, t1b, buf0);
  k_tconv2m   <<<8192, 256, 0, stream>>>(buf0, t2w, t2b, out + 1);
  k_final     <<<1, 256, 0, stream>>>(partials, counts, out);
}

// Round 16
// 495.277 us; speedup vs baseline: 1.0537x; 1.0537x over previous
//
#include <hip/hip_runtime.h>
#include <math.h>

#define KC 512
#define DD 128

typedef __attribute__((ext_vector_type(8))) short short8;
typedef __attribute__((ext_vector_type(4))) short short4v;
typedef __attribute__((ext_vector_type(4))) float f32x4;

#define MFMA(a, b, c) __builtin_amdgcn_mfma_f32_16x16x32_bf16(a, b, c, 0, 0, 0)

#define GLOAD_LDS16(g, l)                                        \
  __builtin_amdgcn_global_load_lds(                              \
      (const __attribute__((address_space(1))) void*)(g),        \
      (__attribute__((address_space(3))) void*)(l), 16, 0, 0)

__device__ __forceinline__ short f2bf(float f) {
  unsigned u = __float_as_uint(f);
  u = (u + 0x7FFFu + ((u >> 16) & 1u)) >> 16;
  return (short)u;
}
__device__ __forceinline__ float bf2f(short s) {
  return __uint_as_float(((unsigned)(unsigned short)s) << 16);
}

// ============================================================================
// k_prep: ALL weight permutations + embnorm + border-zero + counts-zero in
// ONE dispatch. grid 2881 x 256
// ============================================================================
__global__ __launch_bounds__(256) void k_prep(
    const float* __restrict__ c2w,
    const float* __restrict__ r1w3, const float* __restrict__ r2w3,
    const float* __restrict__ d1w3, const float* __restrict__ d2w3,
    const float* __restrict__ r1w1, const float* __restrict__ r2w1,
    const float* __restrict__ d1w1, const float* __restrict__ d2w1,
    const float* __restrict__ prew, const float* __restrict__ t1w,
    const float* __restrict__ emb,
    short* __restrict__ wAc2, short* __restrict__ wAr3,
    short* __restrict__ wAr1, short* __restrict__ wApre,
    short* __restrict__ wAt1, short* __restrict__ Ecat,
    float* __restrict__ en, short* __restrict__ A1,
    short* __restrict__ XrP, int* __restrict__ counts) {
  int blk = blockIdx.x, t = threadIdx.x;
  if (blk < 512) {  // perm_c2
    int e = blk * 256 + t;
    int j = e & 7, l = (e >> 3) & 63, ot = (e >> 9) & 7, kc = e >> 12;
    int o = ot * 16 + (l & 15), g = l >> 4;
    int tap = kc >> 1, ci = (kc & 1) * 32 + 8 * g + j;
    wAc2[e] = f2bf(c2w[(o * 64 + ci) * 16 + tap]);
  } else if (blk < 1088) {  // perm_r3 x4
    int sub = blk - 512;
    int which = sub / 144, bb = sub - which * 144;
    const float* w = which == 0 ? r1w3 : which == 1 ? r2w3
                     : which == 2 ? d1w3 : d2w3;
    short* dst = wAr3 + which * 36864;
    int e = bb * 256 + t;
    int j = e & 7, l = (e >> 3) & 63, ot = (e >> 9) & 1, kc = e >> 10;
    int o = ot * 16 + (l & 15), g = l >> 4;
    int tap = kc >> 2, ci = (kc & 3) * 32 + 8 * g + j;
    dst[e] = f2bf(w[(o * 128 + ci) * 9 + tap]);
  } else if (blk < 1152) {  // perm_r1 x4
    int sub = blk - 1088;
    int which = sub >> 4, bb = sub & 15;
    const float* w = which == 0 ? r1w1 : which == 1 ? r2w1
                     : which == 2 ? d1w1 : d2w1;
    short* dst = wAr1 + which * 4096;
    int e = bb * 256 + t;
    int j = e & 7, l = (e >> 3) & 63, ot = e >> 9;
    int o = ot * 16 + (l & 15), g = l >> 4;
    int ci = 8 * g + j;
    dst[e] = f2bf(w[o * 32 + ci]);
  } else if (blk < 1216) {  // perm_pre
    int e = (blk - 1152) * 256 + t;
    int j = e & 7, l = (e >> 3) & 63, ot = (e >> 9) & 7, kc = e >> 12;
    int o = ot * 16 + (l & 15), g = l >> 4;
    int ci = kc * 32 + 8 * g + j;
    wApre[e] = f2bf(prew[o * 128 + ci]);
  } else if (blk < 1728) {  // perm_t1
    int e = (blk - 1216) * 256 + t;
    int j = e & 7, l = (e >> 3) & 63, ot = (e >> 9) & 3, kc = (e >> 11) & 15,
        pp = e >> 15;
    int pyr = pp >> 1, pxr = pp & 1;
    int o = ot * 16 + (l & 15), g = l >> 4;
    int tt = kc >> 2, dy = tt >> 1, dx = tt & 1;
    int ky = (1 - pyr) + 2 * dy, kx = (1 - pxr) + 2 * dx;
    int ci = (kc & 3) * 32 + 8 * g + j;
    wAt1[e] = f2bf(t1w[(ci * 64 + o) * 16 + ky * 4 + kx]);
  } else if (blk < 2496) {  // perm_E
    int e = (blk - 1728) * 256 + t;
    int j = e & 7, l = (e >> 3) & 63, ot = (e >> 9) & 31, kc = e >> 14;
    int c = ot * 16 + (l & 15);
    int k = kc * 32 + 8 * (l >> 4) + j;
    float v = emb[c * DD + (k & 127)];
    short hi = f2bf(v);
    Ecat[e] = (k < 256) ? hi : f2bf(v - bf2f(hi));
  } else if (blk < 2624) {  // embnorm: 4 codes per block (wave = code)
    int c = (blk - 2496) * 4 + (t >> 6), l = t & 63;
    float a = emb[c * DD + l], b2 = emb[c * DD + 64 + l];
    float s = a * a + b2 * b2;
#pragma unroll
    for (int m = 32; m >= 1; m >>= 1) s += __shfl_xor(s, m);
    if (l == 0) en[c] = s;
  } else if (blk < 2880) {  // border zero
    int bb = blk - 2624;
    int b = bb >> 3;
    int tid = ((bb & 7) << 8) + t;  // 0..2047
    short8 z8 = {};
    long baseA = (long)b * 1081600;  // 130*130*64
    for (int e = tid; e < 2080; e += 2048) {
      int r = e >= 1040;
      int rem = r ? e - 1040 : e;
      *(short8*)(A1 + baseA + (r ? 129L * 130 * 64 : 0) + rem * 8) = z8;
    }
    {
      int c = tid >> 10, rem = tid & 1023;
      int row = 1 + (rem >> 3), s8 = rem & 7;
      *(short8*)(A1 + baseA + (row * 130L + (c ? 129 : 0)) * 64 + s8 * 8) = z8;
    }
    long baseX = (long)b * 557568;  // 66*66*128
    for (int e = tid; e < 2112; e += 2048) {
      int r = e >= 1056;
      int rem = r ? e - 1056 : e;
      *(short8*)(XrP + baseX + (r ? 65L * 66 * 128 : 0) + rem * 8) = z8;
    }
    {
      int c = tid >> 10, rem = tid & 1023;
      int row = 1 + (rem >> 4), s8 = rem & 15;
      *(short8*)(XrP + baseX + (row * 66L + (c ? 65 : 0)) * 128 + s8 * 8) = z8;
    }
  } else {  // counts zero
    counts[t] = 0;
    counts[t + 256] = 0;
  }
}

// ============================================================================
// conv1: x[32,1,256,256] f32 -> A1[32,130,130,64] bf16 relu (padded, ch-last)
// grid 4096 = 32 b x 128 y
// ============================================================================
__global__ __launch_bounds__(256) void k_conv1(const float* __restrict__ x,
    const float* __restrict__ w, const float* __restrict__ bias,
    short* __restrict__ A1) {
  __shared__ float sXp[4 * 260];
  __shared__ float sWt[16 * 64];
  int blk = blockIdx.x;
  int y = blk & 127, b = blk >> 7;
  int t = threadIdx.x;
  for (int e = t; e < 1024; e += 256) sWt[e] = w[(e & 63) * 16 + (e >> 6)];
  if (t < 4) {
    sXp[t * 260] = 0.f;
    sXp[t * 260 + 257] = 0.f;
    sXp[t * 260 + 258] = 0.f;
    sXp[t * 260 + 259] = 0.f;
  }
  for (int e = t; e < 1024; e += 256) {
    int r = e >> 8, col = e & 255;
    int giy = 2 * y - 1 + r;
    float v = 0.f;
    if ((unsigned)giy < 256u) v = x[(b * 256 + giy) * 256 + col];
    sXp[r * 260 + col + 1] = v;
  }
  __syncthreads();
  int og = t >> 6, l = t & 63, o0 = og * 16;
  float acc0[16], acc1[16];
#pragma unroll
  for (int oo = 0; oo < 16; ++oo) { acc0[oo] = 0.f; acc1[oo] = 0.f; }
  int xA = 2 * l, xB = 2 * l + 128;
#pragma unroll
  for (int ky = 0; ky < 4; ++ky) {
#pragma unroll
    for (int kx = 0; kx < 4; ++kx) {
      float a0 = sXp[ky * 260 + xA + kx];
      float a1 = sXp[ky * 260 + xB + kx];
      const float* wrow = &sWt[(ky * 4 + kx) * 64 + o0];
#pragma unroll
      for (int oo = 0; oo < 16; ++oo) {
        float wv = wrow[oo];
        acc0[oo] = fmaf(a0, wv, acc0[oo]);
        acc1[oo] = fmaf(a1, wv, acc1[oo]);
      }
    }
  }
  long base0 = (((long)(b * 130 + y + 1)) * 130 + l + 1) * 64 + o0;
  long base1 = base0 + 64 * 64;
  short8 s0a, s0b, s1a, s1b;
#pragma unroll
  for (int oo = 0; oo < 8; ++oo) {
    s0a[oo] = f2bf(fmaxf(acc0[oo] + bias[o0 + oo], 0.f));
    s0b[oo] = f2bf(fmaxf(acc0[oo + 8] + bias[o0 + oo + 8], 0.f));
    s1a[oo] = f2bf(fmaxf(acc1[oo] + bias[o0 + oo], 0.f));
    s1b[oo] = f2bf(fmaxf(acc1[oo + 8] + bias[o0 + oo + 8], 0.f));
  }
  *(short8*)(A1 + base0) = s0a;
  *(short8*)(A1 + base0 + 8) = s0b;
  *(short8*)(A1 + base1) = s1a;
  *(short8*)(A1 + base1 + 8) = s1b;
}

// ============================================================================
// conv2 MFMA v2 (LDS-staged input, register depth-1 weight prefetch):
// A1[130,130,64] bf16 -> relu -> Xf[64,64,128] f32 + XrP[66,66,128] bf16.
// (Async slab variant regressed: 8 MFMA/step cannot cover a vmcnt(0) L2
// round-trip; register prefetch lets the compiler pipeline the whole K-loop.)
// grid 2048 = 32 b x 8 by x 8 bx
// ============================================================================
__global__ __launch_bounds__(256) void k_conv2m(const short* __restrict__ A1,
    const short* __restrict__ wA, const float* __restrict__ bias,
    float* __restrict__ Xf, short* __restrict__ XrP) {
  __shared__ short sX[22032];  // 324 px * 68 shorts (136 B) = 44,064 B
  int blk = blockIdx.x;
  int bx = blk & 7, by = (blk >> 3) & 7, b = blk >> 6;
  int t = threadIdx.x;
  int R0 = by * 16, C0 = bx * 16;
  for (int q = t; q < 2592; q += 256) {
    int p = q >> 3, seg = q & 7;
    int iy = p / 18, ix = p - iy * 18;
    short8 v = *(const short8*)(A1 +
        (((long)b * 130 + R0 + iy) * 130 + C0 + ix) * 64 + seg * 8);
    *(short8*)((char*)sX + p * 136 + seg * 16) = v;
  }
  __syncthreads();
  int w = t >> 6, l = t & 63, lr = l & 15, g = l >> 4;
  int Bb[4];
#pragma unroll
  for (int pt = 0; pt < 4; ++pt) {
    int p = pt * 16 + lr;
    int lp = 2 * (p >> 3) * 18 + 2 * (p & 7);
    Bb[pt] = lp * 136 + g * 16;
  }
  const short* pA0 = wA + (2 * w * 64 + l) * 8;
  const short* pA1 = pA0 + 512;
  f32x4 acc[2][4] = {};
  short8 a0 = *(const short8*)pA0;
  short8 a1 = *(const short8*)pA1;
  short8 bv[4];
#pragma unroll
  for (int i = 0; i < 4; ++i)
    bv[i] = *(const short8*)((const char*)sX + Bb[i]);
  for (int kc = 0; kc < 31; ++kc) {
    int nk = kc + 1;
    int tap = nk >> 1;
    int off = ((tap >> 2) * 18 + (tap & 3)) * 136 + (nk & 1) * 64;
    short8 na0 = *(const short8*)(pA0 + nk * 4096);
    short8 na1 = *(const short8*)(pA1 + nk * 4096);
    short8 nb[4];
#pragma unroll
    for (int i = 0; i < 4; ++i)
      nb[i] = *(const short8*)((const char*)sX + Bb[i] + off);
#pragma unroll
    for (int i = 0; i < 4; ++i) {
      acc[0][i] = MFMA(a0, bv[i], acc[0][i]);
      acc[1][i] = MFMA(a1, bv[i], acc[1][i]);
    }
    a0 = na0; a1 = na1;
#pragma unroll
    for (int i = 0; i < 4; ++i) bv[i] = nb[i];
  }
#pragma unroll
  for (int i = 0; i < 4; ++i) {
    acc[0][i] = MFMA(a0, bv[i], acc[0][i]);
    acc[1][i] = MFMA(a1, bv[i], acc[1][i]);
  }
#pragma unroll
  for (int oi = 0; oi < 2; ++oi) {
    int o0 = (2 * w + oi) * 16 + 4 * g;
#pragma unroll
    for (int pt = 0; pt < 4; ++pt) {
      int p = pt * 16 + lr;
      int y = by * 8 + (p >> 3), x = bx * 8 + (p & 7);
      f32x4 nv; short4v sv;
#pragma unroll
      for (int r = 0; r < 4; ++r) {
        float v = fmaxf(acc[oi][pt][r] + bias[o0 + r], 0.f);
        nv[r] = v; sv[r] = f2bf(v);
      }
      *(f32x4*)(Xf + ((b * 64 + y) * 64 + x) * 128 + o0) = nv;
      *(short4v*)(XrP + ((b * 66 + y + 1) * 66 + x + 1) * 128 + o0) = sv;
    }
  }
}

// ============================================================================
// resblk fused: res3 (3x3 conv, XrP -> H in LDS) + res1 (1x1 conv + residual).
// Block = 8x16 out-px (res3m tiling), grid 1024 = 32 b x 8 yt x 4 tx.
// MODE 0: write Xf + XrPout.  MODE 1: write XrPout only.  MODE 2: encoder
// tail - xr stays in LDS, then prem -> Zcat (Zc aliases Xf, barrier-ordered).
// ============================================================================
template <int MODE>
__global__ __launch_bounds__(256) void k_resblk(
    const short* __restrict__ XrPin, const short* __restrict__ wA3,
    const short* __restrict__ wA1, float* Xf, short* XrPout,
    const short* __restrict__ wAp, const float* __restrict__ preb,
    short* Zc) {
  __shared__ short sX[23040];  // phase1 XrP tile; MODE2 phase2 reuses as sXr
  __shared__ short sH[128 * 40];  // H: 128 px * 40 sh (80 B stride)
  int blk = blockIdx.x;
  int tx = blk & 3, yt = (blk >> 2) & 7, b = blk >> 5;
  int t = threadIdx.x;
  int r0 = yt * 8, c0 = tx * 16;
  for (int q = t; q < 2880; q += 256) {
    int p = q >> 4, seg = q & 15;
    int iy = p / 18, ix = p - iy * 18;
    short8 v = *(const short8*)(XrPin +
        (((long)b * 66 + r0 + iy) * 66 + c0 + ix) * 128 + seg * 8);
    *(short8*)((char*)sX + p * 256 + ((seg * 16) ^ ((p & 7) << 4))) = v;
  }
  __syncthreads();
  int w = t >> 6, l = t & 63, lr = l & 15, g = l >> 4;
  // ---- phase 1: res3 3x3 conv, H -> sH ----
  {
    const short* pA0 = wA3 + l * 8;
    const short* pA1 = pA0 + 512;
    f32x4 acc[2][2] = {};
    short8 a0 = *(const short8*)pA0;
    short8 a1 = *(const short8*)pA1;
    short8 bv[2];
#pragma unroll
    for (int j = 0; j < 2; ++j) {
      int lp = (2 * w + j) * 18 + lr;
      bv[j] = *(const short8*)((const char*)sX + lp * 256 +
                               ((g * 16) ^ ((lp & 7) << 4)));
    }
    for (int kc = 0; kc < 35; ++kc) {
      int nk = kc + 1;
      int tap = nk >> 2;
      int ky = tap / 3, kx = tap - ky * 3;
      int inner = g * 16 + (nk & 3) * 64;
      short8 na0 = *(const short8*)(pA0 + nk * 1024);
      short8 na1 = *(const short8*)(pA1 + nk * 1024);
      short8 nb[2];
#pragma unroll
      for (int j = 0; j < 2; ++j) {
        int lp = (2 * w + j + ky) * 18 + lr + kx;
        nb[j] = *(const short8*)((const char*)sX + lp * 256 +
                                 (inner ^ ((lp & 7) << 4)));
      }
#pragma unroll
      for (int j = 0; j < 2; ++j) {
        acc[0][j] = MFMA(a0, bv[j], acc[0][j]);
        acc[1][j] = MFMA(a1, bv[j], acc[1][j]);
      }
      a0 = na0; a1 = na1;
      bv[0] = nb[0]; bv[1] = nb[1];
    }
#pragma unroll
    for (int j = 0; j < 2; ++j) {
      acc[0][j] = MFMA(a0, bv[j], acc[0][j]);
      acc[1][j] = MFMA(a1, bv[j], acc[1][j]);
    }
#pragma unroll
    for (int oi = 0; oi < 2; ++oi) {
      int o0 = oi * 16 + 4 * g;
#pragma unroll
      for (int j = 0; j < 2; ++j) {
        int p = (2 * w + j) * 16 + lr;
        short4v sv;
#pragma unroll
        for (int r = 0; r < 4; ++r) sv[r] = f2bf(fmaxf(acc[oi][j][r], 0.f));
        *(short4v*)(sH + p * 40 + o0) = sv;
      }
    }
  }
  __syncthreads();
  // ---- phase 2: res1 1x1 conv + residual over 128 px ----
  {
    f32x4 acc[2][8] = {};
    short8 a0 = *(const short8*)(wA1 + (2 * w * 64 + l) * 8);
    short8 a1 = *(const short8*)(wA1 + ((2 * w + 1) * 64 + l) * 8);
#pragma unroll
    for (int pt = 0; pt < 8; ++pt) {
      short8 bv = *(const short8*)(sH + (pt * 16 + lr) * 40 + 8 * g);
      acc[0][pt] = MFMA(a0, bv, acc[0][pt]);
      acc[1][pt] = MFMA(a1, bv, acc[1][pt]);
    }
#pragma unroll
    for (int oi = 0; oi < 2; ++oi) {
      int o0 = (2 * w + oi) * 16 + 4 * g;
#pragma unroll
      for (int pt = 0; pt < 8; ++pt) {
        int y = r0 + pt, x = c0 + lr;
        float* xp = Xf + ((b * 64 + y) * 64 + x) * 128 + o0;
        f32x4 old = *(f32x4*)xp;
        f32x4 nv; short4v sv;
#pragma unroll
        for (int r = 0; r < 4; ++r) {
          nv[r] = old[r] + acc[oi][pt][r];
          sv[r] = f2bf(fmaxf(nv[r], 0.f));
        }
        if (MODE == 0) *(f32x4*)xp = nv;
        if (MODE != 2) {
          *(short4v*)(XrPout + ((b * 66 + y + 1) * 66 + x + 1) * 128 + o0) =
              sv;
        } else {
          int p = pt * 16 + lr;
          *(short4v*)((char*)sX + p * 256 + ((o0 * 2) ^ ((p & 7) << 4))) = sv;
        }
      }
    }
  }
  if (MODE == 2) {
    __syncthreads();
    // ---- phase 3: prem 1x1 conv over xr (in sX), write Zcat ----
    const short* pA0 = wAp + (2 * w * 64 + l) * 8;
    const short* pA1 = pA0 + 512;
    f32x4 acc[2][8] = {};
#pragma unroll
    for (int kc = 0; kc < 4; ++kc) {
      short8 a0 = *(const short8*)(pA0 + kc * 4096);
      short8 a1 = *(const short8*)(pA1 + kc * 4096);
#pragma unroll
      for (int pt = 0; pt < 8; ++pt) {
        int p = pt * 16 + lr;
        short8 bv = *(const short8*)((const char*)sX + p * 256 +
                                     ((kc * 64 + g * 16) ^ ((p & 7) << 4)));
        acc[0][pt] = MFMA(a0, bv, acc[0][pt]);
        acc[1][pt] = MFMA(a1, bv, acc[1][pt]);
      }
    }
#pragma unroll
    for (int oi = 0; oi < 2; ++oi) {
      int o0 = (2 * w + oi) * 16 + 4 * g;
#pragma unroll
      for (int pt = 0; pt < 8; ++pt) {
        int y = r0 + pt, x = c0 + lr;
        long pix = (long)(b * 64 + y) * 64 + x;
        short4v hv, lv;
#pragma unroll
        for (int r = 0; r < 4; ++r) {
          float v = acc[oi][pt][r] + preb[o0 + r];
          short hi = f2bf(v);
          hv[r] = hi;
          lv[r] = f2bf(v - bf2f(hi));
        }
        *(short4v*)(Zc + pix * 256 + o0) = hv;
        *(short4v*)(Zc + pix * 256 + 128 + o0) = lv;
      }
    }
  }
}

// ============================================================================
// VQ MFMA v9 (async E-staging, 128 px): 128 px x 512 codes, 8 waves (512 thr),
// grid 1024. Wave w owns 64 codes -> acc[4][8] = 128 AGPR; A operands via
// global_load_lds slab. Z tile 64 KB LDS (XOR swizzle). Fused argmin + hist +
// loss + gather.
// ============================================================================
__global__ __launch_bounds__(512) void k_vqm9(const short* __restrict__ Zc,
    const short* __restrict__ Ec, const float* __restrict__ en,
    const float* __restrict__ emb, int* __restrict__ counts,
    float* __restrict__ partials, float* __restrict__ Q,
    short* __restrict__ QrP) {
  __shared__ short sZ[32768];  // 128 px * 256 sh, swizzled = 64 KB
  __shared__ short sE[16384];  // E slab: 8 wave-regions x 2048 sh = 32 KB
  __shared__ float sV[8][128];
  __shared__ int sC[8][128];
  __shared__ float sZn[128];
  __shared__ int sIdx[128];
  __shared__ int sHist[KC];
  int blk = blockIdx.x;
  long pix0 = (long)blk * 128;
  int t = threadIdx.x, w = t >> 6, l = t & 63, c16 = l & 15, g = (l >> 4) & 3;
  for (int e = t; e < KC; e += 512) sHist[e] = 0;

  // stage Z tile: swizzle inner-byte ^ ((pix&7)<<4)
  for (int q = t; q < 4096; q += 512) {
    int p = q >> 5, seg = q & 31;
    short8 v = *(const short8*)(Zc + (pix0 + p) * 256 + seg * 8);
    *(short8*)((char*)sZ + p * 512 + ((seg * 16) ^ ((p & 7) << 4))) = v;
  }
  __syncthreads();

  // ||z||^2 per pixel from LDS: 4 threads/pixel, each 32 dims (128 px)
  {
    int pz = t >> 2, seg4 = t & 3;
    const char* zb = (const char*)sZ + pz * 512;
    int swp = (pz & 7) << 4;
    float s = 0.f;
#pragma unroll
    for (int qq = 0; qq < 4; ++qq) {
      int ih = seg4 * 64 + 16 * qq;  // zh inner byte
      short8 h8 = *(const short8*)(zb + (ih ^ swp));
      short8 l8 = *(const short8*)(zb + ((ih + 256) ^ swp));
#pragma unroll
      for (int j = 0; j < 8; ++j) {
        float zv = bf2f(h8[j]) + bf2f(l8[j]);
        s = fmaf(zv, zv, s);
      }
    }
    s += __shfl_xor(s, 1);
    s += __shfl_xor(s, 2);
    if (seg4 == 0) sZn[pz] = s;
  }

  // GEMM: 12 K-steps of 32; wave-local async E staging; 8 pixel-tiles.
  int sw = (c16 & 7) << 4;
  int zrow = c16 * 512;
  short* sEw = sE + w * 2048;                   // wave-uniform LDS base
  const short* gEw = Ec + w * 2048 + l * 8;     // per-lane global src
  f32x4 acc[4][8] = {};
  for (int kc = 0; kc < 12; ++kc) {
    if (kc) asm volatile("s_waitcnt lgkmcnt(0)" ::: "memory");
#pragma unroll
    for (int i = 0; i < 4; ++i)
      GLOAD_LDS16(gEw + kc * 16384 + i * 512, sEw + i * 512);
    asm volatile("s_waitcnt vmcnt(0)" ::: "memory");
    int koff = kc < 8 ? kc : kc - 8;
    int inn = ((koff * 64 + g * 16) ^ sw);
    const char* zb = (const char*)sZ + zrow + inn;
    short8 a0 = *(const short8*)(sEw + l * 8);
    short8 a1 = *(const short8*)(sEw + 512 + l * 8);
    short8 a2 = *(const short8*)(sEw + 1024 + l * 8);
    short8 a3 = *(const short8*)(sEw + 1536 + l * 8);
#pragma unroll
    for (int pt = 0; pt < 8; ++pt) {
      short8 bb = *(const short8*)(zb + pt * 8192);
      acc[0][pt] = MFMA(a0, bb, acc[0][pt]);
      acc[1][pt] = MFMA(a1, bb, acc[1][pt]);
      acc[2][pt] = MFMA(a2, bb, acc[2][pt]);
      acc[3][pt] = MFMA(a3, bb, acc[3][pt]);
    }
  }
  // running argmin over the wave's 64 codes (codes ascend: ct, r)
  float bvv[8];
  int bcc[8];
#pragma unroll
  for (int pt = 0; pt < 8; ++pt) { bvv[pt] = 3.4e38f; bcc[pt] = 0; }
#pragma unroll
  for (int ct = 0; ct < 4; ++ct) {
    f32x4 en4 = *(const f32x4*)(en + w * 64 + ct * 16 + 4 * g);
#pragma unroll
    for (int pt = 0; pt < 8; ++pt) {
#pragma unroll
      for (int r = 0; r < 4; ++r) {
        float d = en4[r] - 2.f * acc[ct][pt][r];
        int code = w * 64 + ct * 16 + 4 * g + r;
        if (d < bvv[pt]) { bvv[pt] = d; bcc[pt] = code; }
      }
    }
  }
  // cross-lane reduce (over g) per pixel
#pragma unroll
  for (int pt = 0; pt < 8; ++pt) {
    float bv = bvv[pt];
    int bc = bcc[pt];
#pragma unroll
    for (int m = 16; m <= 32; m <<= 1) {
      float ov = __shfl_xor(bv, m);
      int oc = __shfl_xor(bc, m);
      if (ov < bv || (ov == bv && oc < bc)) { bv = ov; bc = oc; }
    }
    if (g == 0) {
      sV[w][pt * 16 + c16] = bv;
      sC[w][pt * 16 + c16] = bc;
    }
  }
  __syncthreads();
  if (t < 128) {
    float bv = sV[0][t];
    int bc = sC[0][t];
#pragma unroll
    for (int w2 = 1; w2 < 8; ++w2) {
      float v = sV[w2][t];
      int c = sC[w2][t];
      if (v < bv || (v == bv && c < bc)) { bv = v; bc = c; }
    }
    sIdx[t] = bc;
    atomicAdd(&sHist[bc], 1);
    sV[0][t] = bv + sZn[t];
  }
  __syncthreads();
  if (t < 64) {
    float ls = sV[0][t] + sV[0][t + 64];
#pragma unroll
    for (int m = 32; m >= 1; m >>= 1) ls += __shfl_xor(ls, m);
    if (t == 0) partials[blk] = ls;
  }
  for (int e = t; e < KC; e += 512) {
    int c = sHist[e];
    if (c) atomicAdd(&counts[e], c);
  }
  // fused gather: Q = emb[idx] f32 (overwrites this block's Zc bytes),
  // QrP = relu bf16 (padded layout)
  for (int e = t; e < 4096; e += 512) {
    int p = e >> 5, d4 = (e & 31) << 2;
    int c = sIdx[p];
    f32x4 q = *(const f32x4*)(emb + c * DD + d4);
    *(f32x4*)(Q + (pix0 + p) * DD + d4) = q;
    short4v sv;
#pragma unroll
    for (int r = 0; r < 4; ++r) sv[r] = f2bf(fmaxf(q[r], 0.f));
    long pixg = pix0 + p;
    int xx = (int)(pixg & 63), yy = (int)((pixg >> 6) & 63),
        bb = (int)(pixg >> 12);
    *(short4v*)(QrP + (((long)(bb * 66 + yy + 1)) * 66 + xx + 1) * 128 + d4) =
        sv;
  }
}

// ============================================================================
// tconv1 MFMA v2 (LDS-staged input, register depth-1 weight prefetch):
// QrP[66,66,128] -> T1[130,130,64] bf16 relu.
// grid 2048 = 32 b x 8 tyt x 8 txt
// ============================================================================
__global__ __launch_bounds__(256) void k_tconv1m(const short* __restrict__ QrP,
    const short* __restrict__ wA, const float* __restrict__ bias,
    short* __restrict__ T1) {
  __shared__ short sX[13600];  // 100 pixels x 136 shorts
  int blk = blockIdx.x;
  int txt = blk & 7, tyt = (blk >> 3) & 7, b = blk >> 6;
  int my0 = tyt * 8, mx0 = txt * 8;
  int t = threadIdx.x;
  for (int q = t; q < 1600; q += 256) {
    int p = q >> 4, seg = q & 15;
    int iy = p / 10, ix = p - iy * 10;
    short8 v = *(const short8*)(QrP +
        ((b * 66 + my0 + iy) * 66 + mx0 + ix) * 128 + seg * 8);
    *(short8*)((char*)sX + p * 272 + seg * 16) = v;
  }
  __syncthreads();
  int w = t >> 6, l = t & 63, lr = l & 15, g = l >> 4;
  int pyr = w >> 1, pxr = w & 1;
  int Bb[4];
#pragma unroll
  for (int nt = 0; nt < 4; ++nt) {
    int p = nt * 16 + lr;
    int my = p >> 3, mx = p & 7;
    Bb[nt] = ((my + pyr + 1) * 10 + (mx + pxr + 1)) * 272 + g * 16;
  }
  const short* pAw = wA + w * 32768 + l * 8;
  f32x4 acc[4][4] = {};
  short8 a[4], bfr[4], na[4], nb[4];
#pragma unroll
  for (int ot = 0; ot < 4; ++ot) a[ot] = *(const short8*)(pAw + ot * 512);
#pragma unroll
  for (int nt = 0; nt < 4; ++nt)
    bfr[nt] = *(const short8*)((const char*)sX + Bb[nt]);
  for (int kc = 0; kc < 15; ++kc) {
    int nk = kc + 1;
    int tt = nk >> 2, dy = tt >> 1, dx = tt & 1;
    int off = -(dy * 10 + dx) * 272 + (nk & 3) * 64;
#pragma unroll
    for (int ot = 0; ot < 4; ++ot)
      na[ot] = *(const short8*)(pAw + nk * 2048 + ot * 512);
#pragma unroll
    for (int nt = 0; nt < 4; ++nt)
      nb[nt] = *(const short8*)((const char*)sX + Bb[nt] + off);
#pragma unroll
    for (int ot = 0; ot < 4; ++ot)
#pragma unroll
      for (int nt = 0; nt < 4; ++nt)
        acc[ot][nt] = MFMA(a[ot], bfr[nt], acc[ot][nt]);
#pragma unroll
    for (int ot = 0; ot < 4; ++ot) a[ot] = na[ot];
#pragma unroll
    for (int nt = 0; nt < 4; ++nt) bfr[nt] = nb[nt];
  }
#pragma unroll
  for (int ot = 0; ot < 4; ++ot)
#pragma unroll
    for (int nt = 0; nt < 4; ++nt)
      acc[ot][nt] = MFMA(a[ot], bfr[nt], acc[ot][nt]);
#pragma unroll
  for (int ot = 0; ot < 4; ++ot) {
    int o0 = ot * 16 + 4 * g;
    f32x4 b4 = *(const f32x4*)(bias + o0);
#pragma unroll
    for (int nt = 0; nt < 4; ++nt) {
      int p = nt * 16 + lr;
      int my = my0 + (p >> 3), mx = mx0 + (p & 7);
      int oy = 2 * my + pyr, ox = 2 * mx + pxr;
      short4v sv;
#pragma unroll
      for (int r = 0; r < 4; ++r)
        sv[r] = f2bf(fmaxf(acc[ot][nt][r] + b4[r], 0.f));
      *(short4v*)(T1 + ((b * 130 + oy + 1) * 130 + ox + 1) * 64 + o0) = sv;
    }
  }
}

// ============================================================================
// tconv2 MFMA v2: T1[130,130,64] bf16 -> x_recon[32,256,256] f32.
// c[tap][px] = W^T * T1 via MFMA (16 taps x 112 px, K=128 [w_hi|w_lo]),
// then 4-entry LDS gather per output. grid 8192 = 32 b x 16 ty x 16 tx.
// ============================================================================
__global__ __launch_bounds__(256) void k_tconv2m(const short* __restrict__ T1,
    const float* __restrict__ w, const float* __restrict__ bias,
    float* __restrict__ xrec) {
  __shared__ short sT[112 * 72];  // 112 px * 144 B = 16,128 B
  __shared__ float sW[1024];
  __shared__ float sC[112 * 20];  // px stride 80 B (16-B aligned) = 8,960 B
  int blk = blockIdx.x;
  int tx = blk & 15, ty = (blk >> 4) & 15, b = blk >> 8;
  int t = threadIdx.x;
  for (int e = t; e < 1024; e += 256) sW[e] = w[e];
  for (int q = t; q < 800; q += 256) {
    int p = q >> 3, seg = q & 7;
    int iy = p / 10, ix = p - iy * 10;
    short8 v = *(const short8*)(T1 +
        (((long)b * 130 + ty * 8 + iy) * 130 + tx * 8 + ix) * 64 + seg * 8);
    *(short8*)((char*)sT + p * 144 + seg * 16) = v;
  }
  __syncthreads();
  int wv = t >> 6, l = t & 63, lr = l & 15, g = l >> 4;
  short8 af[4];
#pragma unroll
  for (int kc = 0; kc < 4; ++kc) {
#pragma unroll
    for (int j = 0; j < 8; ++j) {
      int k = kc * 32 + 8 * g + j;
      float val = sW[(k & 63) * 16 + lr];
      short hi = f2bf(val);
      af[kc][j] = (k < 64) ? hi : f2bf(val - bf2f(hi));
    }
  }
#pragma unroll
  for (int ti = 0; ti < 2; ++ti) {
    int tile = wv + 4 * ti;
    if (tile < 7) {
      f32x4 acc = {};
#pragma unroll
      for (int kc = 0; kc < 4; ++kc) {
        short8 bf = *(const short8*)((const char*)sT +
            (tile * 16 + lr) * 144 + ((kc & 1) * 64 + g * 16));
        acc = MFMA(af[kc], bf, acc);
      }
      *(f32x4*)(sC + (tile * 16 + lr) * 20 + g * 4) = acc;
    }
  }
  __syncthreads();
  int row = t >> 4, col = t & 15;
  int pyr = row & 1, pxr = col & 1;
  int ml = row >> 1, nl = col >> 1;
  int kye = 1 - pyr, kxe = 1 - pxr;
  float acc = bias[0];
#pragma unroll
  for (int dy = 0; dy < 2; ++dy)
#pragma unroll
    for (int dx = 0; dx < 2; ++dx) {
      int px = (ml + pyr - dy + 1) * 10 + (nl + pxr - dx + 1);
      int tap = (kye + 2 * dy) * 4 + (kxe + 2 * dx);
      acc += sC[px * 20 + tap];
    }
  int oy = ty * 16 + row, ox = tx * 16 + col;
  xrec[((long)b * 256 + oy) * 256 + ox] = acc;
}

// ============================================================================
// finalize: loss from 1024 partials; perplexity from counts
// ============================================================================
__global__ __launch_bounds__(256) void k_final(const float* __restrict__ partials,
    const int* __restrict__ counts, float* __restrict__ out) {
  int t = threadIdx.x;
  float s = 0.f;
  for (int i = t; i < 1024; i += 256) s += partials[i];
#pragma unroll
  for (int m = 32; m >= 1; m >>= 1) s += __shfl_xor(s, m);
  __shared__ float sr[4];
  if ((t & 63) == 0) sr[t >> 6] = s;
  __syncthreads();
  if (t == 0) {
    float tot = sr[0] + sr[1] + sr[2] + sr[3];
    out[0] = 1.25f * tot / 16777216.0f;
  }
  float h = 0.f;
  for (int c = t; c < KC; c += 256) {
    float avg = (float)counts[c] / 131072.0f;
    h += avg * logf(avg + 1e-10f);
  }
#pragma unroll
  for (int m = 32; m >= 1; m >>= 1) h += __shfl_xor(h, m);
  __shared__ float sr2[4];
  if ((t & 63) == 0) sr2[t >> 6] = h;
  __syncthreads();
  if (t == 0) out[1 + 32 * 256 * 256] = expf(-(sr2[0] + sr2[1] + sr2[2] + sr2[3]));
}

// ============================================================================
extern "C" void kernel_launch(void* const* d_in, const int* in_sizes, int n_in,
                              void* d_out, int out_size, void* d_ws, size_t ws_size,
                              hipStream_t stream) {
  const float* x    = (const float*)d_in[0];
  const float* c1w  = (const float*)d_in[1];
  const float* c1b  = (const float*)d_in[2];
  const float* c2w  = (const float*)d_in[3];
  const float* c2b  = (const float*)d_in[4];
  const float* r1w3 = (const float*)d_in[5];
  const float* r1w1 = (const float*)d_in[6];
  const float* r2w3 = (const float*)d_in[7];
  const float* r2w1 = (const float*)d_in[8];
  const float* prew = (const float*)d_in[9];
  const float* preb = (const float*)d_in[10];
  const float* emb  = (const float*)d_in[11];
  const float* d1w3 = (const float*)d_in[12];
  const float* d1w1 = (const float*)d_in[13];
  const float* d2w3 = (const float*)d_in[14];
  const float* d2w1 = (const float*)d_in[15];
  const float* t1w  = (const float*)d_in[16];
  const float* t1b  = (const float*)d_in[17];
  const float* t2w  = (const float*)d_in[18];
  const float* t2b  = (const float*)d_in[19];
  float* out = (float*)d_out;

  char* ws = (char*)d_ws;
  short* buf0 = (short*)(ws);                      // A1 / T1 : 69,222,400 B
  float* bufX = (float*)(ws + 69222400);           // Xf / Zcat / Q : 67,108,864 B
  short* bufR = (short*)(ws + 136331264);          // XrP / QrP : 35,684,352 B
  int*   counts = (int*)(ws + 180928512);          // 2,048 B
  float* partials = (float*)(ws + 180930560);      // 8,192 B
  float* en   = (float*)(ws + 180938752);          // 2,048 B
  short* wAc2 = (short*)(ws + 180940800);          // 262,144 B
  short* wAr3 = (short*)(ws + 181202944);          // 294,912 B
  short* wAr1 = (short*)(ws + 181497856);          // 32,768 B
  short* wApre= (short*)(ws + 181530624);          // 32,768 B
  short* wAt1 = (short*)(ws + 181563392);          // 262,144 B
  short* Ecat = (short*)(ws + 181825536);          // 393,216 B -> ends 182,218,752

  short* Zcat = (short*)bufX;  // Zcat aliases Xf (k_resblk<2> reads Xf,
                               // writes the same bytes after a barrier)

  short* wAr3_e1 = wAr3;
  short* wAr3_e2 = wAr3 + 36864;
  short* wAr3_d1 = wAr3 + 2 * 36864;
  short* wAr3_d2 = wAr3 + 3 * 36864;
  short* wAr1_e1 = wAr1;
  short* wAr1_e2 = wAr1 + 4096;
  short* wAr1_d1 = wAr1 + 2 * 4096;
  short* wAr1_d2 = wAr1 + 3 * 4096;

  k_prep <<<2881, 256, 0, stream>>>(c2w, r1w3, r2w3, d1w3, d2w3,
                                    r1w1, r2w1, d1w1, d2w1, prew, t1w, emb,
                                    wAc2, wAr3, wAr1, wApre, wAt1, Ecat,
                                    en, buf0, bufR, counts);

  k_conv1     <<<4096, 256, 0, stream>>>(x, c1w, c1b, buf0);
  k_conv2m    <<<2048, 256, 0, stream>>>(buf0, wAc2, c2b, bufX, bufR);
  k_resblk<0> <<<1024, 256, 0, stream>>>(bufR, wAr3_e1, wAr1_e1, bufX, bufR,
                                         nullptr, nullptr, nullptr);
  k_resblk<2> <<<1024, 256, 0, stream>>>(bufR, wAr3_e2, wAr1_e2, bufX, nullptr,
                                         wApre, preb, Zcat);
  k_vqm9      <<<1024, 512, 0, stream>>>(Zcat, Ecat, en, emb, counts,
                                         partials, bufX, bufR);
  k_resblk<0> <<<1024, 256, 0, stream>>>(bufR, wAr3_d1, wAr1_d1, bufX, bufR,
                                         nullptr, nullptr, nullptr);
  k_resblk<1> <<<1024, 256, 0, stream>>>(bufR, wAr3_d2, wAr1_d2, bufX, bufR,
                                         nullptr, nullptr, nullptr);
  k_tconv1m   <<<2048, 256, 0, stream>>>(bufR, wAt1, t1b, buf0);
  k_tconv2m   <<<8192, 256, 0, stream>>>(buf0, t2w, t2b, out + 1);
  k_final     <<<1, 256, 0, stream>>>(partials, counts, out);
}

// Round 17
// 485.534 us; speedup vs baseline: 1.0748x; 1.0201x over previous
//
#include <hip/hip_runtime.h>
#include <math.h>

#define KC 512
#define DD 128

typedef __attribute__((ext_vector_type(8))) short short8;
typedef __attribute__((ext_vector_type(4))) short short4v;
typedef __attribute__((ext_vector_type(4))) float f32x4;

#define MFMA(a, b, c) __builtin_amdgcn_mfma_f32_16x16x32_bf16(a, b, c, 0, 0, 0)

__device__ __forceinline__ short f2bf(float f) {
  unsigned u = __float_as_uint(f);
  u = (u + 0x7FFFu + ((u >> 16) & 1u)) >> 16;
  return (short)u;
}
__device__ __forceinline__ float bf2f(short s) {
  return __uint_as_float(((unsigned)(unsigned short)s) << 16);
}

// ============================================================================
// k_prep: ALL weight permutations + embnorm + border-zero + counts-zero
// + conv1 (independent of every prep output: writes A1 INTERIOR only,
// border-zero writes the ring - disjoint) in ONE dispatch.
// Block ranges:
//   [0,512)      perm_c2      [512,1088)   perm_r3 x4   [1088,1152) perm_r1 x4
//   [1152,1216)  perm_pre     [1216,1728)  perm_t1      [1728,2496) perm_E
//   [2496,2624)  embnorm      [2624,2880)  border       [2880] counts zero
//   [2881,6977)  conv1: x[32,1,256,256] f32 -> A1 interior bf16 relu
// grid 6977 x 256
// ============================================================================
__global__ __launch_bounds__(256) void k_prep(
    const float* __restrict__ c2w,
    const float* __restrict__ r1w3, const float* __restrict__ r2w3,
    const float* __restrict__ d1w3, const float* __restrict__ d2w3,
    const float* __restrict__ r1w1, const float* __restrict__ r2w1,
    const float* __restrict__ d1w1, const float* __restrict__ d2w1,
    const float* __restrict__ prew, const float* __restrict__ t1w,
    const float* __restrict__ emb,
    const float* __restrict__ x, const float* __restrict__ c1w,
    const float* __restrict__ c1b,
    short* __restrict__ wAc2, short* __restrict__ wAr3,
    short* __restrict__ wAr1, short* __restrict__ wApre,
    short* __restrict__ wAt1, short* __restrict__ Ecat,
    float* __restrict__ en, short* __restrict__ A1,
    short* __restrict__ XrP, int* __restrict__ counts) {
  __shared__ float sXp[4 * 260];
  __shared__ float sWt[16 * 64];
  int blk = blockIdx.x, t = threadIdx.x;
  if (blk < 512) {  // perm_c2
    int e = blk * 256 + t;
    int j = e & 7, l = (e >> 3) & 63, ot = (e >> 9) & 7, kc = e >> 12;
    int o = ot * 16 + (l & 15), g = l >> 4;
    int tap = kc >> 1, ci = (kc & 1) * 32 + 8 * g + j;
    wAc2[e] = f2bf(c2w[(o * 64 + ci) * 16 + tap]);
  } else if (blk < 1088) {  // perm_r3 x4
    int sub = blk - 512;
    int which = sub / 144, bb = sub - which * 144;
    const float* w = which == 0 ? r1w3 : which == 1 ? r2w3
                     : which == 2 ? d1w3 : d2w3;
    short* dst = wAr3 + which * 36864;
    int e = bb * 256 + t;
    int j = e & 7, l = (e >> 3) & 63, ot = (e >> 9) & 1, kc = e >> 10;
    int o = ot * 16 + (l & 15), g = l >> 4;
    int tap = kc >> 2, ci = (kc & 3) * 32 + 8 * g + j;
    dst[e] = f2bf(w[(o * 128 + ci) * 9 + tap]);
  } else if (blk < 1152) {  // perm_r1 x4
    int sub = blk - 1088;
    int which = sub >> 4, bb = sub & 15;
    const float* w = which == 0 ? r1w1 : which == 1 ? r2w1
                     : which == 2 ? d1w1 : d2w1;
    short* dst = wAr1 + which * 4096;
    int e = bb * 256 + t;
    int j = e & 7, l = (e >> 3) & 63, ot = e >> 9;
    int o = ot * 16 + (l & 15), g = l >> 4;
    int ci = 8 * g + j;
    dst[e] = f2bf(w[o * 32 + ci]);
  } else if (blk < 1216) {  // perm_pre
    int e = (blk - 1152) * 256 + t;
    int j = e & 7, l = (e >> 3) & 63, ot = (e >> 9) & 7, kc = e >> 12;
    int o = ot * 16 + (l & 15), g = l >> 4;
    int ci = kc * 32 + 8 * g + j;
    wApre[e] = f2bf(prew[o * 128 + ci]);
  } else if (blk < 1728) {  // perm_t1
    int e = (blk - 1216) * 256 + t;
    int j = e & 7, l = (e >> 3) & 63, ot = (e >> 9) & 3, kc = (e >> 11) & 15,
        pp = e >> 15;
    int pyr = pp >> 1, pxr = pp & 1;
    int o = ot * 16 + (l & 15), g = l >> 4;
    int tt = kc >> 2, dy = tt >> 1, dx = tt & 1;
    int ky = (1 - pyr) + 2 * dy, kx = (1 - pxr) + 2 * dx;
    int ci = (kc & 3) * 32 + 8 * g + j;
    wAt1[e] = f2bf(t1w[(ci * 64 + o) * 16 + ky * 4 + kx]);
  } else if (blk < 2496) {  // perm_E
    int e = (blk - 1728) * 256 + t;
    int j = e & 7, l = (e >> 3) & 63, ot = (e >> 9) & 31, kc = e >> 14;
    int c = ot * 16 + (l & 15);
    int k = kc * 32 + 8 * (l >> 4) + j;
    float v = emb[c * DD + (k & 127)];
    short hi = f2bf(v);
    Ecat[e] = (k < 256) ? hi : f2bf(v - bf2f(hi));
  } else if (blk < 2624) {  // embnorm: 4 codes per block (wave = code)
    int c = (blk - 2496) * 4 + (t >> 6), l = t & 63;
    float a = emb[c * DD + l], b2 = emb[c * DD + 64 + l];
    float s = a * a + b2 * b2;
#pragma unroll
    for (int m = 32; m >= 1; m >>= 1) s += __shfl_xor(s, m);
    if (l == 0) en[c] = s;
  } else if (blk < 2880) {  // border zero
    int bb = blk - 2624;
    int b = bb >> 3;
    int tid = ((bb & 7) << 8) + t;  // 0..2047
    short8 z8 = {};
    long baseA = (long)b * 1081600;  // 130*130*64
    for (int e = tid; e < 2080; e += 2048) {
      int r = e >= 1040;
      int rem = r ? e - 1040 : e;
      *(short8*)(A1 + baseA + (r ? 129L * 130 * 64 : 0) + rem * 8) = z8;
    }
    {
      int c = tid >> 10, rem = tid & 1023;
      int row = 1 + (rem >> 3), s8 = rem & 7;
      *(short8*)(A1 + baseA + (row * 130L + (c ? 129 : 0)) * 64 + s8 * 8) = z8;
    }
    long baseX = (long)b * 557568;  // 66*66*128
    for (int e = tid; e < 2112; e += 2048) {
      int r = e >= 1056;
      int rem = r ? e - 1056 : e;
      *(short8*)(XrP + baseX + (r ? 65L * 66 * 128 : 0) + rem * 8) = z8;
    }
    {
      int c = tid >> 10, rem = tid & 1023;
      int row = 1 + (rem >> 4), s8 = rem & 15;
      *(short8*)(XrP + baseX + (row * 66L + (c ? 65 : 0)) * 128 + s8 * 8) = z8;
    }
  } else if (blk == 2880) {  // counts zero
    counts[t] = 0;
    counts[t + 256] = 0;
  } else {  // conv1 (interior of A1)
    int cb = blk - 2881;
    int y = cb & 127, b = cb >> 7;
    for (int e = t; e < 1024; e += 256) sWt[e] = c1w[(e & 63) * 16 + (e >> 6)];
    if (t < 4) {
      sXp[t * 260] = 0.f;
      sXp[t * 260 + 257] = 0.f;
      sXp[t * 260 + 258] = 0.f;
      sXp[t * 260 + 259] = 0.f;
    }
    for (int e = t; e < 1024; e += 256) {
      int r = e >> 8, col = e & 255;
      int giy = 2 * y - 1 + r;
      float v = 0.f;
      if ((unsigned)giy < 256u) v = x[(b * 256 + giy) * 256 + col];
      sXp[r * 260 + col + 1] = v;
    }
    __syncthreads();
    int og = t >> 6, l = t & 63, o0 = og * 16;
    float acc0[16], acc1[16];
#pragma unroll
    for (int oo = 0; oo < 16; ++oo) { acc0[oo] = 0.f; acc1[oo] = 0.f; }
    int xA = 2 * l, xB = 2 * l + 128;
#pragma unroll
    for (int ky = 0; ky < 4; ++ky) {
#pragma unroll
      for (int kx = 0; kx < 4; ++kx) {
        float a0 = sXp[ky * 260 + xA + kx];
        float a1 = sXp[ky * 260 + xB + kx];
        const float* wrow = &sWt[(ky * 4 + kx) * 64 + o0];
#pragma unroll
        for (int oo = 0; oo < 16; ++oo) {
          float wv = wrow[oo];
          acc0[oo] = fmaf(a0, wv, acc0[oo]);
          acc1[oo] = fmaf(a1, wv, acc1[oo]);
        }
      }
    }
    long base0 = (((long)(b * 130 + y + 1)) * 130 + l + 1) * 64 + o0;
    long base1 = base0 + 64 * 64;
    short8 s0a, s0b, s1a, s1b;
#pragma unroll
    for (int oo = 0; oo < 8; ++oo) {
      s0a[oo] = f2bf(fmaxf(acc0[oo] + c1b[o0 + oo], 0.f));
      s0b[oo] = f2bf(fmaxf(acc0[oo + 8] + c1b[o0 + oo + 8], 0.f));
      s1a[oo] = f2bf(fmaxf(acc1[oo] + c1b[o0 + oo], 0.f));
      s1b[oo] = f2bf(fmaxf(acc1[oo + 8] + c1b[o0 + oo + 8], 0.f));
    }
    *(short8*)(A1 + base0) = s0a;
    *(short8*)(A1 + base0 + 8) = s0b;
    *(short8*)(A1 + base1) = s1a;
    *(short8*)(A1 + base1 + 8) = s1b;
  }
}

// ============================================================================
// conv2 MFMA v2 (LDS-staged input, register depth-1 weight prefetch):
// A1[130,130,64] bf16 -> relu -> Xf[64,64,128] f32 + XrP[66,66,128] bf16.
// grid 2048 = 32 b x 8 by x 8 bx
// ============================================================================
__global__ __launch_bounds__(256) void k_conv2m(const short* __restrict__ A1,
    const short* __restrict__ wA, const float* __restrict__ bias,
    float* __restrict__ Xf, short* __restrict__ XrP) {
  __shared__ short sX[22032];  // 324 px * 68 shorts (136 B) = 44,064 B
  int blk = blockIdx.x;
  int bx = blk & 7, by = (blk >> 3) & 7, b = blk >> 6;
  int t = threadIdx.x;
  int R0 = by * 16, C0 = bx * 16;
  for (int q = t; q < 2592; q += 256) {
    int p = q >> 3, seg = q & 7;
    int iy = p / 18, ix = p - iy * 18;
    short8 v = *(const short8*)(A1 +
        (((long)b * 130 + R0 + iy) * 130 + C0 + ix) * 64 + seg * 8);
    *(short8*)((char*)sX + p * 136 + seg * 16) = v;
  }
  __syncthreads();
  int w = t >> 6, l = t & 63, lr = l & 15, g = l >> 4;
  int Bb[4];
#pragma unroll
  for (int pt = 0; pt < 4; ++pt) {
    int p = pt * 16 + lr;
    int lp = 2 * (p >> 3) * 18 + 2 * (p & 7);
    Bb[pt] = lp * 136 + g * 16;
  }
  const short* pA0 = wA + (2 * w * 64 + l) * 8;
  const short* pA1 = pA0 + 512;
  f32x4 acc[2][4] = {};
  short8 a0 = *(const short8*)pA0;
  short8 a1 = *(const short8*)pA1;
  short8 bv[4];
#pragma unroll
  for (int i = 0; i < 4; ++i)
    bv[i] = *(const short8*)((const char*)sX + Bb[i]);
  for (int kc = 0; kc < 31; ++kc) {
    int nk = kc + 1;
    int tap = nk >> 1;
    int off = ((tap >> 2) * 18 + (tap & 3)) * 136 + (nk & 1) * 64;
    short8 na0 = *(const short8*)(pA0 + nk * 4096);
    short8 na1 = *(const short8*)(pA1 + nk * 4096);
    short8 nb[4];
#pragma unroll
    for (int i = 0; i < 4; ++i)
      nb[i] = *(const short8*)((const char*)sX + Bb[i] + off);
#pragma unroll
    for (int i = 0; i < 4; ++i) {
      acc[0][i] = MFMA(a0, bv[i], acc[0][i]);
      acc[1][i] = MFMA(a1, bv[i], acc[1][i]);
    }
    a0 = na0; a1 = na1;
#pragma unroll
    for (int i = 0; i < 4; ++i) bv[i] = nb[i];
  }
#pragma unroll
  for (int i = 0; i < 4; ++i) {
    acc[0][i] = MFMA(a0, bv[i], acc[0][i]);
    acc[1][i] = MFMA(a1, bv[i], acc[1][i]);
  }
#pragma unroll
  for (int oi = 0; oi < 2; ++oi) {
    int o0 = (2 * w + oi) * 16 + 4 * g;
#pragma unroll
    for (int pt = 0; pt < 4; ++pt) {
      int p = pt * 16 + lr;
      int y = by * 8 + (p >> 3), x = bx * 8 + (p & 7);
      f32x4 nv; short4v sv;
#pragma unroll
      for (int r = 0; r < 4; ++r) {
        float v = fmaxf(acc[oi][pt][r] + bias[o0 + r], 0.f);
        nv[r] = v; sv[r] = f2bf(v);
      }
      *(f32x4*)(Xf + ((b * 64 + y) * 64 + x) * 128 + o0) = nv;
      *(short4v*)(XrP + ((b * 66 + y + 1) * 66 + x + 1) * 128 + o0) = sv;
    }
  }
}

// ============================================================================
// resblk fused: res3 (3x3 conv, XrP -> H in LDS) + res1 (1x1 conv + residual).
// Block = 8x16 out-px (res3m tiling), grid 1024 = 32 b x 8 yt x 4 tx.
// MODE 0: write Xf + XrPout.  MODE 1: write XrPout only.  MODE 2: encoder
// tail - xr stays in LDS, then prem -> Zcat (Zc aliases Xf, barrier-ordered).
// ============================================================================
template <int MODE>
__global__ __launch_bounds__(256) void k_resblk(
    const short* __restrict__ XrPin, const short* __restrict__ wA3,
    const short* __restrict__ wA1, float* Xf, short* XrPout,
    const short* __restrict__ wAp, const float* __restrict__ preb,
    short* Zc) {
  __shared__ short sX[23040];  // phase1 XrP tile; MODE2 phase2 reuses as sXr
  __shared__ short sH[128 * 40];  // H: 128 px * 40 sh (80 B stride)
  int blk = blockIdx.x;
  int tx = blk & 3, yt = (blk >> 2) & 7, b = blk >> 5;
  int t = threadIdx.x;
  int r0 = yt * 8, c0 = tx * 16;
  for (int q = t; q < 2880; q += 256) {
    int p = q >> 4, seg = q & 15;
    int iy = p / 18, ix = p - iy * 18;
    short8 v = *(const short8*)(XrPin +
        (((long)b * 66 + r0 + iy) * 66 + c0 + ix) * 128 + seg * 8);
    *(short8*)((char*)sX + p * 256 + ((seg * 16) ^ ((p & 7) << 4))) = v;
  }
  __syncthreads();
  int w = t >> 6, l = t & 63, lr = l & 15, g = l >> 4;
  // ---- phase 1: res3 3x3 conv, H -> sH ----
  {
    const short* pA0 = wA3 + l * 8;
    const short* pA1 = pA0 + 512;
    f32x4 acc[2][2] = {};
    short8 a0 = *(const short8*)pA0;
    short8 a1 = *(const short8*)pA1;
    short8 bv[2];
#pragma unroll
    for (int j = 0; j < 2; ++j) {
      int lp = (2 * w + j) * 18 + lr;
      bv[j] = *(const short8*)((const char*)sX + lp * 256 +
                               ((g * 16) ^ ((lp & 7) << 4)));
    }
    for (int kc = 0; kc < 35; ++kc) {
      int nk = kc + 1;
      int tap = nk >> 2;
      int ky = tap / 3, kx = tap - ky * 3;
      int inner = g * 16 + (nk & 3) * 64;
      short8 na0 = *(const short8*)(pA0 + nk * 1024);
      short8 na1 = *(const short8*)(pA1 + nk * 1024);
      short8 nb[2];
#pragma unroll
      for (int j = 0; j < 2; ++j) {
        int lp = (2 * w + j + ky) * 18 + lr + kx;
        nb[j] = *(const short8*)((const char*)sX + lp * 256 +
                                 (inner ^ ((lp & 7) << 4)));
      }
#pragma unroll
      for (int j = 0; j < 2; ++j) {
        acc[0][j] = MFMA(a0, bv[j], acc[0][j]);
        acc[1][j] = MFMA(a1, bv[j], acc[1][j]);
      }
      a0 = na0; a1 = na1;
      bv[0] = nb[0]; bv[1] = nb[1];
    }
#pragma unroll
    for (int j = 0; j < 2; ++j) {
      acc[0][j] = MFMA(a0, bv[j], acc[0][j]);
      acc[1][j] = MFMA(a1, bv[j], acc[1][j]);
    }
#pragma unroll
    for (int oi = 0; oi < 2; ++oi) {
      int o0 = oi * 16 + 4 * g;
#pragma unroll
      for (int j = 0; j < 2; ++j) {
        int p = (2 * w + j) * 16 + lr;
        short4v sv;
#pragma unroll
        for (int r = 0; r < 4; ++r) sv[r] = f2bf(fmaxf(acc[oi][j][r], 0.f));
        *(short4v*)(sH + p * 40 + o0) = sv;
      }
    }
  }
  __syncthreads();
  // ---- phase 2: res1 1x1 conv + residual over 128 px ----
  {
    f32x4 acc[2][8] = {};
    short8 a0 = *(const short8*)(wA1 + (2 * w * 64 + l) * 8);
    short8 a1 = *(const short8*)(wA1 + ((2 * w + 1) * 64 + l) * 8);
#pragma unroll
    for (int pt = 0; pt < 8; ++pt) {
      short8 bv = *(const short8*)(sH + (pt * 16 + lr) * 40 + 8 * g);
      acc[0][pt] = MFMA(a0, bv, acc[0][pt]);
      acc[1][pt] = MFMA(a1, bv, acc[1][pt]);
    }
#pragma unroll
    for (int oi = 0; oi < 2; ++oi) {
      int o0 = (2 * w + oi) * 16 + 4 * g;
#pragma unroll
      for (int pt = 0; pt < 8; ++pt) {
        int y = r0 + pt, x = c0 + lr;
        float* xp = Xf + ((b * 64 + y) * 64 + x) * 128 + o0;
        f32x4 old = *(f32x4*)xp;
        f32x4 nv; short4v sv;
#pragma unroll
        for (int r = 0; r < 4; ++r) {
          nv[r] = old[r] + acc[oi][pt][r];
          sv[r] = f2bf(fmaxf(nv[r], 0.f));
        }
        if (MODE == 0) *(f32x4*)xp = nv;
        if (MODE != 2) {
          *(short4v*)(XrPout + ((b * 66 + y + 1) * 66 + x + 1) * 128 + o0) =
              sv;
        } else {
          int p = pt * 16 + lr;
          *(short4v*)((char*)sX + p * 256 + ((o0 * 2) ^ ((p & 7) << 4))) = sv;
        }
      }
    }
  }
  if (MODE == 2) {
    __syncthreads();
    // ---- phase 3: prem 1x1 conv over xr (in sX), write Zcat ----
    const short* pA0 = wAp + (2 * w * 64 + l) * 8;
    const short* pA1 = pA0 + 512;
    f32x4 acc[2][8] = {};
#pragma unroll
    for (int kc = 0; kc < 4; ++kc) {
      short8 a0 = *(const short8*)(pA0 + kc * 4096);
      short8 a1 = *(const short8*)(pA1 + kc * 4096);
#pragma unroll
      for (int pt = 0; pt < 8; ++pt) {
        int p = pt * 16 + lr;
        short8 bv = *(const short8*)((const char*)sX + p * 256 +
                                     ((kc * 64 + g * 16) ^ ((p & 7) << 4)));
        acc[0][pt] = MFMA(a0, bv, acc[0][pt]);
        acc[1][pt] = MFMA(a1, bv, acc[1][pt]);
      }
    }
#pragma unroll
    for (int oi = 0; oi < 2; ++oi) {
      int o0 = (2 * w + oi) * 16 + 4 * g;
#pragma unroll
      for (int pt = 0; pt < 8; ++pt) {
        int y = r0 + pt, x = c0 + lr;
        long pix = (long)(b * 64 + y) * 64 + x;
        short4v hv, lv;
#pragma unroll
        for (int r = 0; r < 4; ++r) {
          float v = acc[oi][pt][r] + preb[o0 + r];
          short hi = f2bf(v);
          hv[r] = hi;
          lv[r] = f2bf(v - bf2f(hi));
        }
        *(short4v*)(Zc + pix * 256 + o0) = hv;
        *(short4v*)(Zc + pix * 256 + 128 + o0) = lv;
      }
    }
  }
}

#define GLOAD_LDS16(g, l)                                        \
  __builtin_amdgcn_global_load_lds(                              \
      (const __attribute__((address_space(1))) void*)(g),        \
      (__attribute__((address_space(3))) void*)(l), 16, 0, 0)

// ============================================================================
// VQ MFMA v9 (async E-staging, 128 px): 128 px x 512 codes, 8 waves (512 thr),
// grid 1024. Wave w owns 64 codes -> acc[4][8] = 128 AGPR; A operands via
// global_load_lds slab. Z tile 64 KB LDS (XOR swizzle). Fused argmin + hist +
// loss + gather.
// ============================================================================
__global__ __launch_bounds__(512) void k_vqm9(const short* __restrict__ Zc,
    const short* __restrict__ Ec, const float* __restrict__ en,
    const float* __restrict__ emb, int* __restrict__ counts,
    float* __restrict__ partials, float* __restrict__ Q,
    short* __restrict__ QrP) {
  __shared__ short sZ[32768];  // 128 px * 256 sh, swizzled = 64 KB
  __shared__ short sE[16384];  // E slab: 8 wave-regions x 2048 sh = 32 KB
  __shared__ float sV[8][128];
  __shared__ int sC[8][128];
  __shared__ float sZn[128];
  __shared__ int sIdx[128];
  __shared__ int sHist[KC];
  int blk = blockIdx.x;
  long pix0 = (long)blk * 128;
  int t = threadIdx.x, w = t >> 6, l = t & 63, c16 = l & 15, g = (l >> 4) & 3;
  for (int e = t; e < KC; e += 512) sHist[e] = 0;

  // stage Z tile: swizzle inner-byte ^ ((pix&7)<<4)
  for (int q = t; q < 4096; q += 512) {
    int p = q >> 5, seg = q & 31;
    short8 v = *(const short8*)(Zc + (pix0 + p) * 256 + seg * 8);
    *(short8*)((char*)sZ + p * 512 + ((seg * 16) ^ ((p & 7) << 4))) = v;
  }
  __syncthreads();

  // ||z||^2 per pixel from LDS: 4 threads/pixel, each 32 dims (128 px)
  {
    int pz = t >> 2, seg4 = t & 3;
    const char* zb = (const char*)sZ + pz * 512;
    int swp = (pz & 7) << 4;
    float s = 0.f;
#pragma unroll
    for (int qq = 0; qq < 4; ++qq) {
      int ih = seg4 * 64 + 16 * qq;  // zh inner byte
      short8 h8 = *(const short8*)(zb + (ih ^ swp));
      short8 l8 = *(const short8*)(zb + ((ih + 256) ^ swp));
#pragma unroll
      for (int j = 0; j < 8; ++j) {
        float zv = bf2f(h8[j]) + bf2f(l8[j]);
        s = fmaf(zv, zv, s);
      }
    }
    s += __shfl_xor(s, 1);
    s += __shfl_xor(s, 2);
    if (seg4 == 0) sZn[pz] = s;
  }

  // GEMM: 12 K-steps of 32; wave-local async E staging; 8 pixel-tiles.
  int sw = (c16 & 7) << 4;
  int zrow = c16 * 512;
  short* sEw = sE + w * 2048;                   // wave-uniform LDS base
  const short* gEw = Ec + w * 2048 + l * 8;     // per-lane global src
  f32x4 acc[4][8] = {};
  for (int kc = 0; kc < 12; ++kc) {
    if (kc) asm volatile("s_waitcnt lgkmcnt(0)" ::: "memory");
#pragma unroll
    for (int i = 0; i < 4; ++i)
      GLOAD_LDS16(gEw + kc * 16384 + i * 512, sEw + i * 512);
    asm volatile("s_waitcnt vmcnt(0)" ::: "memory");
    int koff = kc < 8 ? kc : kc - 8;
    int inn = ((koff * 64 + g * 16) ^ sw);
    const char* zb = (const char*)sZ + zrow + inn;
    short8 a0 = *(const short8*)(sEw + l * 8);
    short8 a1 = *(const short8*)(sEw + 512 + l * 8);
    short8 a2 = *(const short8*)(sEw + 1024 + l * 8);
    short8 a3 = *(const short8*)(sEw + 1536 + l * 8);
#pragma unroll
    for (int pt = 0; pt < 8; ++pt) {
      short8 bb = *(const short8*)(zb + pt * 8192);
      acc[0][pt] = MFMA(a0, bb, acc[0][pt]);
      acc[1][pt] = MFMA(a1, bb, acc[1][pt]);
      acc[2][pt] = MFMA(a2, bb, acc[2][pt]);
      acc[3][pt] = MFMA(a3, bb, acc[3][pt]);
    }
  }
  // running argmin over the wave's 64 codes (codes ascend: ct, r)
  float bvv[8];
  int bcc[8];
#pragma unroll
  for (int pt = 0; pt < 8; ++pt) { bvv[pt] = 3.4e38f; bcc[pt] = 0; }
#pragma unroll
  for (int ct = 0; ct < 4; ++ct) {
    f32x4 en4 = *(const f32x4*)(en + w * 64 + ct * 16 + 4 * g);
#pragma unroll
    for (int pt = 0; pt < 8; ++pt) {
#pragma unroll
      for (int r = 0; r < 4; ++r) {
        float d = en4[r] - 2.f * acc[ct][pt][r];
        int code = w * 64 + ct * 16 + 4 * g + r;
        if (d < bvv[pt]) { bvv[pt] = d; bcc[pt] = code; }
      }
    }
  }
  // cross-lane reduce (over g) per pixel
#pragma unroll
  for (int pt = 0; pt < 8; ++pt) {
    float bv = bvv[pt];
    int bc = bcc[pt];
#pragma unroll
    for (int m = 16; m <= 32; m <<= 1) {
      float ov = __shfl_xor(bv, m);
      int oc = __shfl_xor(bc, m);
      if (ov < bv || (ov == bv && oc < bc)) { bv = ov; bc = oc; }
    }
    if (g == 0) {
      sV[w][pt * 16 + c16] = bv;
      sC[w][pt * 16 + c16] = bc;
    }
  }
  __syncthreads();
  if (t < 128) {
    float bv = sV[0][t];
    int bc = sC[0][t];
#pragma unroll
    for (int w2 = 1; w2 < 8; ++w2) {
      float v = sV[w2][t];
      int c = sC[w2][t];
      if (v < bv || (v == bv && c < bc)) { bv = v; bc = c; }
    }
    sIdx[t] = bc;
    atomicAdd(&sHist[bc], 1);
    sV[0][t] = bv + sZn[t];
  }
  __syncthreads();
  if (t < 64) {
    float ls = sV[0][t] + sV[0][t + 64];
#pragma unroll
    for (int m = 32; m >= 1; m >>= 1) ls += __shfl_xor(ls, m);
    if (t == 0) partials[blk] = ls;
  }
  for (int e = t; e < KC; e += 512) {
    int c = sHist[e];
    if (c) atomicAdd(&counts[e], c);
  }
  // fused gather: Q = emb[idx] f32 (overwrites this block's Zc bytes),
  // QrP = relu bf16 (padded layout)
  for (int e = t; e < 4096; e += 512) {
    int p = e >> 5, d4 = (e & 31) << 2;
    int c = sIdx[p];
    f32x4 q = *(const f32x4*)(emb + c * DD + d4);
    *(f32x4*)(Q + (pix0 + p) * DD + d4) = q;
    short4v sv;
#pragma unroll
    for (int r = 0; r < 4; ++r) sv[r] = f2bf(fmaxf(q[r], 0.f));
    long pixg = pix0 + p;
    int xx = (int)(pixg & 63), yy = (int)((pixg >> 6) & 63),
        bb = (int)(pixg >> 12);
    *(short4v*)(QrP + (((long)(bb * 66 + yy + 1)) * 66 + xx + 1) * 128 + d4) =
        sv;
  }
}

// ============================================================================
// tconv1 MFMA v2 (LDS-staged input, register depth-1 weight prefetch):
// QrP[66,66,128] -> T1[130,130,64] bf16 relu.
// grid 2048 = 32 b x 8 tyt x 8 txt
// ============================================================================
__global__ __launch_bounds__(256) void k_tconv1m(const short* __restrict__ QrP,
    const short* __restrict__ wA, const float* __restrict__ bias,
    short* __restrict__ T1) {
  __shared__ short sX[13600];  // 100 pixels x 136 shorts
  int blk = blockIdx.x;
  int txt = blk & 7, tyt = (blk >> 3) & 7, b = blk >> 6;
  int my0 = tyt * 8, mx0 = txt * 8;
  int t = threadIdx.x;
  for (int q = t; q < 1600; q += 256) {
    int p = q >> 4, seg = q & 15;
    int iy = p / 10, ix = p - iy * 10;
    short8 v = *(const short8*)(QrP +
        ((b * 66 + my0 + iy) * 66 + mx0 + ix) * 128 + seg * 8);
    *(short8*)((char*)sX + p * 272 + seg * 16) = v;
  }
  __syncthreads();
  int w = t >> 6, l = t & 63, lr = l & 15, g = l >> 4;
  int pyr = w >> 1, pxr = w & 1;
  int Bb[4];
#pragma unroll
  for (int nt = 0; nt < 4; ++nt) {
    int p = nt * 16 + lr;
    int my = p >> 3, mx = p & 7;
    Bb[nt] = ((my + pyr + 1) * 10 + (mx + pxr + 1)) * 272 + g * 16;
  }
  const short* pAw = wA + w * 32768 + l * 8;
  f32x4 acc[4][4] = {};
  short8 a[4], bfr[4], na[4], nb[4];
#pragma unroll
  for (int ot = 0; ot < 4; ++ot) a[ot] = *(const short8*)(pAw + ot * 512);
#pragma unroll
  for (int nt = 0; nt < 4; ++nt)
    bfr[nt] = *(const short8*)((const char*)sX + Bb[nt]);
  for (int kc = 0; kc < 15; ++kc) {
    int nk = kc + 1;
    int tt = nk >> 2, dy = tt >> 1, dx = tt & 1;
    int off = -(dy * 10 + dx) * 272 + (nk & 3) * 64;
#pragma unroll
    for (int ot = 0; ot < 4; ++ot)
      na[ot] = *(const short8*)(pAw + nk * 2048 + ot * 512);
#pragma unroll
    for (int nt = 0; nt < 4; ++nt)
      nb[nt] = *(const short8*)((const char*)sX + Bb[nt] + off);
#pragma unroll
    for (int ot = 0; ot < 4; ++ot)
#pragma unroll
      for (int nt = 0; nt < 4; ++nt)
        acc[ot][nt] = MFMA(a[ot], bfr[nt], acc[ot][nt]);
#pragma unroll
    for (int ot = 0; ot < 4; ++ot) a[ot] = na[ot];
#pragma unroll
    for (int nt = 0; nt < 4; ++nt) bfr[nt] = nb[nt];
  }
#pragma unroll
  for (int ot = 0; ot < 4; ++ot)
#pragma unroll
    for (int nt = 0; nt < 4; ++nt)
      acc[ot][nt] = MFMA(a[ot], bfr[nt], acc[ot][nt]);
#pragma unroll
  for (int ot = 0; ot < 4; ++ot) {
    int o0 = ot * 16 + 4 * g;
    f32x4 b4 = *(const f32x4*)(bias + o0);
#pragma unroll
    for (int nt = 0; nt < 4; ++nt) {
      int p = nt * 16 + lr;
      int my = my0 + (p >> 3), mx = mx0 + (p & 7);
      int oy = 2 * my + pyr, ox = 2 * mx + pxr;
      short4v sv;
#pragma unroll
      for (int r = 0; r < 4; ++r)
        sv[r] = f2bf(fmaxf(acc[ot][nt][r] + b4[r], 0.f));
      *(short4v*)(T1 + ((b * 130 + oy + 1) * 130 + ox + 1) * 64 + o0) = sv;
    }
  }
}

// ============================================================================
// tconv2 MFMA v2 + fused finalize: T1[130,130,64] bf16 -> x_recon f32.
// Block 8192 (one extra) computes loss/perplexity (inputs were produced by
// vqm9, 5 dispatches earlier). grid 8193.
// ============================================================================
__global__ __launch_bounds__(256) void k_tconv2m(const short* __restrict__ T1,
    const float* __restrict__ w, const float* __restrict__ bias,
    float* __restrict__ out, const float* __restrict__ partials,
    const int* __restrict__ counts) {
  __shared__ short sT[112 * 72];  // 112 px * 144 B = 16,128 B
  __shared__ float sW[1024];
  __shared__ float sC[112 * 20];  // px stride 80 B (16-B aligned)
  int blk = blockIdx.x;
  int t = threadIdx.x;
  if (blk == 8192) {  // finalize: loss from 1024 partials; perplexity
    float s = 0.f;
    for (int i = t; i < 1024; i += 256) s += partials[i];
#pragma unroll
    for (int m = 32; m >= 1; m >>= 1) s += __shfl_xor(s, m);
    __shared__ float sr[4];
    if ((t & 63) == 0) sr[t >> 6] = s;
    __syncthreads();
    if (t == 0) {
      float tot = sr[0] + sr[1] + sr[2] + sr[3];
      out[0] = 1.25f * tot / 16777216.0f;
    }
    float h = 0.f;
    for (int c = t; c < KC; c += 256) {
      float avg = (float)counts[c] / 131072.0f;
      h += avg * logf(avg + 1e-10f);
    }
#pragma unroll
    for (int m = 32; m >= 1; m >>= 1) h += __shfl_xor(h, m);
    __shared__ float sr2[4];
    if ((t & 63) == 0) sr2[t >> 6] = h;
    __syncthreads();
    if (t == 0)
      out[1 + 32 * 256 * 256] = expf(-(sr2[0] + sr2[1] + sr2[2] + sr2[3]));
    return;
  }
  float* xrec = out + 1;
  int tx = blk & 15, ty = (blk >> 4) & 15, b = blk >> 8;
  for (int e = t; e < 1024; e += 256) sW[e] = w[e];
  for (int q = t; q < 800; q += 256) {
    int p = q >> 3, seg = q & 7;
    int iy = p / 10, ix = p - iy * 10;
    short8 v = *(const short8*)(T1 +
        (((long)b * 130 + ty * 8 + iy) * 130 + tx * 8 + ix) * 64 + seg * 8);
    *(short8*)((char*)sT + p * 144 + seg * 16) = v;
  }
  __syncthreads();
  int wv = t >> 6, l = t & 63, lr = l & 15, g = l >> 4;
  short8 af[4];
#pragma unroll
  for (int kc = 0; kc < 4; ++kc) {
#pragma unroll
    for (int j = 0; j < 8; ++j) {
      int k = kc * 32 + 8 * g + j;
      float val = sW[(k & 63) * 16 + lr];
      short hi = f2bf(val);
      af[kc][j] = (k < 64) ? hi : f2bf(val - bf2f(hi));
    }
  }
#pragma unroll
  for (int ti = 0; ti < 2; ++ti) {
    int tile = wv + 4 * ti;
    if (tile < 7) {
      f32x4 acc = {};
#pragma unroll
      for (int kc = 0; kc < 4; ++kc) {
        short8 bf = *(const short8*)((const char*)sT +
            (tile * 16 + lr) * 144 + ((kc & 1) * 64 + g * 16));
        acc = MFMA(af[kc], bf, acc);
      }
      *(f32x4*)(sC + (tile * 16 + lr) * 20 + g * 4) = acc;
    }
  }
  __syncthreads();
  int row = t >> 4, col = t & 15;
  int pyr = row & 1, pxr = col & 1;
  int ml = row >> 1, nl = col >> 1;
  int kye = 1 - pyr, kxe = 1 - pxr;
  float acc = bias[0];
#pragma unroll
  for (int dy = 0; dy < 2; ++dy)
#pragma unroll
    for (int dx = 0; dx < 2; ++dx) {
      int px = (ml + pyr - dy + 1) * 10 + (nl + pxr - dx + 1);
      int tap = (kye + 2 * dy) * 4 + (kxe + 2 * dx);
      acc += sC[px * 20 + tap];
    }
  int oy = ty * 16 + row, ox = tx * 16 + col;
  xrec[((long)b * 256 + oy) * 256 + ox] = acc;
}

// ============================================================================
extern "C" void kernel_launch(void* const* d_in, const int* in_sizes, int n_in,
                              void* d_out, int out_size, void* d_ws, size_t ws_size,
                              hipStream_t stream) {
  const float* x    = (const float*)d_in[0];
  const float* c1w  = (const float*)d_in[1];
  const float* c1b  = (const float*)d_in[2];
  const float* c2w  = (const float*)d_in[3];
  const float* c2b  = (const float*)d_in[4];
  const float* r1w3 = (const float*)d_in[5];
  const float* r1w1 = (const float*)d_in[6];
  const float* r2w3 = (const float*)d_in[7];
  const float* r2w1 = (const float*)d_in[8];
  const float* prew = (const float*)d_in[9];
  const float* preb = (const float*)d_in[10];
  const float* emb  = (const float*)d_in[11];
  const float* d1w3 = (const float*)d_in[12];
  const float* d1w1 = (const float*)d_in[13];
  const float* d2w3 = (const float*)d_in[14];
  const float* d2w1 = (const float*)d_in[15];
  const float* t1w  = (const float*)d_in[16];
  const float* t1b  = (const float*)d_in[17];
  const float* t2w  = (const float*)d_in[18];
  const float* t2b  = (const float*)d_in[19];
  float* out = (float*)d_out;

  char* ws = (char*)d_ws;
  short* buf0 = (short*)(ws);                      // A1 / T1 : 69,222,400 B
  float* bufX = (float*)(ws + 69222400);           // Xf / Zcat / Q : 67,108,864 B
  short* bufR = (short*)(ws + 136331264);          // XrP / QrP : 35,684,352 B
  int*   counts = (int*)(ws + 180928512);          // 2,048 B
  float* partials = (float*)(ws + 180930560);      // 8,192 B
  float* en   = (float*)(ws + 180938752);          // 2,048 B
  short* wAc2 = (short*)(ws + 180940800);          // 262,144 B
  short* wAr3 = (short*)(ws + 181202944);          // 294,912 B
  short* wAr1 = (short*)(ws + 181497856);          // 32,768 B
  short* wApre= (short*)(ws + 181530624);          // 32,768 B
  short* wAt1 = (short*)(ws + 181563392);          // 262,144 B
  short* Ecat = (short*)(ws + 181825536);          // 393,216 B -> ends 182,218,752

  short* Zcat = (short*)bufX;  // Zcat aliases Xf (k_resblk<2> reads Xf,
                               // writes the same bytes after a barrier)

  short* wAr3_e1 = wAr3;
  short* wAr3_e2 = wAr3 + 36864;
  short* wAr3_d1 = wAr3 + 2 * 36864;
  short* wAr3_d2 = wAr3 + 3 * 36864;
  short* wAr1_e1 = wAr1;
  short* wAr1_e2 = wAr1 + 4096;
  short* wAr1_d1 = wAr1 + 2 * 4096;
  short* wAr1_d2 = wAr1 + 3 * 4096;

  k_prep <<<6977, 256, 0, stream>>>(c2w, r1w3, r2w3, d1w3, d2w3,
                                    r1w1, r2w1, d1w1, d2w1, prew, t1w, emb,
                                    x, c1w, c1b,
                                    wAc2, wAr3, wAr1, wApre, wAt1, Ecat,
                                    en, buf0, bufR, counts);

  k_conv2m    <<<2048, 256, 0, stream>>>(buf0, wAc2, c2b, bufX, bufR);
  k_resblk<0> <<<1024, 256, 0, stream>>>(bufR, wAr3_e1, wAr1_e1, bufX, bufR,
                                         nullptr, nullptr, nullptr);
  k_resblk<2> <<<1024, 256, 0, stream>>>(bufR, wAr3_e2, wAr1_e2, bufX, nullptr,
                                         wApre, preb, Zcat);
  k_vqm9      <<<1024, 512, 0, stream>>>(Zcat, Ecat, en, emb, counts,
                                         partials, bufX, bufR);
  k_resblk<0> <<<1024, 256, 0, stream>>>(bufR, wAr3_d1, wAr1_d1, bufX, bufR,
                                         nullptr, nullptr, nullptr);
  k_resblk<1> <<<1024, 256, 0, stream>>>(bufR, wAr3_d2, wAr1_d2, bufX, bufR,
                                         nullptr, nullptr, nullptr);
  k_tconv1m   <<<2048, 256, 0, stream>>>(bufR, wAt1, t1b, buf0);
  k_tconv2m   <<<8193, 256, 0, stream>>>(buf0, t2w, t2b, out, partials,
                                         counts);
}

// Round 18
// 472.863 us; speedup vs baseline: 1.1036x; 1.0268x over previous
//
#include <hip/hip_runtime.h>
#include <math.h>

#define KC 512
#define DD 128

typedef __attribute__((ext_vector_type(8))) short short8;
typedef __attribute__((ext_vector_type(4))) short short4v;
typedef __attribute__((ext_vector_type(4))) float f32x4;

#define MFMA(a, b, c) __builtin_amdgcn_mfma_f32_16x16x32_bf16(a, b, c, 0, 0, 0)

__device__ __forceinline__ short f2bf(float f) {
  unsigned u = __float_as_uint(f);
  u = (u + 0x7FFFu + ((u >> 16) & 1u)) >> 16;
  return (short)u;
}
__device__ __forceinline__ float bf2f(short s) {
  return __uint_as_float(((unsigned)(unsigned short)s) << 16);
}

// ============================================================================
// k_prep: ALL weight permutations + embnorm + border-zero + counts-zero
// + conv1 (writes A1 INTERIOR only; border-zero writes the ring - disjoint).
// grid 6977 x 256
// ============================================================================
__global__ __launch_bounds__(256) void k_prep(
    const float* __restrict__ c2w,
    const float* __restrict__ r1w3, const float* __restrict__ r2w3,
    const float* __restrict__ d1w3, const float* __restrict__ d2w3,
    const float* __restrict__ r1w1, const float* __restrict__ r2w1,
    const float* __restrict__ d1w1, const float* __restrict__ d2w1,
    const float* __restrict__ prew, const float* __restrict__ t1w,
    const float* __restrict__ emb,
    const float* __restrict__ x, const float* __restrict__ c1w,
    const float* __restrict__ c1b,
    short* __restrict__ wAc2, short* __restrict__ wAr3,
    short* __restrict__ wAr1, short* __restrict__ wApre,
    short* __restrict__ wAt1, short* __restrict__ Ecat,
    float* __restrict__ en, short* __restrict__ A1,
    short* __restrict__ XrP, int* __restrict__ counts) {
  __shared__ float sXp[4 * 260];
  __shared__ float sWt[16 * 64];
  int blk = blockIdx.x, t = threadIdx.x;
  if (blk < 512) {  // perm_c2
    int e = blk * 256 + t;
    int j = e & 7, l = (e >> 3) & 63, ot = (e >> 9) & 7, kc = e >> 12;
    int o = ot * 16 + (l & 15), g = l >> 4;
    int tap = kc >> 1, ci = (kc & 1) * 32 + 8 * g + j;
    wAc2[e] = f2bf(c2w[(o * 64 + ci) * 16 + tap]);
  } else if (blk < 1088) {  // perm_r3 x4
    int sub = blk - 512;
    int which = sub / 144, bb = sub - which * 144;
    const float* w = which == 0 ? r1w3 : which == 1 ? r2w3
                     : which == 2 ? d1w3 : d2w3;
    short* dst = wAr3 + which * 36864;
    int e = bb * 256 + t;
    int j = e & 7, l = (e >> 3) & 63, ot = (e >> 9) & 1, kc = e >> 10;
    int o = ot * 16 + (l & 15), g = l >> 4;
    int tap = kc >> 2, ci = (kc & 3) * 32 + 8 * g + j;
    dst[e] = f2bf(w[(o * 128 + ci) * 9 + tap]);
  } else if (blk < 1152) {  // perm_r1 x4
    int sub = blk - 1088;
    int which = sub >> 4, bb = sub & 15;
    const float* w = which == 0 ? r1w1 : which == 1 ? r2w1
                     : which == 2 ? d1w1 : d2w1;
    short* dst = wAr1 + which * 4096;
    int e = bb * 256 + t;
    int j = e & 7, l = (e >> 3) & 63, ot = e >> 9;
    int o = ot * 16 + (l & 15), g = l >> 4;
    int ci = 8 * g + j;
    dst[e] = f2bf(w[o * 32 + ci]);
  } else if (blk < 1216) {  // perm_pre
    int e = (blk - 1152) * 256 + t;
    int j = e & 7, l = (e >> 3) & 63, ot = (e >> 9) & 7, kc = e >> 12;
    int o = ot * 16 + (l & 15), g = l >> 4;
    int ci = kc * 32 + 8 * g + j;
    wApre[e] = f2bf(prew[o * 128 + ci]);
  } else if (blk < 1728) {  // perm_t1
    int e = (blk - 1216) * 256 + t;
    int j = e & 7, l = (e >> 3) & 63, ot = (e >> 9) & 3, kc = (e >> 11) & 15,
        pp = e >> 15;
    int pyr = pp >> 1, pxr = pp & 1;
    int o = ot * 16 + (l & 15), g = l >> 4;
    int tt = kc >> 2, dy = tt >> 1, dx = tt & 1;
    int ky = (1 - pyr) + 2 * dy, kx = (1 - pxr) + 2 * dx;
    int ci = (kc & 3) * 32 + 8 * g + j;
    wAt1[e] = f2bf(t1w[(ci * 64 + o) * 16 + ky * 4 + kx]);
  } else if (blk < 2496) {  // perm_E
    int e = (blk - 1728) * 256 + t;
    int j = e & 7, l = (e >> 3) & 63, ot = (e >> 9) & 31, kc = e >> 14;
    int c = ot * 16 + (l & 15);
    int k = kc * 32 + 8 * (l >> 4) + j;
    float v = emb[c * DD + (k & 127)];
    short hi = f2bf(v);
    Ecat[e] = (k < 256) ? hi : f2bf(v - bf2f(hi));
  } else if (blk < 2624) {  // embnorm: 4 codes per block (wave = code)
    int c = (blk - 2496) * 4 + (t >> 6), l = t & 63;
    float a = emb[c * DD + l], b2 = emb[c * DD + 64 + l];
    float s = a * a + b2 * b2;
#pragma unroll
    for (int m = 32; m >= 1; m >>= 1) s += __shfl_xor(s, m);
    if (l == 0) en[c] = s;
  } else if (blk < 2880) {  // border zero
    int bb = blk - 2624;
    int b = bb >> 3;
    int tid = ((bb & 7) << 8) + t;  // 0..2047
    short8 z8 = {};
    long baseA = (long)b * 1081600;  // 130*130*64
    for (int e = tid; e < 2080; e += 2048) {
      int r = e >= 1040;
      int rem = r ? e - 1040 : e;
      *(short8*)(A1 + baseA + (r ? 129L * 130 * 64 : 0) + rem * 8) = z8;
    }
    {
      int c = tid >> 10, rem = tid & 1023;
      int row = 1 + (rem >> 3), s8 = rem & 7;
      *(short8*)(A1 + baseA + (row * 130L + (c ? 129 : 0)) * 64 + s8 * 8) = z8;
    }
    long baseX = (long)b * 557568;  // 66*66*128
    for (int e = tid; e < 2112; e += 2048) {
      int r = e >= 1056;
      int rem = r ? e - 1056 : e;
      *(short8*)(XrP + baseX + (r ? 65L * 66 * 128 : 0) + rem * 8) = z8;
    }
    {
      int c = tid >> 10, rem = tid & 1023;
      int row = 1 + (rem >> 4), s8 = rem & 15;
      *(short8*)(XrP + baseX + (row * 66L + (c ? 65 : 0)) * 128 + s8 * 8) = z8;
    }
  } else if (blk == 2880) {  // counts zero
    counts[t] = 0;
    counts[t + 256] = 0;
  } else {  // conv1 (interior of A1)
    int cb = blk - 2881;
    int y = cb & 127, b = cb >> 7;
    for (int e = t; e < 1024; e += 256) sWt[e] = c1w[(e & 63) * 16 + (e >> 6)];
    if (t < 4) {
      sXp[t * 260] = 0.f;
      sXp[t * 260 + 257] = 0.f;
      sXp[t * 260 + 258] = 0.f;
      sXp[t * 260 + 259] = 0.f;
    }
    for (int e = t; e < 1024; e += 256) {
      int r = e >> 8, col = e & 255;
      int giy = 2 * y - 1 + r;
      float v = 0.f;
      if ((unsigned)giy < 256u) v = x[(b * 256 + giy) * 256 + col];
      sXp[r * 260 + col + 1] = v;
    }
    __syncthreads();
    int og = t >> 6, l = t & 63, o0 = og * 16;
    float acc0[16], acc1[16];
#pragma unroll
    for (int oo = 0; oo < 16; ++oo) { acc0[oo] = 0.f; acc1[oo] = 0.f; }
    int xA = 2 * l, xB = 2 * l + 128;
#pragma unroll
    for (int ky = 0; ky < 4; ++ky) {
#pragma unroll
      for (int kx = 0; kx < 4; ++kx) {
        float a0 = sXp[ky * 260 + xA + kx];
        float a1 = sXp[ky * 260 + xB + kx];
        const float* wrow = &sWt[(ky * 4 + kx) * 64 + o0];
#pragma unroll
        for (int oo = 0; oo < 16; ++oo) {
          float wv = wrow[oo];
          acc0[oo] = fmaf(a0, wv, acc0[oo]);
          acc1[oo] = fmaf(a1, wv, acc1[oo]);
        }
      }
    }
    long base0 = (((long)(b * 130 + y + 1)) * 130 + l + 1) * 64 + o0;
    long base1 = base0 + 64 * 64;
    short8 s0a, s0b, s1a, s1b;
#pragma unroll
    for (int oo = 0; oo < 8; ++oo) {
      s0a[oo] = f2bf(fmaxf(acc0[oo] + c1b[o0 + oo], 0.f));
      s0b[oo] = f2bf(fmaxf(acc0[oo + 8] + c1b[o0 + oo + 8], 0.f));
      s1a[oo] = f2bf(fmaxf(acc1[oo] + c1b[o0 + oo], 0.f));
      s1b[oo] = f2bf(fmaxf(acc1[oo + 8] + c1b[o0 + oo + 8], 0.f));
    }
    *(short8*)(A1 + base0) = s0a;
    *(short8*)(A1 + base0 + 8) = s0b;
    *(short8*)(A1 + base1) = s1a;
    *(short8*)(A1 + base1 + 8) = s1b;
  }
}

// ============================================================================
// conv2 MFMA v2 (LDS-staged input, register depth-1 weight prefetch):
// A1[130,130,64] bf16 -> relu -> Xf[64,64,128] f32 + XrP[66,66,128] bf16.
// grid 2048 = 32 b x 8 by x 8 bx
// ============================================================================
__global__ __launch_bounds__(256) void k_conv2m(const short* __restrict__ A1,
    const short* __restrict__ wA, const float* __restrict__ bias,
    float* __restrict__ Xf, short* __restrict__ XrP) {
  __shared__ short sX[22032];  // 324 px * 68 shorts (136 B) = 44,064 B
  int blk = blockIdx.x;
  int bx = blk & 7, by = (blk >> 3) & 7, b = blk >> 6;
  int t = threadIdx.x;
  int R0 = by * 16, C0 = bx * 16;
  for (int q = t; q < 2592; q += 256) {
    int p = q >> 3, seg = q & 7;
    int iy = p / 18, ix = p - iy * 18;
    short8 v = *(const short8*)(A1 +
        (((long)b * 130 + R0 + iy) * 130 + C0 + ix) * 64 + seg * 8);
    *(short8*)((char*)sX + p * 136 + seg * 16) = v;
  }
  __syncthreads();
  int w = t >> 6, l = t & 63, lr = l & 15, g = l >> 4;
  int Bb[4];
#pragma unroll
  for (int pt = 0; pt < 4; ++pt) {
    int p = pt * 16 + lr;
    int lp = 2 * (p >> 3) * 18 + 2 * (p & 7);
    Bb[pt] = lp * 136 + g * 16;
  }
  const short* pA0 = wA + (2 * w * 64 + l) * 8;
  const short* pA1 = pA0 + 512;
  f32x4 acc[2][4] = {};
  short8 a0 = *(const short8*)pA0;
  short8 a1 = *(const short8*)pA1;
  short8 bv[4];
#pragma unroll
  for (int i = 0; i < 4; ++i)
    bv[i] = *(const short8*)((const char*)sX + Bb[i]);
  for (int kc = 0; kc < 31; ++kc) {
    int nk = kc + 1;
    int tap = nk >> 1;
    int off = ((tap >> 2) * 18 + (tap & 3)) * 136 + (nk & 1) * 64;
    short8 na0 = *(const short8*)(pA0 + nk * 4096);
    short8 na1 = *(const short8*)(pA1 + nk * 4096);
    short8 nb[4];
#pragma unroll
    for (int i = 0; i < 4; ++i)
      nb[i] = *(const short8*)((const char*)sX + Bb[i] + off);
#pragma unroll
    for (int i = 0; i < 4; ++i) {
      acc[0][i] = MFMA(a0, bv[i], acc[0][i]);
      acc[1][i] = MFMA(a1, bv[i], acc[1][i]);
    }
    a0 = na0; a1 = na1;
#pragma unroll
    for (int i = 0; i < 4; ++i) bv[i] = nb[i];
  }
#pragma unroll
  for (int i = 0; i < 4; ++i) {
    acc[0][i] = MFMA(a0, bv[i], acc[0][i]);
    acc[1][i] = MFMA(a1, bv[i], acc[1][i]);
  }
#pragma unroll
  for (int oi = 0; oi < 2; ++oi) {
    int o0 = (2 * w + oi) * 16 + 4 * g;
#pragma unroll
    for (int pt = 0; pt < 4; ++pt) {
      int p = pt * 16 + lr;
      int y = by * 8 + (p >> 3), x = bx * 8 + (p & 7);
      f32x4 nv; short4v sv;
#pragma unroll
      for (int r = 0; r < 4; ++r) {
        float v = fmaxf(acc[oi][pt][r] + bias[o0 + r], 0.f);
        nv[r] = v; sv[r] = f2bf(v);
      }
      *(f32x4*)(Xf + ((b * 64 + y) * 64 + x) * 128 + o0) = nv;
      *(short4v*)(XrP + ((b * 66 + y + 1) * 66 + x + 1) * 128 + o0) = sv;
    }
  }
}

// ============================================================================
// resblk fused: res3 (3x3 conv, XrP -> H in LDS) + res1 (1x1 conv + residual).
// Block = 8x16 out-px (res3m tiling), grid 1024 = 32 b x 8 yt x 4 tx.
// MODE 0: residual from Xf; write Xf + XrPout.
// MODE 1: residual from Xf; write XrPout only.
// MODE 2: encoder tail - residual from Xf; xr stays in LDS, then prem -> Zcat
//         (Zc aliases Xf, barrier-ordered).
// MODE 3: decoder head - residual = emb[idx[pix]] (L2-resident gather;
//         eliminates the 64 MB Q materialization); write Xf + XrPout.
// ============================================================================
template <int MODE>
__global__ __launch_bounds__(256) void k_resblk(
    const short* __restrict__ XrPin, const short* __restrict__ wA3,
    const short* __restrict__ wA1, float* Xf, short* XrPout,
    const short* __restrict__ wAp, const float* __restrict__ preb,
    short* Zc, const float* __restrict__ embp, const int* __restrict__ idxb) {
  __shared__ short sX[23040];  // phase1 XrP tile; MODE2 phase2 reuses as sXr
  __shared__ short sH[128 * 40];  // H: 128 px * 40 sh (80 B stride)
  int blk = blockIdx.x;
  int tx = blk & 3, yt = (blk >> 2) & 7, b = blk >> 5;
  int t = threadIdx.x;
  int r0 = yt * 8, c0 = tx * 16;
  for (int q = t; q < 2880; q += 256) {
    int p = q >> 4, seg = q & 15;
    int iy = p / 18, ix = p - iy * 18;
    short8 v = *(const short8*)(XrPin +
        (((long)b * 66 + r0 + iy) * 66 + c0 + ix) * 128 + seg * 8);
    *(short8*)((char*)sX + p * 256 + ((seg * 16) ^ ((p & 7) << 4))) = v;
  }
  __syncthreads();
  int w = t >> 6, l = t & 63, lr = l & 15, g = l >> 4;
  // ---- phase 1: res3 3x3 conv, H -> sH ----
  {
    const short* pA0 = wA3 + l * 8;
    const short* pA1 = pA0 + 512;
    f32x4 acc[2][2] = {};
    short8 a0 = *(const short8*)pA0;
    short8 a1 = *(const short8*)pA1;
    short8 bv[2];
#pragma unroll
    for (int j = 0; j < 2; ++j) {
      int lp = (2 * w + j) * 18 + lr;
      bv[j] = *(const short8*)((const char*)sX + lp * 256 +
                               ((g * 16) ^ ((lp & 7) << 4)));
    }
    for (int kc = 0; kc < 35; ++kc) {
      int nk = kc + 1;
      int tap = nk >> 2;
      int ky = tap / 3, kx = tap - ky * 3;
      int inner = g * 16 + (nk & 3) * 64;
      short8 na0 = *(const short8*)(pA0 + nk * 1024);
      short8 na1 = *(const short8*)(pA1 + nk * 1024);
      short8 nb[2];
#pragma unroll
      for (int j = 0; j < 2; ++j) {
        int lp = (2 * w + j + ky) * 18 + lr + kx;
        nb[j] = *(const short8*)((const char*)sX + lp * 256 +
                                 (inner ^ ((lp & 7) << 4)));
      }
#pragma unroll
      for (int j = 0; j < 2; ++j) {
        acc[0][j] = MFMA(a0, bv[j], acc[0][j]);
        acc[1][j] = MFMA(a1, bv[j], acc[1][j]);
      }
      a0 = na0; a1 = na1;
      bv[0] = nb[0]; bv[1] = nb[1];
    }
#pragma unroll
    for (int j = 0; j < 2; ++j) {
      acc[0][j] = MFMA(a0, bv[j], acc[0][j]);
      acc[1][j] = MFMA(a1, bv[j], acc[1][j]);
    }
#pragma unroll
    for (int oi = 0; oi < 2; ++oi) {
      int o0 = oi * 16 + 4 * g;
#pragma unroll
      for (int j = 0; j < 2; ++j) {
        int p = (2 * w + j) * 16 + lr;
        short4v sv;
#pragma unroll
        for (int r = 0; r < 4; ++r) sv[r] = f2bf(fmaxf(acc[oi][j][r], 0.f));
        *(short4v*)(sH + p * 40 + o0) = sv;
      }
    }
  }
  __syncthreads();
  // ---- phase 2: res1 1x1 conv + residual over 128 px ----
  {
    f32x4 acc[2][8] = {};
    short8 a0 = *(const short8*)(wA1 + (2 * w * 64 + l) * 8);
    short8 a1 = *(const short8*)(wA1 + ((2 * w + 1) * 64 + l) * 8);
#pragma unroll
    for (int pt = 0; pt < 8; ++pt) {
      short8 bv = *(const short8*)(sH + (pt * 16 + lr) * 40 + 8 * g);
      acc[0][pt] = MFMA(a0, bv, acc[0][pt]);
      acc[1][pt] = MFMA(a1, bv, acc[1][pt]);
    }
#pragma unroll
    for (int oi = 0; oi < 2; ++oi) {
      int o0 = (2 * w + oi) * 16 + 4 * g;
#pragma unroll
      for (int pt = 0; pt < 8; ++pt) {
        int y = r0 + pt, x = c0 + lr;
        float* xp = Xf + ((b * 64 + y) * 64 + x) * 128 + o0;
        f32x4 old;
        if (MODE == 3) {
          int cix = idxb[(b * 64 + y) * 64 + x];
          old = *(const f32x4*)(embp + cix * DD + o0);
        } else {
          old = *(f32x4*)xp;
        }
        f32x4 nv; short4v sv;
#pragma unroll
        for (int r = 0; r < 4; ++r) {
          nv[r] = old[r] + acc[oi][pt][r];
          sv[r] = f2bf(fmaxf(nv[r], 0.f));
        }
        if (MODE == 0 || MODE == 3) *(f32x4*)xp = nv;
        if (MODE != 2) {
          *(short4v*)(XrPout + ((b * 66 + y + 1) * 66 + x + 1) * 128 + o0) =
              sv;
        } else {
          int p = pt * 16 + lr;
          *(short4v*)((char*)sX + p * 256 + ((o0 * 2) ^ ((p & 7) << 4))) = sv;
        }
      }
    }
  }
  if (MODE == 2) {
    __syncthreads();
    // ---- phase 3: prem 1x1 conv over xr (in sX), write Zcat ----
    const short* pA0 = wAp + (2 * w * 64 + l) * 8;
    const short* pA1 = pA0 + 512;
    f32x4 acc[2][8] = {};
#pragma unroll
    for (int kc = 0; kc < 4; ++kc) {
      short8 a0 = *(const short8*)(pA0 + kc * 4096);
      short8 a1 = *(const short8*)(pA1 + kc * 4096);
#pragma unroll
      for (int pt = 0; pt < 8; ++pt) {
        int p = pt * 16 + lr;
        short8 bv = *(const short8*)((const char*)sX + p * 256 +
                                     ((kc * 64 + g * 16) ^ ((p & 7) << 4)));
        acc[0][pt] = MFMA(a0, bv, acc[0][pt]);
        acc[1][pt] = MFMA(a1, bv, acc[1][pt]);
      }
    }
#pragma unroll
    for (int oi = 0; oi < 2; ++oi) {
      int o0 = (2 * w + oi) * 16 + 4 * g;
#pragma unroll
      for (int pt = 0; pt < 8; ++pt) {
        int y = r0 + pt, x = c0 + lr;
        long pix = (long)(b * 64 + y) * 64 + x;
        short4v hv, lv;
#pragma unroll
        for (int r = 0; r < 4; ++r) {
          float v = acc[oi][pt][r] + preb[o0 + r];
          short hi = f2bf(v);
          hv[r] = hi;
          lv[r] = f2bf(v - bf2f(hi));
        }
        *(short4v*)(Zc + pix * 256 + o0) = hv;
        *(short4v*)(Zc + pix * 256 + 128 + o0) = lv;
      }
    }
  }
}

#define GLOAD_LDS16(g, l)                                        \
  __builtin_amdgcn_global_load_lds(                              \
      (const __attribute__((address_space(1))) void*)(g),        \
      (__attribute__((address_space(3))) void*)(l), 16, 0, 0)

// ============================================================================
// VQ MFMA v10 (async E-staging, 128 px, idx output): 128 px x 512 codes,
// 8 waves (512 thr), grid 1024. Writes idx (0.5 MB) instead of Q (64 MB) -
// the decoder head re-gathers emb[idx] from L2 (k_resblk<3>). QrP unchanged.
// ============================================================================
__global__ __launch_bounds__(512) void k_vqm9(const short* __restrict__ Zc,
    const short* __restrict__ Ec, const float* __restrict__ en,
    const float* __restrict__ emb, int* __restrict__ counts,
    float* __restrict__ partials, int* __restrict__ idx_out,
    short* __restrict__ QrP) {
  __shared__ short sZ[32768];  // 128 px * 256 sh, swizzled = 64 KB
  __shared__ short sE[16384];  // E slab: 8 wave-regions x 2048 sh = 32 KB
  __shared__ float sV[8][128];
  __shared__ int sC[8][128];
  __shared__ float sZn[128];
  __shared__ int sIdx[128];
  __shared__ int sHist[KC];
  int blk = blockIdx.x;
  long pix0 = (long)blk * 128;
  int t = threadIdx.x, w = t >> 6, l = t & 63, c16 = l & 15, g = (l >> 4) & 3;
  for (int e = t; e < KC; e += 512) sHist[e] = 0;

  // stage Z tile: swizzle inner-byte ^ ((pix&7)<<4)
  for (int q = t; q < 4096; q += 512) {
    int p = q >> 5, seg = q & 31;
    short8 v = *(const short8*)(Zc + (pix0 + p) * 256 + seg * 8);
    *(short8*)((char*)sZ + p * 512 + ((seg * 16) ^ ((p & 7) << 4))) = v;
  }
  __syncthreads();

  // ||z||^2 per pixel from LDS: 4 threads/pixel, each 32 dims (128 px)
  {
    int pz = t >> 2, seg4 = t & 3;
    const char* zb = (const char*)sZ + pz * 512;
    int swp = (pz & 7) << 4;
    float s = 0.f;
#pragma unroll
    for (int qq = 0; qq < 4; ++qq) {
      int ih = seg4 * 64 + 16 * qq;  // zh inner byte
      short8 h8 = *(const short8*)(zb + (ih ^ swp));
      short8 l8 = *(const short8*)(zb + ((ih + 256) ^ swp));
#pragma unroll
      for (int j = 0; j < 8; ++j) {
        float zv = bf2f(h8[j]) + bf2f(l8[j]);
        s = fmaf(zv, zv, s);
      }
    }
    s += __shfl_xor(s, 1);
    s += __shfl_xor(s, 2);
    if (seg4 == 0) sZn[pz] = s;
  }

  // GEMM: 12 K-steps of 32; wave-local async E staging; 8 pixel-tiles.
  int sw = (c16 & 7) << 4;
  int zrow = c16 * 512;
  short* sEw = sE + w * 2048;                   // wave-uniform LDS base
  const short* gEw = Ec + w * 2048 + l * 8;     // per-lane global src
  f32x4 acc[4][8] = {};
  for (int kc = 0; kc < 12; ++kc) {
    if (kc) asm volatile("s_waitcnt lgkmcnt(0)" ::: "memory");
#pragma unroll
    for (int i = 0; i < 4; ++i)
      GLOAD_LDS16(gEw + kc * 16384 + i * 512, sEw + i * 512);
    asm volatile("s_waitcnt vmcnt(0)" ::: "memory");
    int koff = kc < 8 ? kc : kc - 8;
    int inn = ((koff * 64 + g * 16) ^ sw);
    const char* zb = (const char*)sZ + zrow + inn;
    short8 a0 = *(const short8*)(sEw + l * 8);
    short8 a1 = *(const short8*)(sEw + 512 + l * 8);
    short8 a2 = *(const short8*)(sEw + 1024 + l * 8);
    short8 a3 = *(const short8*)(sEw + 1536 + l * 8);
#pragma unroll
    for (int pt = 0; pt < 8; ++pt) {
      short8 bb = *(const short8*)(zb + pt * 8192);
      acc[0][pt] = MFMA(a0, bb, acc[0][pt]);
      acc[1][pt] = MFMA(a1, bb, acc[1][pt]);
      acc[2][pt] = MFMA(a2, bb, acc[2][pt]);
      acc[3][pt] = MFMA(a3, bb, acc[3][pt]);
    }
  }
  // running argmin over the wave's 64 codes (codes ascend: ct, r)
  float bvv[8];
  int bcc[8];
#pragma unroll
  for (int pt = 0; pt < 8; ++pt) { bvv[pt] = 3.4e38f; bcc[pt] = 0; }
#pragma unroll
  for (int ct = 0; ct < 4; ++ct) {
    f32x4 en4 = *(const f32x4*)(en + w * 64 + ct * 16 + 4 * g);
#pragma unroll
    for (int pt = 0; pt < 8; ++pt) {
#pragma unroll
      for (int r = 0; r < 4; ++r) {
        float d = en4[r] - 2.f * acc[ct][pt][r];
        int code = w * 64 + ct * 16 + 4 * g + r;
        if (d < bvv[pt]) { bvv[pt] = d; bcc[pt] = code; }
      }
    }
  }
  // cross-lane reduce (over g) per pixel
#pragma unroll
  for (int pt = 0; pt < 8; ++pt) {
    float bv = bvv[pt];
    int bc = bcc[pt];
#pragma unroll
    for (int m = 16; m <= 32; m <<= 1) {
      float ov = __shfl_xor(bv, m);
      int oc = __shfl_xor(bc, m);
      if (ov < bv || (ov == bv && oc < bc)) { bv = ov; bc = oc; }
    }
    if (g == 0) {
      sV[w][pt * 16 + c16] = bv;
      sC[w][pt * 16 + c16] = bc;
    }
  }
  __syncthreads();
  if (t < 128) {
    float bv = sV[0][t];
    int bc = sC[0][t];
#pragma unroll
    for (int w2 = 1; w2 < 8; ++w2) {
      float v = sV[w2][t];
      int c = sC[w2][t];
      if (v < bv || (v == bv && c < bc)) { bv = v; bc = c; }
    }
    sIdx[t] = bc;
    idx_out[pix0 + t] = bc;
    atomicAdd(&sHist[bc], 1);
    sV[0][t] = bv + sZn[t];
  }
  __syncthreads();
  if (t < 64) {
    float ls = sV[0][t] + sV[0][t + 64];
#pragma unroll
    for (int m = 32; m >= 1; m >>= 1) ls += __shfl_xor(ls, m);
    if (t == 0) partials[blk] = ls;
  }
  for (int e = t; e < KC; e += 512) {
    int c = sHist[e];
    if (c) atomicAdd(&counts[e], c);
  }
  // fused gather: QrP = relu(emb[idx]) bf16 (padded layout); Q f32 is NOT
  // materialized (decoder re-gathers from L2-resident emb via idx).
  for (int e = t; e < 4096; e += 512) {
    int p = e >> 5, d4 = (e & 31) << 2;
    int c = sIdx[p];
    f32x4 q = *(const f32x4*)(emb + c * DD + d4);
    short4v sv;
#pragma unroll
    for (int r = 0; r < 4; ++r) sv[r] = f2bf(fmaxf(q[r], 0.f));
    long pixg = pix0 + p;
    int xx = (int)(pixg & 63), yy = (int)((pixg >> 6) & 63),
        bb = (int)(pixg >> 12);
    *(short4v*)(QrP + (((long)(bb * 66 + yy + 1)) * 66 + xx + 1) * 128 + d4) =
        sv;
  }
}

// ============================================================================
// tconv1 MFMA v2 (LDS-staged input, register depth-1 weight prefetch):
// QrP[66,66,128] -> T1[130,130,64] bf16 relu.
// grid 2048 = 32 b x 8 tyt x 8 txt
// ============================================================================
__global__ __launch_bounds__(256) void k_tconv1m(const short* __restrict__ QrP,
    const short* __restrict__ wA, const float* __restrict__ bias,
    short* __restrict__ T1) {
  __shared__ short sX[13600];  // 100 pixels x 136 shorts
  int blk = blockIdx.x;
  int txt = blk & 7, tyt = (blk >> 3) & 7, b = blk >> 6;
  int my0 = tyt * 8, mx0 = txt * 8;
  int t = threadIdx.x;
  for (int q = t; q < 1600; q += 256) {
    int p = q >> 4, seg = q & 15;
    int iy = p / 10, ix = p - iy * 10;
    short8 v = *(const short8*)(QrP +
        ((b * 66 + my0 + iy) * 66 + mx0 + ix) * 128 + seg * 8);
    *(short8*)((char*)sX + p * 272 + seg * 16) = v;
  }
  __syncthreads();
  int w = t >> 6, l = t & 63, lr = l & 15, g = l >> 4;
  int pyr = w >> 1, pxr = w & 1;
  int Bb[4];
#pragma unroll
  for (int nt = 0; nt < 4; ++nt) {
    int p = nt * 16 + lr;
    int my = p >> 3, mx = p & 7;
    Bb[nt] = ((my + pyr + 1) * 10 + (mx + pxr + 1)) * 272 + g * 16;
  }
  const short* pAw = wA + w * 32768 + l * 8;
  f32x4 acc[4][4] = {};
  short8 a[4], bfr[4], na[4], nb[4];
#pragma unroll
  for (int ot = 0; ot < 4; ++ot) a[ot] = *(const short8*)(pAw + ot * 512);
#pragma unroll
  for (int nt = 0; nt < 4; ++nt)
    bfr[nt] = *(const short8*)((const char*)sX + Bb[nt]);
  for (int kc = 0; kc < 15; ++kc) {
    int nk = kc + 1;
    int tt = nk >> 2, dy = tt >> 1, dx = tt & 1;
    int off = -(dy * 10 + dx) * 272 + (nk & 3) * 64;
#pragma unroll
    for (int ot = 0; ot < 4; ++ot)
      na[ot] = *(const short8*)(pAw + nk * 2048 + ot * 512);
#pragma unroll
    for (int nt = 0; nt < 4; ++nt)
      nb[nt] = *(const short8*)((const char*)sX + Bb[nt] + off);
#pragma unroll
    for (int ot = 0; ot < 4; ++ot)
#pragma unroll
      for (int nt = 0; nt < 4; ++nt)
        acc[ot][nt] = MFMA(a[ot], bfr[nt], acc[ot][nt]);
#pragma unroll
    for (int ot = 0; ot < 4; ++ot) a[ot] = na[ot];
#pragma unroll
    for (int nt = 0; nt < 4; ++nt) bfr[nt] = nb[nt];
  }
#pragma unroll
  for (int ot = 0; ot < 4; ++ot)
#pragma unroll
    for (int nt = 0; nt < 4; ++nt)
      acc[ot][nt] = MFMA(a[ot], bfr[nt], acc[ot][nt]);
#pragma unroll
  for (int ot = 0; ot < 4; ++ot) {
    int o0 = ot * 16 + 4 * g;
    f32x4 b4 = *(const f32x4*)(bias + o0);
#pragma unroll
    for (int nt = 0; nt < 4; ++nt) {
      int p = nt * 16 + lr;
      int my = my0 + (p >> 3), mx = mx0 + (p & 7);
      int oy = 2 * my + pyr, ox = 2 * mx + pxr;
      short4v sv;
#pragma unroll
      for (int r = 0; r < 4; ++r)
        sv[r] = f2bf(fmaxf(acc[ot][nt][r] + b4[r], 0.f));
      *(short4v*)(T1 + ((b * 130 + oy + 1) * 130 + ox + 1) * 64 + o0) = sv;
    }
  }
}

// ============================================================================
// tconv2 MFMA v2 + fused finalize: T1[130,130,64] bf16 -> x_recon f32.
// Block 8192 (one extra) computes loss/perplexity. grid 8193.
// ============================================================================
__global__ __launch_bounds__(256) void k_tconv2m(const short* __restrict__ T1,
    const float* __restrict__ w, const float* __restrict__ bias,
    float* __restrict__ out, const float* __restrict__ partials,
    const int* __restrict__ counts) {
  __shared__ short sT[112 * 72];  // 112 px * 144 B = 16,128 B
  __shared__ float sW[1024];
  __shared__ float sC[112 * 20];  // px stride 80 B (16-B aligned)
  int blk = blockIdx.x;
  int t = threadIdx.x;
  if (blk == 8192) {  // finalize: loss from 1024 partials; perplexity
    float s = 0.f;
    for (int i = t; i < 1024; i += 256) s += partials[i];
#pragma unroll
    for (int m = 32; m >= 1; m >>= 1) s += __shfl_xor(s, m);
    __shared__ float sr[4];
    if ((t & 63) == 0) sr[t >> 6] = s;
    __syncthreads();
    if (t == 0) {
      float tot = sr[0] + sr[1] + sr[2] + sr[3];
      out[0] = 1.25f * tot / 16777216.0f;
    }
    float h = 0.f;
    for (int c = t; c < KC; c += 256) {
      float avg = (float)counts[c] / 131072.0f;
      h += avg * logf(avg + 1e-10f);
    }
#pragma unroll
    for (int m = 32; m >= 1; m >>= 1) h += __shfl_xor(h, m);
    __shared__ float sr2[4];
    if ((t & 63) == 0) sr2[t >> 6] = h;
    __syncthreads();
    if (t == 0)
      out[1 + 32 * 256 * 256] = expf(-(sr2[0] + sr2[1] + sr2[2] + sr2[3]));
    return;
  }
  float* xrec = out + 1;
  int tx = blk & 15, ty = (blk >> 4) & 15, b = blk >> 8;
  for (int e = t; e < 1024; e += 256) sW[e] = w[e];
  for (int q = t; q < 800; q += 256) {
    int p = q >> 3, seg = q & 7;
    int iy = p / 10, ix = p - iy * 10;
    short8 v = *(const short8*)(T1 +
        (((long)b * 130 + ty * 8 + iy) * 130 + tx * 8 + ix) * 64 + seg * 8);
    *(short8*)((char*)sT + p * 144 + seg * 16) = v;
  }
  __syncthreads();
  int wv = t >> 6, l = t & 63, lr = l & 15, g = l >> 4;
  short8 af[4];
#pragma unroll
  for (int kc = 0; kc < 4; ++kc) {
#pragma unroll
    for (int j = 0; j < 8; ++j) {
      int k = kc * 32 + 8 * g + j;
      float val = sW[(k & 63) * 16 + lr];
      short hi = f2bf(val);
      af[kc][j] = (k < 64) ? hi : f2bf(val - bf2f(hi));
    }
  }
#pragma unroll
  for (int ti = 0; ti < 2; ++ti) {
    int tile = wv + 4 * ti;
    if (tile < 7) {
      f32x4 acc = {};
#pragma unroll
      for (int kc = 0; kc < 4; ++kc) {
        short8 bf = *(const short8*)((const char*)sT +
            (tile * 16 + lr) * 144 + ((kc & 1) * 64 + g * 16));
        acc = MFMA(af[kc], bf, acc);
      }
      *(f32x4*)(sC + (tile * 16 + lr) * 20 + g * 4) = acc;
    }
  }
  __syncthreads();
  int row = t >> 4, col = t & 15;
  int pyr = row & 1, pxr = col & 1;
  int ml = row >> 1, nl = col >> 1;
  int kye = 1 - pyr, kxe = 1 - pxr;
  float acc = bias[0];
#pragma unroll
  for (int dy = 0; dy < 2; ++dy)
#pragma unroll
    for (int dx = 0; dx < 2; ++dx) {
      int px = (ml + pyr - dy + 1) * 10 + (nl + pxr - dx + 1);
      int tap = (kye + 2 * dy) * 4 + (kxe + 2 * dx);
      acc += sC[px * 20 + tap];
    }
  int oy = ty * 16 + row, ox = tx * 16 + col;
  xrec[((long)b * 256 + oy) * 256 + ox] = acc;
}

// ============================================================================
extern "C" void kernel_launch(void* const* d_in, const int* in_sizes, int n_in,
                              void* d_out, int out_size, void* d_ws, size_t ws_size,
                              hipStream_t stream) {
  const float* x    = (const float*)d_in[0];
  const float* c1w  = (const float*)d_in[1];
  const float* c1b  = (const float*)d_in[2];
  const float* c2w  = (const float*)d_in[3];
  const float* c2b  = (const float*)d_in[4];
  const float* r1w3 = (const float*)d_in[5];
  const float* r1w1 = (const float*)d_in[6];
  const float* r2w3 = (const float*)d_in[7];
  const float* r2w1 = (const float*)d_in[8];
  const float* prew = (const float*)d_in[9];
  const float* preb = (const float*)d_in[10];
  const float* emb  = (const float*)d_in[11];
  const float* d1w3 = (const float*)d_in[12];
  const float* d1w1 = (const float*)d_in[13];
  const float* d2w3 = (const float*)d_in[14];
  const float* d2w1 = (const float*)d_in[15];
  const float* t1w  = (const float*)d_in[16];
  const float* t1b  = (const float*)d_in[17];
  const float* t2w  = (const float*)d_in[18];
  const float* t2b  = (const float*)d_in[19];
  float* out = (float*)d_out;

  char* ws = (char*)d_ws;
  short* buf0 = (short*)(ws);                      // A1 / T1 : 69,222,400 B
  float* bufX = (float*)(ws + 69222400);           // Xf / Zcat : 67,108,864 B
  short* bufR = (short*)(ws + 136331264);          // XrP / QrP : 35,684,352 B
  int*   idx  = (int*)(ws + 180404224);            // 524,288 B
  int*   counts = (int*)(ws + 180928512);          // 2,048 B
  float* partials = (float*)(ws + 180930560);      // 8,192 B
  float* en   = (float*)(ws + 180938752);          // 2,048 B
  short* wAc2 = (short*)(ws + 180940800);          // 262,144 B
  short* wAr3 = (short*)(ws + 181202944);          // 294,912 B
  short* wAr1 = (short*)(ws + 181497856);          // 32,768 B
  short* wApre= (short*)(ws + 181530624);          // 32,768 B
  short* wAt1 = (short*)(ws + 181563392);          // 262,144 B
  short* Ecat = (short*)(ws + 181825536);          // 393,216 B -> ends 182,218,752

  short* Zcat = (short*)bufX;  // Zcat aliases Xf (k_resblk<2> reads Xf,
                               // writes the same bytes after a barrier;
                               // k_resblk<3> later overwrites with dec Xf)

  short* wAr3_e1 = wAr3;
  short* wAr3_e2 = wAr3 + 36864;
  short* wAr3_d1 = wAr3 + 2 * 36864;
  short* wAr3_d2 = wAr3 + 3 * 36864;
  short* wAr1_e1 = wAr1;
  short* wAr1_e2 = wAr1 + 4096;
  short* wAr1_d1 = wAr1 + 2 * 4096;
  short* wAr1_d2 = wAr1 + 3 * 4096;

  k_prep <<<6977, 256, 0, stream>>>(c2w, r1w3, r2w3, d1w3, d2w3,
                                    r1w1, r2w1, d1w1, d2w1, prew, t1w, emb,
                                    x, c1w, c1b,
                                    wAc2, wAr3, wAr1, wApre, wAt1, Ecat,
                                    en, buf0, bufR, counts);

  k_conv2m    <<<2048, 256, 0, stream>>>(buf0, wAc2, c2b, bufX, bufR);
  k_resblk<0> <<<1024, 256, 0, stream>>>(bufR, wAr3_e1, wAr1_e1, bufX, bufR,
                                         nullptr, nullptr, nullptr,
                                         nullptr, nullptr);
  k_resblk<2> <<<1024, 256, 0, stream>>>(bufR, wAr3_e2, wAr1_e2, bufX, nullptr,
                                         wApre, preb, Zcat, nullptr, nullptr);
  k_vqm9      <<<1024, 512, 0, stream>>>(Zcat, Ecat, en, emb, counts,
                                         partials, idx, bufR);
  k_resblk<3> <<<1024, 256, 0, stream>>>(bufR, wAr3_d1, wAr1_d1, bufX, bufR,
                                         nullptr, nullptr, nullptr,
                                         emb, idx);
  k_resblk<1> <<<1024, 256, 0, stream>>>(bufR, wAr3_d2, wAr1_d2, bufX, bufR,
                                         nullptr, nullptr, nullptr,
                                         nullptr, nullptr);
  k_tconv1m   <<<2048, 256, 0, stream>>>(bufR, wAt1, t1b, buf0);
  k_tconv2m   <<<8193, 256, 0, stream>>>(buf0, t2w, t2b, out, partials,
                                         counts);
}

// Round 19
// 464.383 us; speedup vs baseline: 1.1238x; 1.0183x over previous
//
#include <hip/hip_runtime.h>
#include <math.h>

#define KC 512
#define DD 128

typedef __attribute__((ext_vector_type(8))) short short8;
typedef __attribute__((ext_vector_type(4))) short short4v;
typedef __attribute__((ext_vector_type(4))) float f32x4;

#define MFMA(a, b, c) __builtin_amdgcn_mfma_f32_16x16x32_bf16(a, b, c, 0, 0, 0)

__device__ __forceinline__ short f2bf(float f) {
  unsigned u = __float_as_uint(f);
  u = (u + 0x7FFFu + ((u >> 16) & 1u)) >> 16;
  return (short)u;
}
__device__ __forceinline__ float bf2f(short s) {
  return __uint_as_float(((unsigned)(unsigned short)s) << 16);
}

// ============================================================================
// k_prep: ALL weight permutations + embnorm + border-zero + counts-zero
// + conv1 (writes A1 INTERIOR only; border-zero writes the ring - disjoint).
// grid 6977 x 256
// ============================================================================
__global__ __launch_bounds__(256) void k_prep(
    const float* __restrict__ c2w,
    const float* __restrict__ r1w3, const float* __restrict__ r2w3,
    const float* __restrict__ d1w3, const float* __restrict__ d2w3,
    const float* __restrict__ r1w1, const float* __restrict__ r2w1,
    const float* __restrict__ d1w1, const float* __restrict__ d2w1,
    const float* __restrict__ prew, const float* __restrict__ t1w,
    const float* __restrict__ emb,
    const float* __restrict__ x, const float* __restrict__ c1w,
    const float* __restrict__ c1b,
    short* __restrict__ wAc2, short* __restrict__ wAr3,
    short* __restrict__ wAr1, short* __restrict__ wApre,
    short* __restrict__ wAt1, short* __restrict__ Ecat,
    float* __restrict__ en, short* __restrict__ A1,
    short* __restrict__ XrP, int* __restrict__ counts) {
  __shared__ float sXp[4 * 260];
  __shared__ float sWt[16 * 64];
  int blk = blockIdx.x, t = threadIdx.x;
  if (blk < 512) {  // perm_c2
    int e = blk * 256 + t;
    int j = e & 7, l = (e >> 3) & 63, ot = (e >> 9) & 7, kc = e >> 12;
    int o = ot * 16 + (l & 15), g = l >> 4;
    int tap = kc >> 1, ci = (kc & 1) * 32 + 8 * g + j;
    wAc2[e] = f2bf(c2w[(o * 64 + ci) * 16 + tap]);
  } else if (blk < 1088) {  // perm_r3 x4
    int sub = blk - 512;
    int which = sub / 144, bb = sub - which * 144;
    const float* w = which == 0 ? r1w3 : which == 1 ? r2w3
                     : which == 2 ? d1w3 : d2w3;
    short* dst = wAr3 + which * 36864;
    int e = bb * 256 + t;
    int j = e & 7, l = (e >> 3) & 63, ot = (e >> 9) & 1, kc = e >> 10;
    int o = ot * 16 + (l & 15), g = l >> 4;
    int tap = kc >> 2, ci = (kc & 3) * 32 + 8 * g + j;
    dst[e] = f2bf(w[(o * 128 + ci) * 9 + tap]);
  } else if (blk < 1152) {  // perm_r1 x4
    int sub = blk - 1088;
    int which = sub >> 4, bb = sub & 15;
    const float* w = which == 0 ? r1w1 : which == 1 ? r2w1
                     : which == 2 ? d1w1 : d2w1;
    short* dst = wAr1 + which * 4096;
    int e = bb * 256 + t;
    int j = e & 7, l = (e >> 3) & 63, ot = e >> 9;
    int o = ot * 16 + (l & 15), g = l >> 4;
    int ci = 8 * g + j;
    dst[e] = f2bf(w[o * 32 + ci]);
  } else if (blk < 1216) {  // perm_pre
    int e = (blk - 1152) * 256 + t;
    int j = e & 7, l = (e >> 3) & 63, ot = (e >> 9) & 7, kc = e >> 12;
    int o = ot * 16 + (l & 15), g = l >> 4;
    int ci = kc * 32 + 8 * g + j;
    wApre[e] = f2bf(prew[o * 128 + ci]);
  } else if (blk < 1728) {  // perm_t1
    int e = (blk - 1216) * 256 + t;
    int j = e & 7, l = (e >> 3) & 63, ot = (e >> 9) & 3, kc = (e >> 11) & 15,
        pp = e >> 15;
    int pyr = pp >> 1, pxr = pp & 1;
    int o = ot * 16 + (l & 15), g = l >> 4;
    int tt = kc >> 2, dy = tt >> 1, dx = tt & 1;
    int ky = (1 - pyr) + 2 * dy, kx = (1 - pxr) + 2 * dx;
    int ci = (kc & 3) * 32 + 8 * g + j;
    wAt1[e] = f2bf(t1w[(ci * 64 + o) * 16 + ky * 4 + kx]);
  } else if (blk < 2496) {  // perm_E
    int e = (blk - 1728) * 256 + t;
    int j = e & 7, l = (e >> 3) & 63, ot = (e >> 9) & 31, kc = e >> 14;
    int c = ot * 16 + (l & 15);
    int k = kc * 32 + 8 * (l >> 4) + j;
    float v = emb[c * DD + (k & 127)];
    short hi = f2bf(v);
    Ecat[e] = (k < 256) ? hi : f2bf(v - bf2f(hi));
  } else if (blk < 2624) {  // embnorm: 4 codes per block (wave = code)
    int c = (blk - 2496) * 4 + (t >> 6), l = t & 63;
    float a = emb[c * DD + l], b2 = emb[c * DD + 64 + l];
    float s = a * a + b2 * b2;
#pragma unroll
    for (int m = 32; m >= 1; m >>= 1) s += __shfl_xor(s, m);
    if (l == 0) en[c] = s;
  } else if (blk < 2880) {  // border zero
    int bb = blk - 2624;
    int b = bb >> 3;
    int tid = ((bb & 7) << 8) + t;  // 0..2047
    short8 z8 = {};
    long baseA = (long)b * 1081600;  // 130*130*64
    for (int e = tid; e < 2080; e += 2048) {
      int r = e >= 1040;
      int rem = r ? e - 1040 : e;
      *(short8*)(A1 + baseA + (r ? 129L * 130 * 64 : 0) + rem * 8) = z8;
    }
    {
      int c = tid >> 10, rem = tid & 1023;
      int row = 1 + (rem >> 3), s8 = rem & 7;
      *(short8*)(A1 + baseA + (row * 130L + (c ? 129 : 0)) * 64 + s8 * 8) = z8;
    }
    long baseX = (long)b * 557568;  // 66*66*128
    for (int e = tid; e < 2112; e += 2048) {
      int r = e >= 1056;
      int rem = r ? e - 1056 : e;
      *(short8*)(XrP + baseX + (r ? 65L * 66 * 128 : 0) + rem * 8) = z8;
    }
    {
      int c = tid >> 10, rem = tid & 1023;
      int row = 1 + (rem >> 4), s8 = rem & 15;
      *(short8*)(XrP + baseX + (row * 66L + (c ? 65 : 0)) * 128 + s8 * 8) = z8;
    }
  } else if (blk == 2880) {  // counts zero
    counts[t] = 0;
    counts[t + 256] = 0;
  } else {  // conv1 (interior of A1)
    int cb = blk - 2881;
    int y = cb & 127, b = cb >> 7;
    for (int e = t; e < 1024; e += 256) sWt[e] = c1w[(e & 63) * 16 + (e >> 6)];
    if (t < 4) {
      sXp[t * 260] = 0.f;
      sXp[t * 260 + 257] = 0.f;
      sXp[t * 260 + 258] = 0.f;
      sXp[t * 260 + 259] = 0.f;
    }
    for (int e = t; e < 1024; e += 256) {
      int r = e >> 8, col = e & 255;
      int giy = 2 * y - 1 + r;
      float v = 0.f;
      if ((unsigned)giy < 256u) v = x[(b * 256 + giy) * 256 + col];
      sXp[r * 260 + col + 1] = v;
    }
    __syncthreads();
    int og = t >> 6, l = t & 63, o0 = og * 16;
    float acc0[16], acc1[16];
#pragma unroll
    for (int oo = 0; oo < 16; ++oo) { acc0[oo] = 0.f; acc1[oo] = 0.f; }
    int xA = 2 * l, xB = 2 * l + 128;
#pragma unroll
    for (int ky = 0; ky < 4; ++ky) {
#pragma unroll
      for (int kx = 0; kx < 4; ++kx) {
        float a0 = sXp[ky * 260 + xA + kx];
        float a1 = sXp[ky * 260 + xB + kx];
        const float* wrow = &sWt[(ky * 4 + kx) * 64 + o0];
#pragma unroll
        for (int oo = 0; oo < 16; ++oo) {
          float wv = wrow[oo];
          acc0[oo] = fmaf(a0, wv, acc0[oo]);
          acc1[oo] = fmaf(a1, wv, acc1[oo]);
        }
      }
    }
    long base0 = (((long)(b * 130 + y + 1)) * 130 + l + 1) * 64 + o0;
    long base1 = base0 + 64 * 64;
    short8 s0a, s0b, s1a, s1b;
#pragma unroll
    for (int oo = 0; oo < 8; ++oo) {
      s0a[oo] = f2bf(fmaxf(acc0[oo] + c1b[o0 + oo], 0.f));
      s0b[oo] = f2bf(fmaxf(acc0[oo + 8] + c1b[o0 + oo + 8], 0.f));
      s1a[oo] = f2bf(fmaxf(acc1[oo] + c1b[o0 + oo], 0.f));
      s1b[oo] = f2bf(fmaxf(acc1[oo + 8] + c1b[o0 + oo + 8], 0.f));
    }
    *(short8*)(A1 + base0) = s0a;
    *(short8*)(A1 + base0 + 8) = s0b;
    *(short8*)(A1 + base1) = s1a;
    *(short8*)(A1 + base1 + 8) = s1b;
  }
}

// ============================================================================
// conv2 MFMA v2 (LDS-staged input, register depth-1 weight prefetch):
// A1[130,130,64] bf16 -> relu -> Xf[64,64,128] f32 + XrP[66,66,128] bf16.
// grid 2048 = 32 b x 8 by x 8 bx
// ============================================================================
__global__ __launch_bounds__(256) void k_conv2m(const short* __restrict__ A1,
    const short* __restrict__ wA, const float* __restrict__ bias,
    float* __restrict__ Xf, short* __restrict__ XrP) {
  __shared__ short sX[22032];  // 324 px * 68 shorts (136 B) = 44,064 B
  int blk = blockIdx.x;
  int bx = blk & 7, by = (blk >> 3) & 7, b = blk >> 6;
  int t = threadIdx.x;
  int R0 = by * 16, C0 = bx * 16;
  for (int q = t; q < 2592; q += 256) {
    int p = q >> 3, seg = q & 7;
    int iy = p / 18, ix = p - iy * 18;
    short8 v = *(const short8*)(A1 +
        (((long)b * 130 + R0 + iy) * 130 + C0 + ix) * 64 + seg * 8);
    *(short8*)((char*)sX + p * 136 + seg * 16) = v;
  }
  __syncthreads();
  int w = t >> 6, l = t & 63, lr = l & 15, g = l >> 4;
  int Bb[4];
#pragma unroll
  for (int pt = 0; pt < 4; ++pt) {
    int p = pt * 16 + lr;
    int lp = 2 * (p >> 3) * 18 + 2 * (p & 7);
    Bb[pt] = lp * 136 + g * 16;
  }
  const short* pA0 = wA + (2 * w * 64 + l) * 8;
  const short* pA1 = pA0 + 512;
  f32x4 acc[2][4] = {};
  short8 a0 = *(const short8*)pA0;
  short8 a1 = *(const short8*)pA1;
  short8 bv[4];
#pragma unroll
  for (int i = 0; i < 4; ++i)
    bv[i] = *(const short8*)((const char*)sX + Bb[i]);
  for (int kc = 0; kc < 31; ++kc) {
    int nk = kc + 1;
    int tap = nk >> 1;
    int off = ((tap >> 2) * 18 + (tap & 3)) * 136 + (nk & 1) * 64;
    short8 na0 = *(const short8*)(pA0 + nk * 4096);
    short8 na1 = *(const short8*)(pA1 + nk * 4096);
    short8 nb[4];
#pragma unroll
    for (int i = 0; i < 4; ++i)
      nb[i] = *(const short8*)((const char*)sX + Bb[i] + off);
#pragma unroll
    for (int i = 0; i < 4; ++i) {
      acc[0][i] = MFMA(a0, bv[i], acc[0][i]);
      acc[1][i] = MFMA(a1, bv[i], acc[1][i]);
    }
    a0 = na0; a1 = na1;
#pragma unroll
    for (int i = 0; i < 4; ++i) bv[i] = nb[i];
  }
#pragma unroll
  for (int i = 0; i < 4; ++i) {
    acc[0][i] = MFMA(a0, bv[i], acc[0][i]);
    acc[1][i] = MFMA(a1, bv[i], acc[1][i]);
  }
#pragma unroll
  for (int oi = 0; oi < 2; ++oi) {
    int o0 = (2 * w + oi) * 16 + 4 * g;
#pragma unroll
    for (int pt = 0; pt < 4; ++pt) {
      int p = pt * 16 + lr;
      int y = by * 8 + (p >> 3), x = bx * 8 + (p & 7);
      f32x4 nv; short4v sv;
#pragma unroll
      for (int r = 0; r < 4; ++r) {
        float v = fmaxf(acc[oi][pt][r] + bias[o0 + r], 0.f);
        nv[r] = v; sv[r] = f2bf(v);
      }
      *(f32x4*)(Xf + ((b * 64 + y) * 64 + x) * 128 + o0) = nv;
      *(short4v*)(XrP + ((b * 66 + y + 1) * 66 + x + 1) * 128 + o0) = sv;
    }
  }
}

// ============================================================================
// resblk fused: res3 (3x3 conv -> H in LDS) + res1 (1x1 conv + residual).
// Block = 8x16 out-px (res3m tiling), grid 1024 = 32 b x 8 yt x 4 tx.
// MODE 0: input XrPin; residual from Xf; write Xf + XrPout.
// MODE 1: input XrPin; residual from Xf; write XrPout only.
// MODE 2: encoder tail - input XrPin; residual from Xf; xr stays in LDS,
//         then prem -> Zcat (Zc aliases Xf, barrier-ordered).
// MODE 3: decoder head - input staged by GATHERING relu(emb[idx[pix]]) from
//         L2 (QrP never materialized); residual = emb[idx[pix]];
//         write Xf + XrPout.
// ============================================================================
template <int MODE>
__global__ __launch_bounds__(256) void k_resblk(
    const short* __restrict__ XrPin, const short* __restrict__ wA3,
    const short* __restrict__ wA1, float* Xf, short* XrPout,
    const short* __restrict__ wAp, const float* __restrict__ preb,
    short* Zc, const float* __restrict__ embp, const int* __restrict__ idxb) {
  __shared__ short sX[23040];  // phase1 tile; MODE2 phase2 reuses as sXr
  __shared__ short sH[128 * 40];  // H: 128 px * 40 sh (80 B stride)
  int blk = blockIdx.x;
  int tx = blk & 3, yt = (blk >> 2) & 7, b = blk >> 5;
  int t = threadIdx.x;
  int r0 = yt * 8, c0 = tx * 16;
  for (int q = t; q < 2880; q += 256) {
    int p = q >> 4, seg = q & 15;
    int iy = p / 18, ix = p - iy * 18;
    short8 v;
    if (MODE == 3) {
      int yy = r0 + iy - 1, xx = c0 + ix - 1;
      if ((unsigned)yy < 64u && (unsigned)xx < 64u) {
        int cix = idxb[(b * 64 + yy) * 64 + xx];
        const float* ep = embp + cix * DD + seg * 8;
        f32x4 q0 = *(const f32x4*)ep;
        f32x4 q1 = *(const f32x4*)(ep + 4);
#pragma unroll
        for (int r = 0; r < 4; ++r) {
          v[r] = f2bf(fmaxf(q0[r], 0.f));
          v[r + 4] = f2bf(fmaxf(q1[r], 0.f));
        }
      } else {
        v = short8{};
      }
    } else {
      v = *(const short8*)(XrPin +
          (((long)b * 66 + r0 + iy) * 66 + c0 + ix) * 128 + seg * 8);
    }
    *(short8*)((char*)sX + p * 256 + ((seg * 16) ^ ((p & 7) << 4))) = v;
  }
  __syncthreads();
  int w = t >> 6, l = t & 63, lr = l & 15, g = l >> 4;
  // ---- phase 1: res3 3x3 conv, H -> sH ----
  {
    const short* pA0 = wA3 + l * 8;
    const short* pA1 = pA0 + 512;
    f32x4 acc[2][2] = {};
    short8 a0 = *(const short8*)pA0;
    short8 a1 = *(const short8*)pA1;
    short8 bv[2];
#pragma unroll
    for (int j = 0; j < 2; ++j) {
      int lp = (2 * w + j) * 18 + lr;
      bv[j] = *(const short8*)((const char*)sX + lp * 256 +
                               ((g * 16) ^ ((lp & 7) << 4)));
    }
    for (int kc = 0; kc < 35; ++kc) {
      int nk = kc + 1;
      int tap = nk >> 2;
      int ky = tap / 3, kx = tap - ky * 3;
      int inner = g * 16 + (nk & 3) * 64;
      short8 na0 = *(const short8*)(pA0 + nk * 1024);
      short8 na1 = *(const short8*)(pA1 + nk * 1024);
      short8 nb[2];
#pragma unroll
      for (int j = 0; j < 2; ++j) {
        int lp = (2 * w + j + ky) * 18 + lr + kx;
        nb[j] = *(const short8*)((const char*)sX + lp * 256 +
                                 (inner ^ ((lp & 7) << 4)));
      }
#pragma unroll
      for (int j = 0; j < 2; ++j) {
        acc[0][j] = MFMA(a0, bv[j], acc[0][j]);
        acc[1][j] = MFMA(a1, bv[j], acc[1][j]);
      }
      a0 = na0; a1 = na1;
      bv[0] = nb[0]; bv[1] = nb[1];
    }
#pragma unroll
    for (int j = 0; j < 2; ++j) {
      acc[0][j] = MFMA(a0, bv[j], acc[0][j]);
      acc[1][j] = MFMA(a1, bv[j], acc[1][j]);
    }
#pragma unroll
    for (int oi = 0; oi < 2; ++oi) {
      int o0 = oi * 16 + 4 * g;
#pragma unroll
      for (int j = 0; j < 2; ++j) {
        int p = (2 * w + j) * 16 + lr;
        short4v sv;
#pragma unroll
        for (int r = 0; r < 4; ++r) sv[r] = f2bf(fmaxf(acc[oi][j][r], 0.f));
        *(short4v*)(sH + p * 40 + o0) = sv;
      }
    }
  }
  __syncthreads();
  // ---- phase 2: res1 1x1 conv + residual over 128 px ----
  {
    f32x4 acc[2][8] = {};
    short8 a0 = *(const short8*)(wA1 + (2 * w * 64 + l) * 8);
    short8 a1 = *(const short8*)(wA1 + ((2 * w + 1) * 64 + l) * 8);
#pragma unroll
    for (int pt = 0; pt < 8; ++pt) {
      short8 bv = *(const short8*)(sH + (pt * 16 + lr) * 40 + 8 * g);
      acc[0][pt] = MFMA(a0, bv, acc[0][pt]);
      acc[1][pt] = MFMA(a1, bv, acc[1][pt]);
    }
#pragma unroll
    for (int oi = 0; oi < 2; ++oi) {
      int o0 = (2 * w + oi) * 16 + 4 * g;
#pragma unroll
      for (int pt = 0; pt < 8; ++pt) {
        int y = r0 + pt, x = c0 + lr;
        float* xp = Xf + ((b * 64 + y) * 64 + x) * 128 + o0;
        f32x4 old;
        if (MODE == 3) {
          int cix = idxb[(b * 64 + y) * 64 + x];
          old = *(const f32x4*)(embp + cix * DD + o0);
        } else {
          old = *(f32x4*)xp;
        }
        f32x4 nv; short4v sv;
#pragma unroll
        for (int r = 0; r < 4; ++r) {
          nv[r] = old[r] + acc[oi][pt][r];
          sv[r] = f2bf(fmaxf(nv[r], 0.f));
        }
        if (MODE == 0 || MODE == 3) *(f32x4*)xp = nv;
        if (MODE != 2) {
          *(short4v*)(XrPout + ((b * 66 + y + 1) * 66 + x + 1) * 128 + o0) =
              sv;
        } else {
          int p = pt * 16 + lr;
          *(short4v*)((char*)sX + p * 256 + ((o0 * 2) ^ ((p & 7) << 4))) = sv;
        }
      }
    }
  }
  if (MODE == 2) {
    __syncthreads();
    // ---- phase 3: prem 1x1 conv over xr (in sX), write Zcat ----
    const short* pA0 = wAp + (2 * w * 64 + l) * 8;
    const short* pA1 = pA0 + 512;
    f32x4 acc[2][8] = {};
#pragma unroll
    for (int kc = 0; kc < 4; ++kc) {
      short8 a0 = *(const short8*)(pA0 + kc * 4096);
      short8 a1 = *(const short8*)(pA1 + kc * 4096);
#pragma unroll
      for (int pt = 0; pt < 8; ++pt) {
        int p = pt * 16 + lr;
        short8 bv = *(const short8*)((const char*)sX + p * 256 +
                                     ((kc * 64 + g * 16) ^ ((p & 7) << 4)));
        acc[0][pt] = MFMA(a0, bv, acc[0][pt]);
        acc[1][pt] = MFMA(a1, bv, acc[1][pt]);
      }
    }
#pragma unroll
    for (int oi = 0; oi < 2; ++oi) {
      int o0 = (2 * w + oi) * 16 + 4 * g;
#pragma unroll
      for (int pt = 0; pt < 8; ++pt) {
        int y = r0 + pt, x = c0 + lr;
        long pix = (long)(b * 64 + y) * 64 + x;
        short4v hv, lv;
#pragma unroll
        for (int r = 0; r < 4; ++r) {
          float v = acc[oi][pt][r] + preb[o0 + r];
          short hi = f2bf(v);
          hv[r] = hi;
          lv[r] = f2bf(v - bf2f(hi));
        }
        *(short4v*)(Zc + pix * 256 + o0) = hv;
        *(short4v*)(Zc + pix * 256 + 128 + o0) = lv;
      }
    }
  }
}

#define GLOAD_LDS16(g, l)                                        \
  __builtin_amdgcn_global_load_lds(                              \
      (const __attribute__((address_space(1))) void*)(g),        \
      (__attribute__((address_space(3))) void*)(l), 16, 0, 0)

// ============================================================================
// VQ MFMA v11 (async E-staging, 128 px, idx-only output): 128 px x 512 codes,
// 8 waves (512 thr), grid 1024. Writes ONLY idx (0.5 MB) + hist + loss -
// both Q and QrP are re-gathered downstream from L2-resident emb via idx
// (k_resblk<3>). No gather/store tail at all.
// ============================================================================
__global__ __launch_bounds__(512) void k_vqm9(const short* __restrict__ Zc,
    const short* __restrict__ Ec, const float* __restrict__ en,
    const float* __restrict__ emb, int* __restrict__ counts,
    float* __restrict__ partials, int* __restrict__ idx_out) {
  __shared__ short sZ[32768];  // 128 px * 256 sh, swizzled = 64 KB
  __shared__ short sE[16384];  // E slab: 8 wave-regions x 2048 sh = 32 KB
  __shared__ float sV[8][128];
  __shared__ int sC[8][128];
  __shared__ float sZn[128];
  __shared__ int sHist[KC];
  int blk = blockIdx.x;
  long pix0 = (long)blk * 128;
  int t = threadIdx.x, w = t >> 6, l = t & 63, c16 = l & 15, g = (l >> 4) & 3;
  for (int e = t; e < KC; e += 512) sHist[e] = 0;

  // stage Z tile: swizzle inner-byte ^ ((pix&7)<<4)
  for (int q = t; q < 4096; q += 512) {
    int p = q >> 5, seg = q & 31;
    short8 v = *(const short8*)(Zc + (pix0 + p) * 256 + seg * 8);
    *(short8*)((char*)sZ + p * 512 + ((seg * 16) ^ ((p & 7) << 4))) = v;
  }
  __syncthreads();

  // ||z||^2 per pixel from LDS: 4 threads/pixel, each 32 dims (128 px)
  {
    int pz = t >> 2, seg4 = t & 3;
    const char* zb = (const char*)sZ + pz * 512;
    int swp = (pz & 7) << 4;
    float s = 0.f;
#pragma unroll
    for (int qq = 0; qq < 4; ++qq) {
      int ih = seg4 * 64 + 16 * qq;  // zh inner byte
      short8 h8 = *(const short8*)(zb + (ih ^ swp));
      short8 l8 = *(const short8*)(zb + ((ih + 256) ^ swp));
#pragma unroll
      for (int j = 0; j < 8; ++j) {
        float zv = bf2f(h8[j]) + bf2f(l8[j]);
        s = fmaf(zv, zv, s);
      }
    }
    s += __shfl_xor(s, 1);
    s += __shfl_xor(s, 2);
    if (seg4 == 0) sZn[pz] = s;
  }

  // GEMM: 12 K-steps of 32; wave-local async E staging; 8 pixel-tiles.
  int sw = (c16 & 7) << 4;
  int zrow = c16 * 512;
  short* sEw = sE + w * 2048;                   // wave-uniform LDS base
  const short* gEw = Ec + w * 2048 + l * 8;     // per-lane global src
  f32x4 acc[4][8] = {};
  for (int kc = 0; kc < 12; ++kc) {
    if (kc) asm volatile("s_waitcnt lgkmcnt(0)" ::: "memory");
#pragma unroll
    for (int i = 0; i < 4; ++i)
      GLOAD_LDS16(gEw + kc * 16384 + i * 512, sEw + i * 512);
    asm volatile("s_waitcnt vmcnt(0)" ::: "memory");
    int koff = kc < 8 ? kc : kc - 8;
    int inn = ((koff * 64 + g * 16) ^ sw);
    const char* zb = (const char*)sZ + zrow + inn;
    short8 a0 = *(const short8*)(sEw + l * 8);
    short8 a1 = *(const short8*)(sEw + 512 + l * 8);
    short8 a2 = *(const short8*)(sEw + 1024 + l * 8);
    short8 a3 = *(const short8*)(sEw + 1536 + l * 8);
#pragma unroll
    for (int pt = 0; pt < 8; ++pt) {
      short8 bb = *(const short8*)(zb + pt * 8192);
      acc[0][pt] = MFMA(a0, bb, acc[0][pt]);
      acc[1][pt] = MFMA(a1, bb, acc[1][pt]);
      acc[2][pt] = MFMA(a2, bb, acc[2][pt]);
      acc[3][pt] = MFMA(a3, bb, acc[3][pt]);
    }
  }
  // running argmin over the wave's 64 codes (codes ascend: ct, r)
  float bvv[8];
  int bcc[8];
#pragma unroll
  for (int pt = 0; pt < 8; ++pt) { bvv[pt] = 3.4e38f; bcc[pt] = 0; }
#pragma unroll
  for (int ct = 0; ct < 4; ++ct) {
    f32x4 en4 = *(const f32x4*)(en + w * 64 + ct * 16 + 4 * g);
#pragma unroll
    for (int pt = 0; pt < 8; ++pt) {
#pragma unroll
      for (int r = 0; r < 4; ++r) {
        float d = en4[r] - 2.f * acc[ct][pt][r];
        int code = w * 64 + ct * 16 + 4 * g + r;
        if (d < bvv[pt]) { bvv[pt] = d; bcc[pt] = code; }
      }
    }
  }
  // cross-lane reduce (over g) per pixel
#pragma unroll
  for (int pt = 0; pt < 8; ++pt) {
    float bv = bvv[pt];
    int bc = bcc[pt];
#pragma unroll
    for (int m = 16; m <= 32; m <<= 1) {
      float ov = __shfl_xor(bv, m);
      int oc = __shfl_xor(bc, m);
      if (ov < bv || (ov == bv && oc < bc)) { bv = ov; bc = oc; }
    }
    if (g == 0) {
      sV[w][pt * 16 + c16] = bv;
      sC[w][pt * 16 + c16] = bc;
    }
  }
  __syncthreads();
  if (t < 128) {
    float bv = sV[0][t];
    int bc = sC[0][t];
#pragma unroll
    for (int w2 = 1; w2 < 8; ++w2) {
      float v = sV[w2][t];
      int c = sC[w2][t];
      if (v < bv || (v == bv && c < bc)) { bv = v; bc = c; }
    }
    idx_out[pix0 + t] = bc;
    atomicAdd(&sHist[bc], 1);
    sV[0][t] = bv + sZn[t];
  }
  __syncthreads();
  if (t < 64) {
    float ls = sV[0][t] + sV[0][t + 64];
#pragma unroll
    for (int m = 32; m >= 1; m >>= 1) ls += __shfl_xor(ls, m);
    if (t == 0) partials[blk] = ls;
  }
  for (int e = t; e < KC; e += 512) {
    int c = sHist[e];
    if (c) atomicAdd(&counts[e], c);
  }
}

// ============================================================================
// tconv1 MFMA v2 (LDS-staged input, register depth-1 weight prefetch):
// QrP[66,66,128] -> T1[130,130,64] bf16 relu.
// grid 2048 = 32 b x 8 tyt x 8 txt
// ============================================================================
__global__ __launch_bounds__(256) void k_tconv1m(const short* __restrict__ QrP,
    const short* __restrict__ wA, const float* __restrict__ bias,
    short* __restrict__ T1) {
  __shared__ short sX[13600];  // 100 pixels x 136 shorts
  int blk = blockIdx.x;
  int txt = blk & 7, tyt = (blk >> 3) & 7, b = blk >> 6;
  int my0 = tyt * 8, mx0 = txt * 8;
  int t = threadIdx.x;
  for (int q = t; q < 1600; q += 256) {
    int p = q >> 4, seg = q & 15;
    int iy = p / 10, ix = p - iy * 10;
    short8 v = *(const short8*)(QrP +
        ((b * 66 + my0 + iy) * 66 + mx0 + ix) * 128 + seg * 8);
    *(short8*)((char*)sX + p * 272 + seg * 16) = v;
  }
  __syncthreads();
  int w = t >> 6, l = t & 63, lr = l & 15, g = l >> 4;
  int pyr = w >> 1, pxr = w & 1;
  int Bb[4];
#pragma unroll
  for (int nt = 0; nt < 4; ++nt) {
    int p = nt * 16 + lr;
    int my = p >> 3, mx = p & 7;
    Bb[nt] = ((my + pyr + 1) * 10 + (mx + pxr + 1)) * 272 + g * 16;
  }
  const short* pAw = wA + w * 32768 + l * 8;
  f32x4 acc[4][4] = {};
  short8 a[4], bfr[4], na[4], nb[4];
#pragma unroll
  for (int ot = 0; ot < 4; ++ot) a[ot] = *(const short8*)(pAw + ot * 512);
#pragma unroll
  for (int nt = 0; nt < 4; ++nt)
    bfr[nt] = *(const short8*)((const char*)sX + Bb[nt]);
  for (int kc = 0; kc < 15; ++kc) {
    int nk = kc + 1;
    int tt = nk >> 2, dy = tt >> 1, dx = tt & 1;
    int off = -(dy * 10 + dx) * 272 + (nk & 3) * 64;
#pragma unroll
    for (int ot = 0; ot < 4; ++ot)
      na[ot] = *(const short8*)(pAw + nk * 2048 + ot * 512);
#pragma unroll
    for (int nt = 0; nt < 4; ++nt)
      nb[nt] = *(const short8*)((const char*)sX + Bb[nt] + off);
#pragma unroll
    for (int ot = 0; ot < 4; ++ot)
#pragma unroll
      for (int nt = 0; nt < 4; ++nt)
        acc[ot][nt] = MFMA(a[ot], bfr[nt], acc[ot][nt]);
#pragma unroll
    for (int ot = 0; ot < 4; ++ot) a[ot] = na[ot];
#pragma unroll
    for (int nt = 0; nt < 4; ++nt) bfr[nt] = nb[nt];
  }
#pragma unroll
  for (int ot = 0; ot < 4; ++ot)
#pragma unroll
    for (int nt = 0; nt < 4; ++nt)
      acc[ot][nt] = MFMA(a[ot], bfr[nt], acc[ot][nt]);
#pragma unroll
  for (int ot = 0; ot < 4; ++ot) {
    int o0 = ot * 16 + 4 * g;
    f32x4 b4 = *(const f32x4*)(bias + o0);
#pragma unroll
    for (int nt = 0; nt < 4; ++nt) {
      int p = nt * 16 + lr;
      int my = my0 + (p >> 3), mx = mx0 + (p & 7);
      int oy = 2 * my + pyr, ox = 2 * mx + pxr;
      short4v sv;
#pragma unroll
      for (int r = 0; r < 4; ++r)
        sv[r] = f2bf(fmaxf(acc[ot][nt][r] + b4[r], 0.f));
      *(short4v*)(T1 + ((b * 130 + oy + 1) * 130 + ox + 1) * 64 + o0) = sv;
    }
  }
}

// ============================================================================
// tconv2 MFMA v2 + fused finalize: T1[130,130,64] bf16 -> x_recon f32.
// Block 8192 (one extra) computes loss/perplexity. grid 8193.
// ============================================================================
__global__ __launch_bounds__(256) void k_tconv2m(const short* __restrict__ T1,
    const float* __restrict__ w, const float* __restrict__ bias,
    float* __restrict__ out, const float* __restrict__ partials,
    const int* __restrict__ counts) {
  __shared__ short sT[112 * 72];  // 112 px * 144 B = 16,128 B
  __shared__ float sW[1024];
  __shared__ float sC[112 * 20];  // px stride 80 B (16-B aligned)
  int blk = blockIdx.x;
  int t = threadIdx.x;
  if (blk == 8192) {  // finalize: loss from 1024 partials; perplexity
    float s = 0.f;
    for (int i = t; i < 1024; i += 256) s += partials[i];
#pragma unroll
    for (int m = 32; m >= 1; m >>= 1) s += __shfl_xor(s, m);
    __shared__ float sr[4];
    if ((t & 63) == 0) sr[t >> 6] = s;
    __syncthreads();
    if (t == 0) {
      float tot = sr[0] + sr[1] + sr[2] + sr[3];
      out[0] = 1.25f * tot / 16777216.0f;
    }
    float h = 0.f;
    for (int c = t; c < KC; c += 256) {
      float avg = (float)counts[c] / 131072.0f;
      h += avg * logf(avg + 1e-10f);
    }
#pragma unroll
    for (int m = 32; m >= 1; m >>= 1) h += __shfl_xor(h, m);
    __shared__ float sr2[4];
    if ((t & 63) == 0) sr2[t >> 6] = h;
    __syncthreads();
    if (t == 0)
      out[1 + 32 * 256 * 256] = expf(-(sr2[0] + sr2[1] + sr2[2] + sr2[3]));
    return;
  }
  float* xrec = out + 1;
  int tx = blk & 15, ty = (blk >> 4) & 15, b = blk >> 8;
  for (int e = t; e < 1024; e += 256) sW[e] = w[e];
  for (int q = t; q < 800; q += 256) {
    int p = q >> 3, seg = q & 7;
    int iy = p / 10, ix = p - iy * 10;
    short8 v = *(const short8*)(T1 +
        (((long)b * 130 + ty * 8 + iy) * 130 + tx * 8 + ix) * 64 + seg * 8);
    *(short8*)((char*)sT + p * 144 + seg * 16) = v;
  }
  __syncthreads();
  int wv = t >> 6, l = t & 63, lr = l & 15, g = l >> 4;
  short8 af[4];
#pragma unroll
  for (int kc = 0; kc < 4; ++kc) {
#pragma unroll
    for (int j = 0; j < 8; ++j) {
      int k = kc * 32 + 8 * g + j;
      float val = sW[(k & 63) * 16 + lr];
      short hi = f2bf(val);
      af[kc][j] = (k < 64) ? hi : f2bf(val - bf2f(hi));
    }
  }
#pragma unroll
  for (int ti = 0; ti < 2; ++ti) {
    int tile = wv + 4 * ti;
    if (tile < 7) {
      f32x4 acc = {};
#pragma unroll
      for (int kc = 0; kc < 4; ++kc) {
        short8 bf = *(const short8*)((const char*)sT +
            (tile * 16 + lr) * 144 + ((kc & 1) * 64 + g * 16));
        acc = MFMA(af[kc], bf, acc);
      }
      *(f32x4*)(sC + (tile * 16 + lr) * 20 + g * 4) = acc;
    }
  }
  __syncthreads();
  int row = t >> 4, col = t & 15;
  int pyr = row & 1, pxr = col & 1;
  int ml = row >> 1, nl = col >> 1;
  int kye = 1 - pyr, kxe = 1 - pxr;
  float acc = bias[0];
#pragma unroll
  for (int dy = 0; dy < 2; ++dy)
#pragma unroll
    for (int dx = 0; dx < 2; ++dx) {
      int px = (ml + pyr - dy + 1) * 10 + (nl + pxr - dx + 1);
      int tap = (kye + 2 * dy) * 4 + (kxe + 2 * dx);
      acc += sC[px * 20 + tap];
    }
  int oy = ty * 16 + row, ox = tx * 16 + col;
  xrec[((long)b * 256 + oy) * 256 + ox] = acc;
}

// ============================================================================
extern "C" void kernel_launch(void* const* d_in, const int* in_sizes, int n_in,
                              void* d_out, int out_size, void* d_ws, size_t ws_size,
                              hipStream_t stream) {
  const float* x    = (const float*)d_in[0];
  const float* c1w  = (const float*)d_in[1];
  const float* c1b  = (const float*)d_in[2];
  const float* c2w  = (const float*)d_in[3];
  const float* c2b  = (const float*)d_in[4];
  const float* r1w3 = (const float*)d_in[5];
  const float* r1w1 = (const float*)d_in[6];
  const float* r2w3 = (const float*)d_in[7];
  const float* r2w1 = (const float*)d_in[8];
  const float* prew = (const float*)d_in[9];
  const float* preb = (const float*)d_in[10];
  const float* emb  = (const float*)d_in[11];
  const float* d1w3 = (const float*)d_in[12];
  const float* d1w1 = (const float*)d_in[13];
  const float* d2w3 = (const float*)d_in[14];
  const float* d2w1 = (const float*)d_in[15];
  const float* t1w  = (const float*)d_in[16];
  const float* t1b  = (const float*)d_in[17];
  const float* t2w  = (const float*)d_in[18];
  const float* t2b  = (const float*)d_in[19];
  float* out = (float*)d_out;

  char* ws = (char*)d_ws;
  short* buf0 = (short*)(ws);                      // A1 / T1 : 69,222,400 B
  float* bufX = (float*)(ws + 69222400);           // Xf / Zcat : 67,108,864 B
  short* bufR = (short*)(ws + 136331264);          // XrP : 35,684,352 B
  int*   idx  = (int*)(ws + 180404224);            // 524,288 B
  int*   counts = (int*)(ws + 180928512);          // 2,048 B
  float* partials = (float*)(ws + 180930560);      // 8,192 B
  float* en   = (float*)(ws + 180938752);          // 2,048 B
  short* wAc2 = (short*)(ws + 180940800);          // 262,144 B
  short* wAr3 = (short*)(ws + 181202944);          // 294,912 B
  short* wAr1 = (short*)(ws + 181497856);          // 32,768 B
  short* wApre= (short*)(ws + 181530624);          // 32,768 B
  short* wAt1 = (short*)(ws + 181563392);          // 262,144 B
  short* Ecat = (short*)(ws + 181825536);          // 393,216 B -> ends 182,218,752

  short* Zcat = (short*)bufX;  // Zcat aliases Xf (k_resblk<2> reads Xf,
                               // writes the same bytes after a barrier;
                               // k_resblk<3> later overwrites with dec Xf)

  short* wAr3_e1 = wAr3;
  short* wAr3_e2 = wAr3 + 36864;
  short* wAr3_d1 = wAr3 + 2 * 36864;
  short* wAr3_d2 = wAr3 + 3 * 36864;
  short* wAr1_e1 = wAr1;
  short* wAr1_e2 = wAr1 + 4096;
  short* wAr1_d1 = wAr1 + 2 * 4096;
  short* wAr1_d2 = wAr1 + 3 * 4096;

  k_prep <<<6977, 256, 0, stream>>>(c2w, r1w3, r2w3, d1w3, d2w3,
                                    r1w1, r2w1, d1w1, d2w1, prew, t1w, emb,
                                    x, c1w, c1b,
                                    wAc2, wAr3, wAr1, wApre, wAt1, Ecat,
                                    en, buf0, bufR, counts);

  k_conv2m    <<<2048, 256, 0, stream>>>(buf0, wAc2, c2b, bufX, bufR);
  k_resblk<0> <<<1024, 256, 0, stream>>>(bufR, wAr3_e1, wAr1_e1, bufX, bufR,
                                         nullptr, nullptr, nullptr,
                                         nullptr, nullptr);
  k_resblk<2> <<<1024, 256, 0, stream>>>(bufR, wAr3_e2, wAr1_e2, bufX, nullptr,
                                         wApre, preb, Zcat, nullptr, nullptr);
  k_vqm9      <<<1024, 512, 0, stream>>>(Zcat, Ecat, en, emb, counts,
                                         partials, idx);
  k_resblk<3> <<<1024, 256, 0, stream>>>(nullptr, wAr3_d1, wAr1_d1, bufX, bufR,
                                         nullptr, nullptr, nullptr,
                                         emb, idx);
  k_resblk<1> <<<1024, 256, 0, stream>>>(bufR, wAr3_d2, wAr1_d2, bufX, bufR,
                                         nullptr, nullptr, nullptr,
                                         nullptr, nullptr);
  k_tconv1m   <<<2048, 256, 0, stream>>>(bufR, wAt1, t1b, buf0);
  k_tconv2m   <<<8193, 256, 0, stream>>>(buf0, t2w, t2b, out, partials,
                                         counts);
}